// Round 2
// baseline (3581.400 us; speedup 1.0000x reference)
//
#include <hip/hip_runtime.h>

#define BN_EPS 1e-5f

// ---------------- degree kernels ----------------
__global__ void fill_ones(float* __restrict__ p, int n) {
  int i = blockIdx.x * blockDim.x + threadIdx.x;
  if (i < n) p[i] = 1.0f;
}

// NOTE: harness materializes integer inputs as int32 (see contract), so
// edge_index is read as int, NOT long long.
__global__ void deg_count(const int* __restrict__ ei, float* __restrict__ deg, int E_) {
  int e = blockIdx.x * blockDim.x + threadIdx.x;
  if (e < E_) {
    int d = ei[(size_t)E_ + e];
    atomicAdd(&deg[d], 1.0f);
  }
}

__global__ void rsqrt_inplace(float* __restrict__ p, int n) {
  int i = blockIdx.x * blockDim.x + threadIdx.x;
  if (i < n) p[i] = rsqrtf(p[i]);
}

// ---------------- dense matmul with fused BN+ReLU on the INPUT ----------------
// out[n, COUT] = act(in[n, CIN]) @ W[CIN, COUT]
// act (FUSE=true): relu((v + bprev[k] - rm[k]) * g[k]*rsqrt(rv[k]+eps) + be[k])
template <int CIN, int COUT, bool FUSE>
__global__ void matmul_bn_relu(const float* __restrict__ in, const float* __restrict__ W,
                               const float* __restrict__ bprev, const float* __restrict__ g,
                               const float* __restrict__ be, const float* __restrict__ rm,
                               const float* __restrict__ rv,
                               float* __restrict__ out, int n) {
  constexpr int ROWS = 256 / COUT;   // nodes per block
  __shared__ float sh[ROWS * CIN];
  const int tid = threadIdx.x;
  const int nodeBase = blockIdx.x * ROWS;

  for (int i = tid; i < ROWS * CIN; i += 256) {
    const int nl = i / CIN, k = i % CIN;
    const int node = nodeBase + nl;
    float v = 0.0f;
    if (node < n) {
      v = in[(size_t)node * CIN + k];
      if constexpr (FUSE) {
        const float a = g[k] * rsqrtf(rv[k] + BN_EPS);
        const float s = (bprev[k] - rm[k]) * a + be[k];
        v = v * a + s;
        v = v > 0.0f ? v : 0.0f;
      }
    }
    sh[i] = v;
  }
  __syncthreads();

  const int nl = tid / COUT, c = tid % COUT;
  const int node = nodeBase + nl;
  if (node >= n) return;
  float acc = 0.0f;
#pragma unroll
  for (int k = 0; k < CIN; ++k)
    acc += sh[nl * CIN + k] * W[k * COUT + c];
  out[(size_t)node * COUT + c] = acc;
}

// ---------------- self-loop init: agg = h * dinv^2 ----------------
template <int COUT>
__global__ void init_agg(const float* __restrict__ h, const float* __restrict__ dinv,
                         float* __restrict__ agg, int n) {
  const long long i = (long long)blockIdx.x * blockDim.x + threadIdx.x;
  const long long total = (long long)n * COUT;
  if (i < total) {
    const int node = (int)(i / COUT);
    const float d = dinv[node];
    agg[i] = h[i] * d * d;
  }
}

// ---------------- edge scatter: agg[dst] += h[src] * dinv[src]*dinv[dst] ----------------
template <int COUT>
__global__ void edge_scatter(const int* __restrict__ ei, const float* __restrict__ dinv,
                             const float* __restrict__ h, float* __restrict__ agg, int E_) {
  constexpr int TPE = COUT / 4;       // threads per edge (float4 per thread)
  constexpr int EPB = 256 / TPE;      // edges per block
  __shared__ int sl[EPB];
  __shared__ int dl[EPB];
  __shared__ float nl[EPB];
  const int tid = threadIdx.x;
  const int base = blockIdx.x * EPB;

  if (tid < EPB) {
    const int e = base + tid;
    if (e < E_) {
      const int s = ei[e];
      const int d = ei[(size_t)E_ + e];
      sl[tid] = s;
      dl[tid] = d;
      nl[tid] = dinv[s] * dinv[d];
    }
  }
  __syncthreads();

  const int el = tid / TPE;
  const int e = base + el;
  if (e >= E_) return;
  const int c = (tid % TPE) * 4;
  const int s = sl[el];
  const int d = dl[el];
  const float w = nl[el];
  const float4 hv = *reinterpret_cast<const float4*>(h + (size_t)s * COUT + c);
  float* ap = agg + (size_t)d * COUT + c;
  atomicAdd(ap + 0, hv.x * w);
  atomicAdd(ap + 1, hv.y * w);
  atomicAdd(ap + 2, hv.z * w);
  atomicAdd(ap + 3, hv.w * w);
}

// ---------------- classifier: act3 -> 32x2 linear -> log_softmax ----------------
__global__ void classifier(const float* __restrict__ agg,
                           const float* __restrict__ b3, const float* __restrict__ g3,
                           const float* __restrict__ be3, const float* __restrict__ rm3,
                           const float* __restrict__ rv3,
                           const float* __restrict__ Wc, const float* __restrict__ bc,
                           float* __restrict__ out, int n) {
  const int i = blockIdx.x * blockDim.x + threadIdx.x;
  if (i >= n) return;
  float l0 = bc[0], l1 = bc[1];
#pragma unroll
  for (int k = 0; k < 32; ++k) {
    const float a = g3[k] * rsqrtf(rv3[k] + BN_EPS);
    const float s = (b3[k] - rm3[k]) * a + be3[k];
    float v = agg[(size_t)i * 32 + k] * a + s;
    v = v > 0.0f ? v : 0.0f;
    l0 += v * Wc[k * 2 + 0];
    l1 += v * Wc[k * 2 + 1];
  }
  const float m = fmaxf(l0, l1);
  const float lse = m + logf(expf(l0 - m) + expf(l1 - m));
  out[(size_t)i * 2 + 0] = l0 - lse;
  out[(size_t)i * 2 + 1] = l1 - lse;
}

// ---------------- launch ----------------
extern "C" void kernel_launch(void* const* d_in, const int* in_sizes, int n_in,
                              void* d_out, int out_size, void* d_ws, size_t ws_size,
                              hipStream_t stream) {
  const float* x      = (const float*)d_in[0];
  const int* ei       = (const int*)d_in[1];   // int32 on device per harness contract
  const float* W1 = (const float*)d_in[2];
  const float* b1 = (const float*)d_in[3];
  const float* g1 = (const float*)d_in[4];
  const float* be1 = (const float*)d_in[5];
  const float* rm1 = (const float*)d_in[6];
  const float* rv1 = (const float*)d_in[7];
  const float* W2 = (const float*)d_in[8];
  const float* b2 = (const float*)d_in[9];
  const float* g2 = (const float*)d_in[10];
  const float* be2 = (const float*)d_in[11];
  const float* rm2 = (const float*)d_in[12];
  const float* rv2 = (const float*)d_in[13];
  const float* W3 = (const float*)d_in[14];
  const float* b3 = (const float*)d_in[15];
  const float* g3 = (const float*)d_in[16];
  const float* be3 = (const float*)d_in[17];
  const float* rm3 = (const float*)d_in[18];
  const float* rv3 = (const float*)d_in[19];
  const float* Wc = (const float*)d_in[20];
  const float* bc = (const float*)d_in[21];

  const int N_ = in_sizes[0] / 8;
  const int E_ = in_sizes[1] / 2;

  char* ws = (char*)d_ws;
  float* dinv = (float*)ws;
  const size_t off0 = (((size_t)N_ * 4) + 255) & ~(size_t)255;
  float* bufA = (float*)(ws + off0);
  const size_t big = (((size_t)N_ * 64 * 4) + 255) & ~(size_t)255;
  float* bufB = (float*)(ws + off0 + big);

  const int nb_n = (N_ + 255) / 256;

  // degrees (deg = 1 + in-degree), then dinv = rsqrt(deg) in place
  fill_ones<<<nb_n, 256, 0, stream>>>(dinv, N_);
  deg_count<<<(E_ + 255) / 256, 256, 0, stream>>>(ei, dinv, E_);
  rsqrt_inplace<<<nb_n, 256, 0, stream>>>(dinv, N_);

  // ---- layer 1: h1 = x @ W1 (A); agg1 (B) ----
  matmul_bn_relu<8, 64, false><<<(N_ + 3) / 4, 256, 0, stream>>>(
      x, W1, nullptr, nullptr, nullptr, nullptr, nullptr, bufA, N_);
  init_agg<64><<<(int)(((size_t)N_ * 64 + 255) / 256), 256, 0, stream>>>(bufA, dinv, bufB, N_);
  edge_scatter<64><<<(E_ + 15) / 16, 256, 0, stream>>>(ei, dinv, bufA, bufB, E_);

  // ---- layer 2: h2 = act1(agg1) @ W2 (A); agg2 (B) ----
  matmul_bn_relu<64, 64, true><<<(N_ + 3) / 4, 256, 0, stream>>>(
      bufB, W2, b1, g1, be1, rm1, rv1, bufA, N_);
  init_agg<64><<<(int)(((size_t)N_ * 64 + 255) / 256), 256, 0, stream>>>(bufA, dinv, bufB, N_);
  edge_scatter<64><<<(E_ + 15) / 16, 256, 0, stream>>>(ei, dinv, bufA, bufB, E_);

  // ---- layer 3: h3 = act2(agg2) @ W3 (A); agg3 (B) ----
  matmul_bn_relu<64, 32, true><<<(N_ + 7) / 8, 256, 0, stream>>>(
      bufB, W3, b2, g2, be2, rm2, rv2, bufA, N_);
  init_agg<32><<<(int)(((size_t)N_ * 32 + 255) / 256), 256, 0, stream>>>(bufA, dinv, bufB, N_);
  edge_scatter<32><<<(E_ + 31) / 32, 256, 0, stream>>>(ei, dinv, bufA, bufB, E_);

  // ---- classifier: act3 -> 32x2 -> log_softmax ----
  classifier<<<nb_n, 256, 0, stream>>>(bufB, b3, g3, be3, rm3, rv3, Wc, bc,
                                       (float*)d_out, N_);
}

// Round 3
// 514.336 us; speedup vs baseline: 6.9632x; 6.9632x over previous
//
#include <hip/hip_runtime.h>

#define BN_EPS 1e-5f

// ============ CSR build ============
__global__ void zero_int(int* __restrict__ p, int n) {
  int i = blockIdx.x * blockDim.x + threadIdx.x;
  if (i < n) p[i] = 0;
}

__global__ void count_dst(const int* __restrict__ ei, int* __restrict__ cnt, int E_) {
  int e = blockIdx.x * blockDim.x + threadIdx.x;
  if (e < E_) atomicAdd(&cnt[ei[(size_t)E_ + e]], 1);
}

__global__ void dinv_from_cnt(const int* __restrict__ cnt, float* __restrict__ dinv, int n) {
  int i = blockIdx.x * blockDim.x + threadIdx.x;
  if (i < n) dinv[i] = rsqrtf((float)cnt[i] + 1.0f);
}

// per-block exclusive scan of 256 ints; block sums to bsum
__global__ void scan256(const int* __restrict__ in, int* __restrict__ out,
                        int* __restrict__ bsum, int n) {
  __shared__ int sh[256];
  const int i = blockIdx.x * 256 + threadIdx.x;
  const int v = (i < n) ? in[i] : 0;
  sh[threadIdx.x] = v;
  __syncthreads();
  for (int off = 1; off < 256; off <<= 1) {
    int t = (threadIdx.x >= off) ? sh[threadIdx.x - off] : 0;
    __syncthreads();
    sh[threadIdx.x] += t;
    __syncthreads();
  }
  if (i < n) out[i] = sh[threadIdx.x] - v;  // exclusive
  if (threadIdx.x == 255) bsum[blockIdx.x] = sh[255];
}

// single-block exclusive scan, n <= 512, in place
__global__ void scan_single(int* __restrict__ data, int n) {
  __shared__ int sh[512];
  const int t = threadIdx.x;
  const int v = (t < n) ? data[t] : 0;
  sh[t] = v;
  __syncthreads();
  for (int off = 1; off < 512; off <<= 1) {
    int u = (t >= off) ? sh[t - off] : 0;
    __syncthreads();
    sh[t] += u;
    __syncthreads();
  }
  if (t < n) data[t] = sh[t] - v;  // exclusive
}

__global__ void add_offsets(int* __restrict__ row_ptr, const int* __restrict__ bsum,
                            int n, int E_) {
  const int i = blockIdx.x * 256 + threadIdx.x;
  if (i < n) row_ptr[i] += bsum[blockIdx.x];
  if (blockIdx.x == 0 && threadIdx.x == 0) row_ptr[n] = E_;
}

__global__ void copy_int(const int* __restrict__ src, int* __restrict__ dst, int n) {
  int i = blockIdx.x * blockDim.x + threadIdx.x;
  if (i < n) dst[i] = src[i];
}

// scatter each edge into its CSR slot: edata[pos] = (src, dinv[src]*dinv[dst])
__global__ void fill_csr(const int* __restrict__ ei, const float* __restrict__ dinv,
                         int* __restrict__ cursor, int2* __restrict__ edata, int E_) {
  int e = blockIdx.x * blockDim.x + threadIdx.x;
  if (e >= E_) return;
  const int s = ei[e];
  const int d = ei[(size_t)E_ + e];
  const float w = dinv[s] * dinv[d];
  const int pos = atomicAdd(&cursor[d], 1);
  edata[pos] = make_int2(s, __float_as_int(w));
}

// ============ dense matmul with fused BN+ReLU on the INPUT ============
// out[n, COUT] = act(in[n, CIN]) @ W[CIN, COUT]
template <int CIN, int COUT, bool FUSE>
__global__ void matmul_bn_relu(const float* __restrict__ in, const float* __restrict__ W,
                               const float* __restrict__ bprev, const float* __restrict__ g,
                               const float* __restrict__ be, const float* __restrict__ rm,
                               const float* __restrict__ rv,
                               float* __restrict__ out, int n) {
  constexpr int ROWS = 256 / COUT;
  __shared__ float sh[ROWS * CIN];
  const int tid = threadIdx.x;
  const int nodeBase = blockIdx.x * ROWS;

  for (int i = tid; i < ROWS * CIN; i += 256) {
    const int nl = i / CIN, k = i % CIN;
    const int node = nodeBase + nl;
    float v = 0.0f;
    if (node < n) {
      v = in[(size_t)node * CIN + k];
      if constexpr (FUSE) {
        const float a = g[k] * rsqrtf(rv[k] + BN_EPS);
        const float s = (bprev[k] - rm[k]) * a + be[k];
        v = v * a + s;
        v = v > 0.0f ? v : 0.0f;
      }
    }
    sh[i] = v;
  }
  __syncthreads();

  const int nl = tid / COUT, c = tid % COUT;
  const int node = nodeBase + nl;
  if (node >= n) return;
  float acc = 0.0f;
#pragma unroll
  for (int k = 0; k < CIN; ++k)
    acc += sh[nl * CIN + k] * W[k * COUT + c];
  out[(size_t)node * COUT + c] = acc;
}

// ============ CSR gather aggregation ============
// agg[node][ch] = h[node][ch]*dinv[node]^2 + sum_e h[src_e][ch]*w_e
// C=64: one wave per node (lane = channel).
// C=32: two nodes per wave (lane>>5 selects node, lane&31 = channel).
template <int C>
__global__ void gather_agg(const float* __restrict__ h, const float* __restrict__ dinv,
                           const int* __restrict__ row_ptr, const int2* __restrict__ edata,
                           float* __restrict__ agg, int n) {
  constexpr int NPW = 64 / C;  // nodes per wave
  const int wave = (int)((blockIdx.x * (long long)blockDim.x + threadIdx.x) >> 6);
  const int lane = threadIdx.x & 63;
  const int node = wave * NPW + (NPW == 1 ? 0 : (lane >> 5));
  const int ch = lane & (C - 1);
  if (node >= n) return;
  const float dn = dinv[node];
  float acc = h[(size_t)node * C + ch] * dn * dn;
  const int beg = row_ptr[node];
  const int end = row_ptr[node + 1];
  int e = beg;
  // unroll-by-2 to keep two gathers in flight
  for (; e + 1 < end; e += 2) {
    const int2 p0 = edata[e];
    const int2 p1 = edata[e + 1];
    const float h0 = h[(size_t)p0.x * C + ch];
    const float h1 = h[(size_t)p1.x * C + ch];
    acc += h0 * __int_as_float(p0.y);
    acc += h1 * __int_as_float(p1.y);
  }
  if (e < end) {
    const int2 p = edata[e];
    acc += h[(size_t)p.x * C + ch] * __int_as_float(p.y);
  }
  agg[(size_t)node * C + ch] = acc;
}

// ============ classifier: act3 -> 32x2 linear -> log_softmax ============
__global__ void classifier(const float* __restrict__ agg,
                           const float* __restrict__ b3, const float* __restrict__ g3,
                           const float* __restrict__ be3, const float* __restrict__ rm3,
                           const float* __restrict__ rv3,
                           const float* __restrict__ Wc, const float* __restrict__ bc,
                           float* __restrict__ out, int n) {
  const int i = blockIdx.x * blockDim.x + threadIdx.x;
  if (i >= n) return;
  float l0 = bc[0], l1 = bc[1];
#pragma unroll
  for (int k = 0; k < 32; ++k) {
    const float a = g3[k] * rsqrtf(rv3[k] + BN_EPS);
    const float s = (b3[k] - rm3[k]) * a + be3[k];
    float v = agg[(size_t)i * 32 + k] * a + s;
    v = v > 0.0f ? v : 0.0f;
    l0 += v * Wc[k * 2 + 0];
    l1 += v * Wc[k * 2 + 1];
  }
  const float m = fmaxf(l0, l1);
  const float lse = m + logf(expf(l0 - m) + expf(l1 - m));
  out[(size_t)i * 2 + 0] = l0 - lse;
  out[(size_t)i * 2 + 1] = l1 - lse;
}

// ============ launch ============
extern "C" void kernel_launch(void* const* d_in, const int* in_sizes, int n_in,
                              void* d_out, int out_size, void* d_ws, size_t ws_size,
                              hipStream_t stream) {
  const float* x  = (const float*)d_in[0];
  const int* ei   = (const int*)d_in[1];   // int32 on device per harness contract
  const float* W1 = (const float*)d_in[2];
  const float* b1 = (const float*)d_in[3];
  const float* g1 = (const float*)d_in[4];
  const float* be1 = (const float*)d_in[5];
  const float* rm1 = (const float*)d_in[6];
  const float* rv1 = (const float*)d_in[7];
  const float* W2 = (const float*)d_in[8];
  const float* b2 = (const float*)d_in[9];
  const float* g2 = (const float*)d_in[10];
  const float* be2 = (const float*)d_in[11];
  const float* rm2 = (const float*)d_in[12];
  const float* rv2 = (const float*)d_in[13];
  const float* W3 = (const float*)d_in[14];
  const float* b3 = (const float*)d_in[15];
  const float* g3 = (const float*)d_in[16];
  const float* be3 = (const float*)d_in[17];
  const float* rm3 = (const float*)d_in[18];
  const float* rv3 = (const float*)d_in[19];
  const float* Wc = (const float*)d_in[20];
  const float* bc = (const float*)d_in[21];

  const int N_ = in_sizes[0] / 8;
  const int E_ = in_sizes[1] / 2;
  const int nbN = (N_ + 255) / 256;          // 256-thread blocks over nodes
  const int nbE = (E_ + 255) / 256;

  auto align = [](size_t v) { return (v + 255) & ~(size_t)255; };
  char* ws = (char*)d_ws;
  size_t off = 0;
  float* dinv   = (float*)(ws + off); off += align((size_t)N_ * 4);
  int* cnt      = (int*)(ws + off);   off += align((size_t)N_ * 4);
  int* row_ptr  = (int*)(ws + off);   off += align(((size_t)N_ + 1) * 4);
  int* cursor   = (int*)(ws + off);   off += align((size_t)N_ * 4);
  int* bsum     = (int*)(ws + off);   off += align((size_t)nbN * 4);
  int2* edata   = (int2*)(ws + off);  off += align((size_t)E_ * 8);
  float* bufA   = (float*)(ws + off); off += align((size_t)N_ * 64 * 4);
  float* bufB   = (float*)(ws + off); off += align((size_t)N_ * 64 * 4);

  // ---- CSR build ----
  zero_int<<<nbN, 256, 0, stream>>>(cnt, N_);
  count_dst<<<nbE, 256, 0, stream>>>(ei, cnt, E_);
  dinv_from_cnt<<<nbN, 256, 0, stream>>>(cnt, dinv, N_);
  scan256<<<nbN, 256, 0, stream>>>(cnt, row_ptr, bsum, N_);
  scan_single<<<1, 512, 0, stream>>>(bsum, nbN);
  add_offsets<<<nbN, 256, 0, stream>>>(row_ptr, bsum, N_, E_);
  copy_int<<<nbN, 256, 0, stream>>>(row_ptr, cursor, N_);
  fill_csr<<<nbE, 256, 0, stream>>>(ei, dinv, cursor, edata, E_);

  // ---- layer 1 ----
  matmul_bn_relu<8, 64, false><<<(N_ + 3) / 4, 256, 0, stream>>>(
      x, W1, nullptr, nullptr, nullptr, nullptr, nullptr, bufA, N_);
  {
    const long long thr = (long long)N_ * 64;     // 1 wave / node
    gather_agg<64><<<(int)((thr + 255) / 256), 256, 0, stream>>>(
        bufA, dinv, row_ptr, edata, bufB, N_);
  }

  // ---- layer 2 ----
  matmul_bn_relu<64, 64, true><<<(N_ + 3) / 4, 256, 0, stream>>>(
      bufB, W2, b1, g1, be1, rm1, rv1, bufA, N_);
  {
    const long long thr = (long long)N_ * 64;
    gather_agg<64><<<(int)((thr + 255) / 256), 256, 0, stream>>>(
        bufA, dinv, row_ptr, edata, bufB, N_);
  }

  // ---- layer 3 ----
  matmul_bn_relu<64, 32, true><<<(N_ + 7) / 8, 256, 0, stream>>>(
      bufB, W3, b2, g2, be2, rm2, rv2, bufA, N_);
  {
    const long long waves = ((long long)N_ + 1) / 2;  // 2 nodes / wave
    const long long thr = waves * 64;
    gather_agg<32><<<(int)((thr + 255) / 256), 256, 0, stream>>>(
        bufA, dinv, row_ptr, edata, bufB, N_);
  }

  // ---- classifier ----
  classifier<<<nbN, 256, 0, stream>>>(bufB, b3, g3, be3, rm3, rv3, Wc, bc,
                                      (float*)d_out, N_);
}

// Round 4
// 412.016 us; speedup vs baseline: 8.6924x; 1.2483x over previous
//
#include <hip/hip_runtime.h>
#include <hip/hip_fp16.h>

#define BN_EPS 1e-5f

// ============ CSR build ============
__global__ void zero_int(int* __restrict__ p, int n) {
  int i = blockIdx.x * blockDim.x + threadIdx.x;
  if (i < n) p[i] = 0;
}

__global__ void count_dst(const int* __restrict__ ei, int* __restrict__ cnt, int E_) {
  int e = blockIdx.x * blockDim.x + threadIdx.x;
  if (e < E_) atomicAdd(&cnt[ei[(size_t)E_ + e]], 1);
}

__global__ void dinv_from_cnt(const int* __restrict__ cnt, float* __restrict__ dinv, int n) {
  int i = blockIdx.x * blockDim.x + threadIdx.x;
  if (i < n) dinv[i] = rsqrtf((float)cnt[i] + 1.0f);
}

__global__ void scan256(const int* __restrict__ in, int* __restrict__ out,
                        int* __restrict__ bsum, int n) {
  __shared__ int sh[256];
  const int i = blockIdx.x * 256 + threadIdx.x;
  const int v = (i < n) ? in[i] : 0;
  sh[threadIdx.x] = v;
  __syncthreads();
  for (int off = 1; off < 256; off <<= 1) {
    int t = (threadIdx.x >= off) ? sh[threadIdx.x - off] : 0;
    __syncthreads();
    sh[threadIdx.x] += t;
    __syncthreads();
  }
  if (i < n) out[i] = sh[threadIdx.x] - v;  // exclusive
  if (threadIdx.x == 255) bsum[blockIdx.x] = sh[255];
}

__global__ void scan_single(int* __restrict__ data, int n) {
  __shared__ int sh[512];
  const int t = threadIdx.x;
  const int v = (t < n) ? data[t] : 0;
  sh[t] = v;
  __syncthreads();
  for (int off = 1; off < 512; off <<= 1) {
    int u = (t >= off) ? sh[t - off] : 0;
    __syncthreads();
    sh[t] += u;
    __syncthreads();
  }
  if (t < n) data[t] = sh[t] - v;  // exclusive
}

__global__ void add_offsets(int* __restrict__ row_ptr, const int* __restrict__ bsum,
                            int n, int E_) {
  const int i = blockIdx.x * 256 + threadIdx.x;
  if (i < n) row_ptr[i] += bsum[blockIdx.x];
  if (blockIdx.x == 0 && threadIdx.x == 0) row_ptr[n] = E_;
}

__global__ void copy_int(const int* __restrict__ src, int* __restrict__ dst, int n) {
  int i = blockIdx.x * blockDim.x + threadIdx.x;
  if (i < n) dst[i] = src[i];
}

__global__ void fill_csr(const int* __restrict__ ei, const float* __restrict__ dinv,
                         int* __restrict__ cursor, int2* __restrict__ edata, int E_) {
  int e = blockIdx.x * blockDim.x + threadIdx.x;
  if (e >= E_) return;
  const int s = ei[e];
  const int d = ei[(size_t)E_ + e];
  const float w = dinv[s] * dinv[d];
  const int pos = atomicAdd(&cursor[d], 1);
  edata[pos] = make_int2(s, __float_as_int(w));
}

// ============ gather on raw x (C=8, fp32): aggx = A_hat x ============
// 1 wave/node; 8 groups x 8 channels; shfl-reduce across groups.
__global__ void gather_x(const float* __restrict__ x, const float* __restrict__ dinv,
                         const int* __restrict__ row_ptr, const int2* __restrict__ edata,
                         float* __restrict__ aggx, int n) {
  const int wid = (int)(((long long)blockIdx.x * blockDim.x + threadIdx.x) >> 6);
  if (wid >= n) return;
  const int lane = threadIdx.x & 63;
  const int ch = lane & 7;
  const int grp = lane >> 3;  // 8 groups
  const int beg = row_ptr[wid], end = row_ptr[wid + 1];
  float acc = 0.0f;
  for (int e = beg + grp; e < end; e += 8) {
    const int2 p = edata[e];
    acc += x[(size_t)p.x * 8 + ch] * __int_as_float(p.y);
  }
  acc += __shfl_xor(acc, 8);
  acc += __shfl_xor(acc, 16);
  acc += __shfl_xor(acc, 32);
  if (grp == 0) {
    const float dn = dinv[wid];
    acc += x[(size_t)wid * 8 + ch] * dn * dn;
    aggx[(size_t)wid * 8 + ch] = acc;
  }
}

// ============ mm1: t1 = act1(aggx @ W1 + b1)  [8 -> 64, fp32 in, fp32 out] ============
__global__ void mm1_act(const float* __restrict__ aggx, const float* __restrict__ W1,
                        const float* __restrict__ b1, const float* __restrict__ g1,
                        const float* __restrict__ be1, const float* __restrict__ rm1,
                        const float* __restrict__ rv1, float* __restrict__ t1, int n) {
  constexpr int ROWS = 8;  // nodes/block; thread computes 2 adjacent outputs
  __shared__ float shin[ROWS * 8];
  __shared__ float shw[8 * 64];
  const int tid = threadIdx.x;
  const int nodeBase = blockIdx.x * ROWS;
  for (int i = tid; i < ROWS * 8; i += 256) {
    const int node = nodeBase + i / 8;
    shin[i] = (node < n) ? aggx[(size_t)node * 8 + (i & 7)] : 0.0f;
  }
  for (int i = tid; i < 8 * 64; i += 256) shw[i] = W1[i];
  __syncthreads();

  const int nl = tid >> 5;          // node-local
  const int c = (tid & 31) * 2;     // output channel pair
  const int node = nodeBase + nl;
  if (node >= n) return;
  float a0 = 0.0f, a1 = 0.0f;
#pragma unroll
  for (int k = 0; k < 8; ++k) {
    const float s = shin[nl * 8 + k];
    const float2 w = *reinterpret_cast<const float2*>(&shw[k * 64 + c]);
    a0 += s * w.x;
    a1 += s * w.y;
  }
  const float s0 = g1[c] * rsqrtf(rv1[c] + BN_EPS);
  const float s1 = g1[c + 1] * rsqrtf(rv1[c + 1] + BN_EPS);
  float v0 = (a0 + b1[c] - rm1[c]) * s0 + be1[c];
  float v1 = (a1 + b1[c + 1] - rm1[c + 1]) * s1 + be1[c + 1];
  v0 = v0 > 0.0f ? v0 : 0.0f;
  v1 = v1 > 0.0f ? v1 : 0.0f;
  *reinterpret_cast<float2*>(&t1[(size_t)node * 64 + c]) = make_float2(v0, v1);
}

// ============ mm2: h2 = t1 @ W2  [64 -> 64, fp32 in, fp16 out] ============
__global__ void mm2(const float* __restrict__ t1, const float* __restrict__ W2,
                    __half* __restrict__ h2, int n) {
  constexpr int ROWS = 8;
  __shared__ float shin[ROWS * 64];
  __shared__ float shw[64 * 64];
  const int tid = threadIdx.x;
  const int nodeBase = blockIdx.x * ROWS;
  for (int i = tid; i < ROWS * 64; i += 256) {
    const int node = nodeBase + (i >> 6);
    shin[i] = (node < n) ? t1[(size_t)node * 64 + (i & 63)] : 0.0f;
  }
  for (int i = tid; i < 64 * 64; i += 256) shw[i] = W2[i];
  __syncthreads();

  const int nl = tid >> 5;
  const int c = (tid & 31) * 2;
  const int node = nodeBase + nl;
  if (node >= n) return;
  float a0 = 0.0f, a1 = 0.0f;
#pragma unroll
  for (int k = 0; k < 64; ++k) {
    const float s = shin[nl * 64 + k];
    const float2 w = *reinterpret_cast<const float2*>(&shw[k * 64 + c]);
    a0 += s * w.x;
    a1 += s * w.y;
  }
  reinterpret_cast<__half2*>(h2)[(size_t)node * 32 + (tid & 31)] = __floats2half2_rn(a0, a1);
}

// ============ gather h2 (C=64, fp16): agg2 = A_hat h2  [fp32 out] ============
// 1 wave/node; lane = (grp 1b | chpair 5b); 2 groups, unrolled x2.
__global__ void gather_h64(const __half* __restrict__ h, const float* __restrict__ dinv,
                           const int* __restrict__ row_ptr, const int2* __restrict__ edata,
                           float* __restrict__ agg, int n) {
  const int wid = (int)(((long long)blockIdx.x * blockDim.x + threadIdx.x) >> 6);
  if (wid >= n) return;
  const int lane = threadIdx.x & 63;
  const int cp = lane & 31;   // channel pair
  const int grp = lane >> 5;  // 2 groups
  const int beg = row_ptr[wid], end = row_ptr[wid + 1];
  const __half2* h2v = reinterpret_cast<const __half2*>(h);
  float ax = 0.0f, ay = 0.0f;
  int e = beg + grp;
  for (; e + 2 < end; e += 4) {
    const int2 p0 = edata[e];
    const int2 p1 = edata[e + 2];
    const float2 v0 = __half22float2(h2v[(size_t)p0.x * 32 + cp]);
    const float2 v1 = __half22float2(h2v[(size_t)p1.x * 32 + cp]);
    const float w0 = __int_as_float(p0.y);
    const float w1 = __int_as_float(p1.y);
    ax += v0.x * w0 + v1.x * w1;
    ay += v0.y * w0 + v1.y * w1;
  }
  if (e < end) {
    const int2 p = edata[e];
    const float2 v = __half22float2(h2v[(size_t)p.x * 32 + cp]);
    const float w = __int_as_float(p.y);
    ax += v.x * w;
    ay += v.y * w;
  }
  ax += __shfl_xor(ax, 32);
  ay += __shfl_xor(ay, 32);
  if (grp == 0) {
    const float dn = dinv[wid];
    const float ss = dn * dn;
    const float2 v = __half22float2(h2v[(size_t)wid * 32 + cp]);
    ax += v.x * ss;
    ay += v.y * ss;
    *reinterpret_cast<float2*>(&agg[(size_t)wid * 64 + cp * 2]) = make_float2(ax, ay);
  }
}

// ============ mm3: h3 = act2(agg2 + b2) @ W3  [64 -> 32, fp32 in, fp16 out] ============
__global__ void mm3_act(const float* __restrict__ agg2, const float* __restrict__ W3,
                        const float* __restrict__ b2, const float* __restrict__ g2,
                        const float* __restrict__ be2, const float* __restrict__ rm2,
                        const float* __restrict__ rv2, __half* __restrict__ h3, int n) {
  constexpr int ROWS = 16;
  __shared__ float shin[ROWS * 64];
  __shared__ float shw[64 * 32];
  const int tid = threadIdx.x;
  const int nodeBase = blockIdx.x * ROWS;
  for (int i = tid; i < ROWS * 64; i += 256) {
    const int node = nodeBase + (i >> 6);
    const int k = i & 63;
    float v = 0.0f;
    if (node < n) {
      const float a = g2[k] * rsqrtf(rv2[k] + BN_EPS);
      const float sft = (b2[k] - rm2[k]) * a + be2[k];
      v = agg2[(size_t)node * 64 + k] * a + sft;
      v = v > 0.0f ? v : 0.0f;
    }
    shin[i] = v;
  }
  for (int i = tid; i < 64 * 32; i += 256) shw[i] = W3[i];
  __syncthreads();

  const int nl = tid >> 4;
  const int c = (tid & 15) * 2;
  const int node = nodeBase + nl;
  if (node >= n) return;
  float a0 = 0.0f, a1 = 0.0f;
#pragma unroll
  for (int k = 0; k < 64; ++k) {
    const float s = shin[nl * 64 + k];
    const float2 w = *reinterpret_cast<const float2*>(&shw[k * 32 + c]);
    a0 += s * w.x;
    a1 += s * w.y;
  }
  reinterpret_cast<__half2*>(h3)[(size_t)node * 16 + (tid & 15)] = __floats2half2_rn(a0, a1);
}

// ============ gather h3 (C=32, fp16) + BN3 + ReLU + 32x2 linear + log_softmax ============
// 1 wave/node; lane = (grp 2b | chpair 4b); 4 groups.
__global__ void gather_cls(const __half* __restrict__ h, const float* __restrict__ dinv,
                           const int* __restrict__ row_ptr, const int2* __restrict__ edata,
                           const float* __restrict__ b3, const float* __restrict__ g3,
                           const float* __restrict__ be3, const float* __restrict__ rm3,
                           const float* __restrict__ rv3, const float* __restrict__ Wc,
                           const float* __restrict__ bc, float* __restrict__ out, int n) {
  const int wid = (int)(((long long)blockIdx.x * blockDim.x + threadIdx.x) >> 6);
  if (wid >= n) return;
  const int lane = threadIdx.x & 63;
  const int cp = lane & 15;   // channel pair (32 channels)
  const int grp = lane >> 4;  // 4 groups
  const int beg = row_ptr[wid], end = row_ptr[wid + 1];
  const __half2* h2v = reinterpret_cast<const __half2*>(h);
  float ax = 0.0f, ay = 0.0f;
  for (int e = beg + grp; e < end; e += 4) {
    const int2 p = edata[e];
    const float2 v = __half22float2(h2v[(size_t)p.x * 16 + cp]);
    const float w = __int_as_float(p.y);
    ax += v.x * w;
    ay += v.y * w;
  }
  ax += __shfl_xor(ax, 16);
  ay += __shfl_xor(ay, 16);
  ax += __shfl_xor(ax, 32);
  ay += __shfl_xor(ay, 32);
  if (grp != 0) return;
  // lanes 0..15: self term + BN + ReLU + partial logits
  const float dn = dinv[wid];
  const float ss = dn * dn;
  const float2 sv = __half22float2(h2v[(size_t)wid * 16 + cp]);
  ax += sv.x * ss;
  ay += sv.y * ss;
  const int c0 = cp * 2, c1 = cp * 2 + 1;
  const float s0 = g3[c0] * rsqrtf(rv3[c0] + BN_EPS);
  const float s1 = g3[c1] * rsqrtf(rv3[c1] + BN_EPS);
  float v0 = (ax + b3[c0] - rm3[c0]) * s0 + be3[c0];
  float v1 = (ay + b3[c1] - rm3[c1]) * s1 + be3[c1];
  v0 = v0 > 0.0f ? v0 : 0.0f;
  v1 = v1 > 0.0f ? v1 : 0.0f;
  float l0 = v0 * Wc[c0 * 2 + 0] + v1 * Wc[c1 * 2 + 0];
  float l1 = v0 * Wc[c0 * 2 + 1] + v1 * Wc[c1 * 2 + 1];
  l0 += __shfl_xor(l0, 1);
  l1 += __shfl_xor(l1, 1);
  l0 += __shfl_xor(l0, 2);
  l1 += __shfl_xor(l1, 2);
  l0 += __shfl_xor(l0, 4);
  l1 += __shfl_xor(l1, 4);
  l0 += __shfl_xor(l0, 8);
  l1 += __shfl_xor(l1, 8);
  if (lane == 0) {
    l0 += bc[0];
    l1 += bc[1];
    const float m = fmaxf(l0, l1);
    const float lse = m + logf(expf(l0 - m) + expf(l1 - m));
    *reinterpret_cast<float2*>(&out[(size_t)wid * 2]) = make_float2(l0 - lse, l1 - lse);
  }
}

// ============ launch ============
extern "C" void kernel_launch(void* const* d_in, const int* in_sizes, int n_in,
                              void* d_out, int out_size, void* d_ws, size_t ws_size,
                              hipStream_t stream) {
  const float* x  = (const float*)d_in[0];
  const int* ei   = (const int*)d_in[1];   // int32 on device per harness contract
  const float* W1 = (const float*)d_in[2];
  const float* b1 = (const float*)d_in[3];
  const float* g1 = (const float*)d_in[4];
  const float* be1 = (const float*)d_in[5];
  const float* rm1 = (const float*)d_in[6];
  const float* rv1 = (const float*)d_in[7];
  const float* W2 = (const float*)d_in[8];
  const float* b2 = (const float*)d_in[9];
  const float* g2 = (const float*)d_in[10];
  const float* be2 = (const float*)d_in[11];
  const float* rm2 = (const float*)d_in[12];
  const float* rv2 = (const float*)d_in[13];
  const float* W3 = (const float*)d_in[14];
  const float* b3 = (const float*)d_in[15];
  const float* g3 = (const float*)d_in[16];
  const float* be3 = (const float*)d_in[17];
  const float* rm3 = (const float*)d_in[18];
  const float* rv3 = (const float*)d_in[19];
  const float* Wc = (const float*)d_in[20];
  const float* bc = (const float*)d_in[21];

  const int N_ = in_sizes[0] / 8;
  const int E_ = in_sizes[1] / 2;
  const int nbN = (N_ + 255) / 256;
  const int nbE = (E_ + 255) / 256;
  const int nbW = (N_ + 3) / 4;  // 1 wave/node, 256-thread blocks

  auto align = [](size_t v) { return (v + 255) & ~(size_t)255; };
  char* ws = (char*)d_ws;
  size_t off = 0;
  float* dinv   = (float*)(ws + off); off += align((size_t)N_ * 4);
  int* cnt      = (int*)(ws + off);   off += align((size_t)N_ * 4);
  int* row_ptr  = (int*)(ws + off);   off += align(((size_t)N_ + 1) * 4);
  int* cursor   = (int*)(ws + off);   off += align((size_t)N_ * 4);
  int* bsum     = (int*)(ws + off);   off += align((size_t)nbN * 4);
  int2* edata   = (int2*)(ws + off);  off += align((size_t)E_ * 8);
  float* aggx   = (float*)(ws + off); off += align((size_t)N_ * 8 * 4);
  float* bufA   = (float*)(ws + off); off += align((size_t)N_ * 64 * 4);  // t1, later agg2
  __half* bufH  = (__half*)(ws + off); off += align((size_t)N_ * 64 * 2); // h2, later h3

  // ---- CSR build ----
  zero_int<<<nbN, 256, 0, stream>>>(cnt, N_);
  count_dst<<<nbE, 256, 0, stream>>>(ei, cnt, E_);
  dinv_from_cnt<<<nbN, 256, 0, stream>>>(cnt, dinv, N_);
  scan256<<<nbN, 256, 0, stream>>>(cnt, row_ptr, bsum, N_);
  scan_single<<<1, 512, 0, stream>>>(bsum, nbN);
  add_offsets<<<nbN, 256, 0, stream>>>(row_ptr, bsum, N_, E_);
  copy_int<<<nbN, 256, 0, stream>>>(row_ptr, cursor, N_);
  fill_csr<<<nbE, 256, 0, stream>>>(ei, dinv, cursor, edata, E_);

  // ---- layer 1: aggregate x (C=8), then fused matmul+BN1+ReLU ----
  gather_x<<<nbW, 256, 0, stream>>>(x, dinv, row_ptr, edata, aggx, N_);
  mm1_act<<<(N_ + 7) / 8, 256, 0, stream>>>(aggx, W1, b1, g1, be1, rm1, rv1, bufA, N_);

  // ---- layer 2: h2 = t1 @ W2 (fp16), gather (C=64 fp16) -> agg2 fp32 ----
  mm2<<<(N_ + 7) / 8, 256, 0, stream>>>(bufA, W2, bufH, N_);
  gather_h64<<<nbW, 256, 0, stream>>>(bufH, dinv, row_ptr, edata, bufA, N_);

  // ---- layer 3: h3 = act2(agg2) @ W3 (fp16), gather (C=32) + classifier ----
  mm3_act<<<(N_ + 15) / 16, 256, 0, stream>>>(bufA, W3, b2, g2, be2, rm2, rv2, bufH, N_);
  gather_cls<<<nbW, 256, 0, stream>>>(bufH, dinv, row_ptr, edata,
                                      b3, g3, be3, rm3, rv3, Wc, bc,
                                      (float*)d_out, N_);
}

// Round 5
// 357.585 us; speedup vs baseline: 10.0155x; 1.1522x over previous
//
#include <hip/hip_runtime.h>
#include <hip/hip_fp16.h>

#define BN_EPS 1e-5f
#define BCAP 5120   // bucket capacity; mean 4096 edges/bucket (E=1.6M, 256-node buckets), sigma~64 -> +16 sigma margin

// ============ CSR build (bucketed two-phase sort; all global writes ~coalesced) ============
__global__ void zero_int(int* __restrict__ p, int n) {
  int i = blockIdx.x * blockDim.x + threadIdx.x;
  if (i < n) p[i] = 0;
}

__global__ void count_dst(const int* __restrict__ ei, int* __restrict__ cnt, int E_) {
  int e = blockIdx.x * blockDim.x + threadIdx.x;
  if (e < E_) atomicAdd(&cnt[ei[(size_t)E_ + e]], 1);
}

__global__ void dinv_from_cnt(const int* __restrict__ cnt, float* __restrict__ dinv, int n) {
  int i = blockIdx.x * blockDim.x + threadIdx.x;
  if (i < n) dinv[i] = rsqrtf((float)cnt[i] + 1.0f);
}

// Phase 1: partition edges into per-bucket regions (bucket = dst>>8).
// grid = ceil(E/4096), block = 256. Writes (src,dst) in ~contiguous runs.
__global__ void p1_partition(const int* __restrict__ ei, int2* __restrict__ bucketbuf,
                             int* __restrict__ bcur, int E_, int NB) {
  __shared__ int hist[512];
  __shared__ int bbase[512];
  const int tid = threadIdx.x;
  const int e0 = blockIdx.x * 4096;
  const int ecount = min(4096, E_ - e0);
  for (int i = tid; i < NB; i += 256) hist[i] = 0;
  __syncthreads();
  for (int i = tid; i < ecount; i += 256) {
    const int d = ei[(size_t)E_ + e0 + i];
    atomicAdd(&hist[d >> 8], 1);
  }
  __syncthreads();
  for (int i = tid; i < NB; i += 256) {
    const int c = hist[i];
    bbase[i] = c ? atomicAdd(&bcur[i], c) : 0;
    hist[i] = 0;  // reuse as local cursor
  }
  __syncthreads();
  for (int i = tid; i < ecount; i += 256) {
    const int s = ei[e0 + i];
    const int d = ei[(size_t)E_ + e0 + i];
    const int b = d >> 8;
    const int slot = bbase[b] + atomicAdd(&hist[b], 1);
    bucketbuf[(size_t)b * BCAP + slot] = make_int2(s, d);
  }
}

// exclusive scan over NB bucket counts (NB <= 512); also sets row_ptr[N]=E.
__global__ void scan_buckets(const int* __restrict__ bcur, int* __restrict__ gbase,
                             int NB, int E_, int* __restrict__ row_ptr, int N_) {
  __shared__ int sh[512];
  const int t = threadIdx.x;
  const int v = (t < NB) ? bcur[t] : 0;
  sh[t] = v;
  __syncthreads();
  for (int off = 1; off < 512; off <<= 1) {
    int u = (t >= off) ? sh[t - off] : 0;
    __syncthreads();
    sh[t] += u;
    __syncthreads();
  }
  if (t < NB) gbase[t] = sh[t] - v;  // exclusive
  if (t == 0) { gbase[NB] = E_; row_ptr[N_] = E_; }
}

// Phase 2: per-bucket counting sort in LDS; coalesced final writes; emits row_ptr.
// grid = NB, block = 256.
__global__ void p2_sort(const int2* __restrict__ bucketbuf, const float* __restrict__ dinv,
                        const int* __restrict__ gbase, int2* __restrict__ edata,
                        int* __restrict__ row_ptr, int N_) {
  __shared__ int cntl[256];
  __shared__ int scn[256];
  __shared__ int cur[256];
  __shared__ int2 sbuf[BCAP];
  const int b = blockIdx.x;
  const int tid = threadIdx.x;
  const int base = gbase[b];
  const int m = gbase[b + 1] - base;
  const int2* srcp = bucketbuf + (size_t)b * BCAP;
  cntl[tid] = 0;
  __syncthreads();
  for (int i = tid; i < m; i += 256) atomicAdd(&cntl[srcp[i].y & 255], 1);
  __syncthreads();
  const int v = cntl[tid];
  scn[tid] = v;
  __syncthreads();
  for (int off = 1; off < 256; off <<= 1) {
    int u = (tid >= off) ? scn[tid - off] : 0;
    __syncthreads();
    scn[tid] += u;
    __syncthreads();
  }
  const int excl = scn[tid] - v;
  cur[tid] = excl;
  const int node = (b << 8) + tid;
  if (node < N_) row_ptr[node] = base + excl;
  __syncthreads();
  for (int i = tid; i < m; i += 256) {
    const int2 sd = srcp[i];
    const float w = dinv[sd.x] * dinv[sd.y];
    const int slot = atomicAdd(&cur[sd.y & 255], 1);
    sbuf[slot] = make_int2(sd.x, __float_as_int(w));
  }
  __syncthreads();
  for (int i = tid; i < m; i += 256) edata[(size_t)base + i] = sbuf[i];
}

// ============ gather on raw x (C=8, fp32): aggx = A_hat x ============
__global__ void gather_x(const float* __restrict__ x, const float* __restrict__ dinv,
                         const int* __restrict__ row_ptr, const int2* __restrict__ edata,
                         float* __restrict__ aggx, int n) {
  const int wid = (int)(((long long)blockIdx.x * blockDim.x + threadIdx.x) >> 6);
  if (wid >= n) return;
  const int lane = threadIdx.x & 63;
  const int ch = lane & 7;
  const int grp = lane >> 3;  // 8 groups
  const int beg = row_ptr[wid], end = row_ptr[wid + 1];
  float acc = 0.0f;
  for (int e = beg + grp; e < end; e += 8) {
    const int2 p = edata[e];
    acc += x[(size_t)p.x * 8 + ch] * __int_as_float(p.y);
  }
  acc += __shfl_xor(acc, 8);
  acc += __shfl_xor(acc, 16);
  acc += __shfl_xor(acc, 32);
  if (grp == 0) {
    const float dn = dinv[wid];
    acc += x[(size_t)wid * 8 + ch] * dn * dn;
    aggx[(size_t)wid * 8 + ch] = acc;
  }
}

// ============ mm1: t1 = act1(aggx @ W1 + b1)  [8 -> 64] ============
__global__ void mm1_act(const float* __restrict__ aggx, const float* __restrict__ W1,
                        const float* __restrict__ b1, const float* __restrict__ g1,
                        const float* __restrict__ be1, const float* __restrict__ rm1,
                        const float* __restrict__ rv1, float* __restrict__ t1, int n) {
  constexpr int ROWS = 8;
  __shared__ float shin[ROWS * 8];
  __shared__ float shw[8 * 64];
  const int tid = threadIdx.x;
  const int nodeBase = blockIdx.x * ROWS;
  for (int i = tid; i < ROWS * 8; i += 256) {
    const int node = nodeBase + i / 8;
    shin[i] = (node < n) ? aggx[(size_t)node * 8 + (i & 7)] : 0.0f;
  }
  for (int i = tid; i < 8 * 64; i += 256) shw[i] = W1[i];
  __syncthreads();

  const int nl = tid >> 5;
  const int c = (tid & 31) * 2;
  const int node = nodeBase + nl;
  if (node >= n) return;
  float a0 = 0.0f, a1 = 0.0f;
#pragma unroll
  for (int k = 0; k < 8; ++k) {
    const float s = shin[nl * 8 + k];
    const float2 w = *reinterpret_cast<const float2*>(&shw[k * 64 + c]);
    a0 += s * w.x;
    a1 += s * w.y;
  }
  const float s0 = g1[c] * rsqrtf(rv1[c] + BN_EPS);
  const float s1 = g1[c + 1] * rsqrtf(rv1[c + 1] + BN_EPS);
  float v0 = (a0 + b1[c] - rm1[c]) * s0 + be1[c];
  float v1 = (a1 + b1[c + 1] - rm1[c + 1]) * s1 + be1[c + 1];
  v0 = v0 > 0.0f ? v0 : 0.0f;
  v1 = v1 > 0.0f ? v1 : 0.0f;
  *reinterpret_cast<float2*>(&t1[(size_t)node * 64 + c]) = make_float2(v0, v1);
}

// ============ mm2: h2 = t1 @ W2  [64 -> 64, fp16 out] ============
__global__ void mm2(const float* __restrict__ t1, const float* __restrict__ W2,
                    __half* __restrict__ h2, int n) {
  constexpr int ROWS = 8;
  __shared__ float shin[ROWS * 64];
  __shared__ float shw[64 * 64];
  const int tid = threadIdx.x;
  const int nodeBase = blockIdx.x * ROWS;
  for (int i = tid; i < ROWS * 64; i += 256) {
    const int node = nodeBase + (i >> 6);
    shin[i] = (node < n) ? t1[(size_t)node * 64 + (i & 63)] : 0.0f;
  }
  for (int i = tid; i < 64 * 64; i += 256) shw[i] = W2[i];
  __syncthreads();

  const int nl = tid >> 5;
  const int c = (tid & 31) * 2;
  const int node = nodeBase + nl;
  if (node >= n) return;
  float a0 = 0.0f, a1 = 0.0f;
#pragma unroll
  for (int k = 0; k < 64; ++k) {
    const float s = shin[nl * 64 + k];
    const float2 w = *reinterpret_cast<const float2*>(&shw[k * 64 + c]);
    a0 += s * w.x;
    a1 += s * w.y;
  }
  reinterpret_cast<__half2*>(h2)[(size_t)node * 32 + (tid & 31)] = __floats2half2_rn(a0, a1);
}

// ============ gather h2 (C=64, fp16): agg2 = A_hat h2 ============
__global__ void gather_h64(const __half* __restrict__ h, const float* __restrict__ dinv,
                           const int* __restrict__ row_ptr, const int2* __restrict__ edata,
                           float* __restrict__ agg, int n) {
  const int wid = (int)(((long long)blockIdx.x * blockDim.x + threadIdx.x) >> 6);
  if (wid >= n) return;
  const int lane = threadIdx.x & 63;
  const int cp = lane & 31;
  const int grp = lane >> 5;  // 2 groups
  const int beg = row_ptr[wid], end = row_ptr[wid + 1];
  const __half2* h2v = reinterpret_cast<const __half2*>(h);
  float ax = 0.0f, ay = 0.0f;
  int e = beg + grp;
  for (; e + 2 < end; e += 4) {
    const int2 p0 = edata[e];
    const int2 p1 = edata[e + 2];
    const float2 v0 = __half22float2(h2v[(size_t)p0.x * 32 + cp]);
    const float2 v1 = __half22float2(h2v[(size_t)p1.x * 32 + cp]);
    const float w0 = __int_as_float(p0.y);
    const float w1 = __int_as_float(p1.y);
    ax += v0.x * w0 + v1.x * w1;
    ay += v0.y * w0 + v1.y * w1;
  }
  if (e < end) {
    const int2 p = edata[e];
    const float2 v = __half22float2(h2v[(size_t)p.x * 32 + cp]);
    const float w = __int_as_float(p.y);
    ax += v.x * w;
    ay += v.y * w;
  }
  ax += __shfl_xor(ax, 32);
  ay += __shfl_xor(ay, 32);
  if (grp == 0) {
    const float dn = dinv[wid];
    const float ss = dn * dn;
    const float2 v = __half22float2(h2v[(size_t)wid * 32 + cp]);
    ax += v.x * ss;
    ay += v.y * ss;
    *reinterpret_cast<float2*>(&agg[(size_t)wid * 64 + cp * 2]) = make_float2(ax, ay);
  }
}

// ============ mm3: h3 = act2(agg2) @ W3  [64 -> 32, fp16 out] ============
__global__ void mm3_act(const float* __restrict__ agg2, const float* __restrict__ W3,
                        const float* __restrict__ b2, const float* __restrict__ g2,
                        const float* __restrict__ be2, const float* __restrict__ rm2,
                        const float* __restrict__ rv2, __half* __restrict__ h3, int n) {
  constexpr int ROWS = 16;
  __shared__ float shin[ROWS * 64];
  __shared__ float shw[64 * 32];
  const int tid = threadIdx.x;
  const int nodeBase = blockIdx.x * ROWS;
  for (int i = tid; i < ROWS * 64; i += 256) {
    const int node = nodeBase + (i >> 6);
    const int k = i & 63;
    float v = 0.0f;
    if (node < n) {
      const float a = g2[k] * rsqrtf(rv2[k] + BN_EPS);
      const float sft = (b2[k] - rm2[k]) * a + be2[k];
      v = agg2[(size_t)node * 64 + k] * a + sft;
      v = v > 0.0f ? v : 0.0f;
    }
    shin[i] = v;
  }
  for (int i = tid; i < 64 * 32; i += 256) shw[i] = W3[i];
  __syncthreads();

  const int nl = tid >> 4;
  const int c = (tid & 15) * 2;
  const int node = nodeBase + nl;
  if (node >= n) return;
  float a0 = 0.0f, a1 = 0.0f;
#pragma unroll
  for (int k = 0; k < 64; ++k) {
    const float s = shin[nl * 64 + k];
    const float2 w = *reinterpret_cast<const float2*>(&shw[k * 32 + c]);
    a0 += s * w.x;
    a1 += s * w.y;
  }
  reinterpret_cast<__half2*>(h3)[(size_t)node * 16 + (tid & 15)] = __floats2half2_rn(a0, a1);
}

// ============ gather h3 (C=32, fp16) + BN3 + ReLU + 32x2 linear + log_softmax ============
__global__ void gather_cls(const __half* __restrict__ h, const float* __restrict__ dinv,
                           const int* __restrict__ row_ptr, const int2* __restrict__ edata,
                           const float* __restrict__ b3, const float* __restrict__ g3,
                           const float* __restrict__ be3, const float* __restrict__ rm3,
                           const float* __restrict__ rv3, const float* __restrict__ Wc,
                           const float* __restrict__ bc, float* __restrict__ out, int n) {
  const int wid = (int)(((long long)blockIdx.x * blockDim.x + threadIdx.x) >> 6);
  if (wid >= n) return;
  const int lane = threadIdx.x & 63;
  const int cp = lane & 15;
  const int grp = lane >> 4;  // 4 groups
  const int beg = row_ptr[wid], end = row_ptr[wid + 1];
  const __half2* h2v = reinterpret_cast<const __half2*>(h);
  float ax = 0.0f, ay = 0.0f;
  for (int e = beg + grp; e < end; e += 4) {
    const int2 p = edata[e];
    const float2 v = __half22float2(h2v[(size_t)p.x * 16 + cp]);
    const float w = __int_as_float(p.y);
    ax += v.x * w;
    ay += v.y * w;
  }
  ax += __shfl_xor(ax, 16);
  ay += __shfl_xor(ay, 16);
  ax += __shfl_xor(ax, 32);
  ay += __shfl_xor(ay, 32);
  if (grp != 0) return;
  const float dn = dinv[wid];
  const float ss = dn * dn;
  const float2 sv = __half22float2(h2v[(size_t)wid * 16 + cp]);
  ax += sv.x * ss;
  ay += sv.y * ss;
  const int c0 = cp * 2, c1 = cp * 2 + 1;
  const float s0 = g3[c0] * rsqrtf(rv3[c0] + BN_EPS);
  const float s1 = g3[c1] * rsqrtf(rv3[c1] + BN_EPS);
  float v0 = (ax + b3[c0] - rm3[c0]) * s0 + be3[c0];
  float v1 = (ay + b3[c1] - rm3[c1]) * s1 + be3[c1];
  v0 = v0 > 0.0f ? v0 : 0.0f;
  v1 = v1 > 0.0f ? v1 : 0.0f;
  float l0 = v0 * Wc[c0 * 2 + 0] + v1 * Wc[c1 * 2 + 0];
  float l1 = v0 * Wc[c0 * 2 + 1] + v1 * Wc[c1 * 2 + 1];
  l0 += __shfl_xor(l0, 1);
  l1 += __shfl_xor(l1, 1);
  l0 += __shfl_xor(l0, 2);
  l1 += __shfl_xor(l1, 2);
  l0 += __shfl_xor(l0, 4);
  l1 += __shfl_xor(l1, 4);
  l0 += __shfl_xor(l0, 8);
  l1 += __shfl_xor(l1, 8);
  if (lane == 0) {
    l0 += bc[0];
    l1 += bc[1];
    const float m = fmaxf(l0, l1);
    const float lse = m + logf(expf(l0 - m) + expf(l1 - m));
    *reinterpret_cast<float2*>(&out[(size_t)wid * 2]) = make_float2(l0 - lse, l1 - lse);
  }
}

// ============ launch ============
extern "C" void kernel_launch(void* const* d_in, const int* in_sizes, int n_in,
                              void* d_out, int out_size, void* d_ws, size_t ws_size,
                              hipStream_t stream) {
  const float* x  = (const float*)d_in[0];
  const int* ei   = (const int*)d_in[1];   // int32 on device per harness contract
  const float* W1 = (const float*)d_in[2];
  const float* b1 = (const float*)d_in[3];
  const float* g1 = (const float*)d_in[4];
  const float* be1 = (const float*)d_in[5];
  const float* rm1 = (const float*)d_in[6];
  const float* rv1 = (const float*)d_in[7];
  const float* W2 = (const float*)d_in[8];
  const float* b2 = (const float*)d_in[9];
  const float* g2 = (const float*)d_in[10];
  const float* be2 = (const float*)d_in[11];
  const float* rm2 = (const float*)d_in[12];
  const float* rv2 = (const float*)d_in[13];
  const float* W3 = (const float*)d_in[14];
  const float* b3 = (const float*)d_in[15];
  const float* g3 = (const float*)d_in[16];
  const float* be3 = (const float*)d_in[17];
  const float* rm3 = (const float*)d_in[18];
  const float* rv3 = (const float*)d_in[19];
  const float* Wc = (const float*)d_in[20];
  const float* bc = (const float*)d_in[21];

  const int N_ = in_sizes[0] / 8;
  const int E_ = in_sizes[1] / 2;
  const int NB = (N_ + 255) >> 8;          // 256-node buckets
  const int nbE = (E_ + 255) / 256;
  const int nbW = (N_ + 3) / 4;            // 1 wave/node, 256-thread blocks

  auto align = [](size_t v) { return (v + 255) & ~(size_t)255; };
  char* ws = (char*)d_ws;
  size_t off = 0;
  float* dinv   = (float*)(ws + off); off += align((size_t)N_ * 4);
  int* cnt      = (int*)(ws + off);                                  // cnt[N_] then bcur[NB], zeroed together
  int* bcur     = cnt + N_;           off += align(((size_t)N_ + NB) * 4);
  int* row_ptr  = (int*)(ws + off);   off += align(((size_t)N_ + 1) * 4);
  int* gbase    = (int*)(ws + off);   off += align(520 * 4);
  int2* edata   = (int2*)(ws + off);  off += align((size_t)E_ * 8);
  float* aggx   = (float*)(ws + off); off += align((size_t)N_ * 8 * 4);
  float* bufA   = (float*)(ws + off); off += align((size_t)N_ * 64 * 4);   // bucketbuf, then t1, then agg2
  __half* bufH  = (__half*)(ws + off); off += align((size_t)N_ * 64 * 2);  // h2, then h3
  int2* bucketbuf = (int2*)bufA;  // NB*BCAP*8B = 16.0MB <= 25.6MB, dead before mm1 writes t1

  // ---- degrees + dinv ----
  zero_int<<<(N_ + NB + 255) / 256, 256, 0, stream>>>(cnt, N_ + NB);
  count_dst<<<nbE, 256, 0, stream>>>(ei, cnt, E_);
  dinv_from_cnt<<<(N_ + 255) / 256, 256, 0, stream>>>(cnt, dinv, N_);

  // ---- bucketed CSR build ----
  p1_partition<<<(E_ + 4095) / 4096, 256, 0, stream>>>(ei, bucketbuf, bcur, E_, NB);
  scan_buckets<<<1, 512, 0, stream>>>(bcur, gbase, NB, E_, row_ptr, N_);
  p2_sort<<<NB, 256, 0, stream>>>(bucketbuf, dinv, gbase, edata, row_ptr, N_);

  // ---- layer 1: aggregate x (C=8), then fused matmul+BN1+ReLU ----
  gather_x<<<nbW, 256, 0, stream>>>(x, dinv, row_ptr, edata, aggx, N_);
  mm1_act<<<(N_ + 7) / 8, 256, 0, stream>>>(aggx, W1, b1, g1, be1, rm1, rv1, bufA, N_);

  // ---- layer 2: h2 = t1 @ W2 (fp16), gather (C=64 fp16) -> agg2 fp32 ----
  mm2<<<(N_ + 7) / 8, 256, 0, stream>>>(bufA, W2, bufH, N_);
  gather_h64<<<nbW, 256, 0, stream>>>(bufH, dinv, row_ptr, edata, bufA, N_);

  // ---- layer 3: h3 = act2(agg2) @ W3 (fp16), gather (C=32) + classifier ----
  mm3_act<<<(N_ + 15) / 16, 256, 0, stream>>>(bufA, W3, b2, g2, be2, rm2, rv2, bufH, N_);
  gather_cls<<<nbW, 256, 0, stream>>>(bufH, dinv, row_ptr, edata,
                                      b3, g3, be3, rm3, rv3, Wc, bc,
                                      (float*)d_out, N_);
}

// Round 6
// 280.886 us; speedup vs baseline: 12.7504x; 1.2731x over previous
//
#include <hip/hip_runtime.h>
#include <hip/hip_fp16.h>

#define BN_EPS 1e-5f
#define BCAP 5120   // bucket capacity; mean 4096 edges/bucket, large safety margin

// ============ CSR build (bucketed two-phase sort; degrees fall out of phase 2) ============
__global__ void zero_int(int* __restrict__ p, int n) {
  int i = blockIdx.x * blockDim.x + threadIdx.x;
  if (i < n) p[i] = 0;
}

// Phase 1: partition edges into per-bucket regions (bucket = dst>>8).
__global__ void p1_partition(const int* __restrict__ ei, int2* __restrict__ bucketbuf,
                             int* __restrict__ bcur, int E_, int NB) {
  __shared__ int hist[512];
  __shared__ int bbase[512];
  const int tid = threadIdx.x;
  const int e0 = blockIdx.x * 4096;
  const int ecount = min(4096, E_ - e0);
  for (int i = tid; i < NB; i += 256) hist[i] = 0;
  __syncthreads();
  for (int i = tid; i < ecount; i += 256) {
    const int d = ei[(size_t)E_ + e0 + i];
    atomicAdd(&hist[d >> 8], 1);
  }
  __syncthreads();
  for (int i = tid; i < NB; i += 256) {
    const int c = hist[i];
    bbase[i] = c ? atomicAdd(&bcur[i], c) : 0;
    hist[i] = 0;  // reuse as local cursor
  }
  __syncthreads();
  for (int i = tid; i < ecount; i += 256) {
    const int s = ei[e0 + i];
    const int d = ei[(size_t)E_ + e0 + i];
    const int b = d >> 8;
    const int slot = bbase[b] + atomicAdd(&hist[b], 1);
    bucketbuf[(size_t)b * BCAP + slot] = make_int2(s, d);
  }
}

// exclusive scan over NB bucket counts (NB <= 512); also sets row_ptr[N]=E.
__global__ void scan_buckets(const int* __restrict__ bcur, int* __restrict__ gbase,
                             int NB, int E_, int* __restrict__ row_ptr, int N_) {
  __shared__ int sh[512];
  const int t = threadIdx.x;
  const int v = (t < NB) ? bcur[t] : 0;
  sh[t] = v;
  __syncthreads();
  for (int off = 1; off < 512; off <<= 1) {
    int u = (t >= off) ? sh[t - off] : 0;
    __syncthreads();
    sh[t] += u;
    __syncthreads();
  }
  if (t < NB) gbase[t] = sh[t] - v;  // exclusive
  if (t == 0) { gbase[NB] = E_; row_ptr[N_] = E_; }
}

// Phase 2: per-bucket counting sort in LDS; emits row_ptr AND dinv (deg = local hist + 1).
// edata stores ONLY src (norm factorized out: agg = dinv[dst]*(sum h'[src] + h'[dst])).
__global__ void p2_sort(const int2* __restrict__ bucketbuf, const int* __restrict__ gbase,
                        int* __restrict__ edata, int* __restrict__ row_ptr,
                        float* __restrict__ dinv, int N_) {
  __shared__ int cntl[256];
  __shared__ int scn[256];
  __shared__ int cur[256];
  __shared__ int sbuf[BCAP];
  const int b = blockIdx.x;
  const int tid = threadIdx.x;
  const int base = gbase[b];
  const int m = gbase[b + 1] - base;
  const int2* srcp = bucketbuf + (size_t)b * BCAP;
  cntl[tid] = 0;
  __syncthreads();
  for (int i = tid; i < m; i += 256) atomicAdd(&cntl[srcp[i].y & 255], 1);
  __syncthreads();
  const int v = cntl[tid];
  scn[tid] = v;
  __syncthreads();
  for (int off = 1; off < 256; off <<= 1) {
    int u = (tid >= off) ? scn[tid - off] : 0;
    __syncthreads();
    scn[tid] += u;
    __syncthreads();
  }
  const int excl = scn[tid] - v;
  cur[tid] = excl;
  const int node = (b << 8) + tid;
  if (node < N_) {
    row_ptr[node] = base + excl;
    dinv[node] = rsqrtf((float)v + 1.0f);   // deg = in-degree + self-loop
  }
  __syncthreads();
  for (int i = tid; i < m; i += 256) {
    const int2 sd = srcp[i];
    const int slot = atomicAdd(&cur[sd.y & 255], 1);
    sbuf[slot] = sd.x;
  }
  __syncthreads();
  for (int i = tid; i < m; i += 256) edata[(size_t)base + i] = sbuf[i];
}

// ============ x' = x * dinv (per node) ============
__global__ void scale_x(const float* __restrict__ x, const float* __restrict__ dinv,
                        float* __restrict__ xs, int n) {
  const int i = blockIdx.x * blockDim.x + threadIdx.x;
  if (i < (n << 3)) xs[i] = x[i] * dinv[i >> 3];
}

// ============ gather on x' (C=8): aggx = dinv * (sum xs[src] + xs[self]) ============
__global__ void gather_x(const float* __restrict__ xs, const float* __restrict__ dinv,
                         const int* __restrict__ row_ptr, const int* __restrict__ edata,
                         float* __restrict__ aggx, int n) {
  const int wid = (int)(((long long)blockIdx.x * blockDim.x + threadIdx.x) >> 6);
  if (wid >= n) return;
  const int lane = threadIdx.x & 63;
  const int ch = lane & 7;
  const int grp = lane >> 3;  // 8 groups
  const int beg = row_ptr[wid], end = row_ptr[wid + 1];
  float acc = 0.0f;
  for (int e = beg + grp; e < end; e += 8)
    acc += xs[(size_t)edata[e] * 8 + ch];
  acc += __shfl_xor(acc, 8);
  acc += __shfl_xor(acc, 16);
  acc += __shfl_xor(acc, 32);
  if (grp == 0) {
    acc += xs[(size_t)wid * 8 + ch];
    aggx[(size_t)wid * 8 + ch] = acc * dinv[wid];
  }
}

// ============ mm1: t1 = act1(aggx @ W1 + b1)  [8 -> 64] ============
__global__ void mm1_act(const float* __restrict__ aggx, const float* __restrict__ W1,
                        const float* __restrict__ b1, const float* __restrict__ g1,
                        const float* __restrict__ be1, const float* __restrict__ rm1,
                        const float* __restrict__ rv1, float* __restrict__ t1, int n) {
  constexpr int ROWS = 8;
  __shared__ float shin[ROWS * 8];
  __shared__ float shw[8 * 64];
  const int tid = threadIdx.x;
  const int nodeBase = blockIdx.x * ROWS;
  for (int i = tid; i < ROWS * 8; i += 256) {
    const int node = nodeBase + i / 8;
    shin[i] = (node < n) ? aggx[(size_t)node * 8 + (i & 7)] : 0.0f;
  }
  for (int i = tid; i < 8 * 64; i += 256) shw[i] = W1[i];
  __syncthreads();

  const int nl = tid >> 5;
  const int c = (tid & 31) * 2;
  const int node = nodeBase + nl;
  if (node >= n) return;
  float a0 = 0.0f, a1 = 0.0f;
#pragma unroll
  for (int k = 0; k < 8; ++k) {
    const float s = shin[nl * 8 + k];
    const float2 w = *reinterpret_cast<const float2*>(&shw[k * 64 + c]);
    a0 += s * w.x;
    a1 += s * w.y;
  }
  const float s0 = g1[c] * rsqrtf(rv1[c] + BN_EPS);
  const float s1 = g1[c + 1] * rsqrtf(rv1[c + 1] + BN_EPS);
  float v0 = (a0 + b1[c] - rm1[c]) * s0 + be1[c];
  float v1 = (a1 + b1[c + 1] - rm1[c + 1]) * s1 + be1[c + 1];
  v0 = v0 > 0.0f ? v0 : 0.0f;
  v1 = v1 > 0.0f ? v1 : 0.0f;
  *reinterpret_cast<float2*>(&t1[(size_t)node * 64 + c]) = make_float2(v0, v1);
}

// ============ mm2: h2' = dinv * (t1 @ W2)  [64 -> 64, fp16 out] ============
__global__ void mm2(const float* __restrict__ t1, const float* __restrict__ W2,
                    const float* __restrict__ dinv, __half* __restrict__ h2, int n) {
  constexpr int ROWS = 8;
  __shared__ float shin[ROWS * 64];
  __shared__ float shw[64 * 64];
  const int tid = threadIdx.x;
  const int nodeBase = blockIdx.x * ROWS;
  for (int i = tid; i < ROWS * 64; i += 256) {
    const int node = nodeBase + (i >> 6);
    shin[i] = (node < n) ? t1[(size_t)node * 64 + (i & 63)] : 0.0f;
  }
  for (int i = tid; i < 64 * 64; i += 256) shw[i] = W2[i];
  __syncthreads();

  const int nl = tid >> 5;
  const int c = (tid & 31) * 2;
  const int node = nodeBase + nl;
  if (node >= n) return;
  float a0 = 0.0f, a1 = 0.0f;
#pragma unroll
  for (int k = 0; k < 64; ++k) {
    const float s = shin[nl * 64 + k];
    const float2 w = *reinterpret_cast<const float2*>(&shw[k * 64 + c]);
    a0 += s * w.x;
    a1 += s * w.y;
  }
  const float dn = dinv[node];
  reinterpret_cast<__half2*>(h2)[(size_t)node * 32 + (tid & 31)] =
      __floats2half2_rn(a0 * dn, a1 * dn);
}

// ============ gather h2' (C=64, fp16): agg2 = dinv * (sum + self) ============
__global__ void gather_h64(const __half* __restrict__ h, const float* __restrict__ dinv,
                           const int* __restrict__ row_ptr, const int* __restrict__ edata,
                           float* __restrict__ agg, int n) {
  const int wid = (int)(((long long)blockIdx.x * blockDim.x + threadIdx.x) >> 6);
  if (wid >= n) return;
  const int lane = threadIdx.x & 63;
  const int cp = lane & 31;
  const int grp = lane >> 5;  // 2 groups
  const int beg = row_ptr[wid], end = row_ptr[wid + 1];
  const __half2* h2v = reinterpret_cast<const __half2*>(h);
  float ax = 0.0f, ay = 0.0f;
  int e = beg + grp;
  for (; e + 2 < end; e += 4) {
    const float2 v0 = __half22float2(h2v[(size_t)edata[e] * 32 + cp]);
    const float2 v1 = __half22float2(h2v[(size_t)edata[e + 2] * 32 + cp]);
    ax += v0.x + v1.x;
    ay += v0.y + v1.y;
  }
  if (e < end) {
    const float2 v = __half22float2(h2v[(size_t)edata[e] * 32 + cp]);
    ax += v.x;
    ay += v.y;
  }
  ax += __shfl_xor(ax, 32);
  ay += __shfl_xor(ay, 32);
  if (grp == 0) {
    const float2 v = __half22float2(h2v[(size_t)wid * 32 + cp]);
    const float dn = dinv[wid];
    ax = (ax + v.x) * dn;
    ay = (ay + v.y) * dn;
    *reinterpret_cast<float2*>(&agg[(size_t)wid * 64 + cp * 2]) = make_float2(ax, ay);
  }
}

// ============ mm3: h3' = dinv * (act2(agg2) @ W3)  [64 -> 32, fp16 out] ============
__global__ void mm3_act(const float* __restrict__ agg2, const float* __restrict__ W3,
                        const float* __restrict__ b2, const float* __restrict__ g2,
                        const float* __restrict__ be2, const float* __restrict__ rm2,
                        const float* __restrict__ rv2, const float* __restrict__ dinv,
                        __half* __restrict__ h3, int n) {
  constexpr int ROWS = 16;
  __shared__ float shin[ROWS * 64];
  __shared__ float shw[64 * 32];
  const int tid = threadIdx.x;
  const int nodeBase = blockIdx.x * ROWS;
  for (int i = tid; i < ROWS * 64; i += 256) {
    const int node = nodeBase + (i >> 6);
    const int k = i & 63;
    float v = 0.0f;
    if (node < n) {
      const float a = g2[k] * rsqrtf(rv2[k] + BN_EPS);
      const float sft = (b2[k] - rm2[k]) * a + be2[k];
      v = agg2[(size_t)node * 64 + k] * a + sft;
      v = v > 0.0f ? v : 0.0f;
    }
    shin[i] = v;
  }
  for (int i = tid; i < 64 * 32; i += 256) shw[i] = W3[i];
  __syncthreads();

  const int nl = tid >> 4;
  const int c = (tid & 15) * 2;
  const int node = nodeBase + nl;
  if (node >= n) return;
  float a0 = 0.0f, a1 = 0.0f;
#pragma unroll
  for (int k = 0; k < 64; ++k) {
    const float s = shin[nl * 64 + k];
    const float2 w = *reinterpret_cast<const float2*>(&shw[k * 32 + c]);
    a0 += s * w.x;
    a1 += s * w.y;
  }
  const float dn = dinv[node];
  reinterpret_cast<__half2*>(h3)[(size_t)node * 16 + (tid & 15)] =
      __floats2half2_rn(a0 * dn, a1 * dn);
}

// ============ gather h3' (C=32) + BN3 + ReLU + 32x2 linear + log_softmax ============
__global__ void gather_cls(const __half* __restrict__ h, const float* __restrict__ dinv,
                           const int* __restrict__ row_ptr, const int* __restrict__ edata,
                           const float* __restrict__ b3, const float* __restrict__ g3,
                           const float* __restrict__ be3, const float* __restrict__ rm3,
                           const float* __restrict__ rv3, const float* __restrict__ Wc,
                           const float* __restrict__ bc, float* __restrict__ out, int n) {
  const int wid = (int)(((long long)blockIdx.x * blockDim.x + threadIdx.x) >> 6);
  if (wid >= n) return;
  const int lane = threadIdx.x & 63;
  const int cp = lane & 15;
  const int grp = lane >> 4;  // 4 groups
  const int beg = row_ptr[wid], end = row_ptr[wid + 1];
  const __half2* h2v = reinterpret_cast<const __half2*>(h);
  float ax = 0.0f, ay = 0.0f;
  for (int e = beg + grp; e < end; e += 4) {
    const float2 v = __half22float2(h2v[(size_t)edata[e] * 16 + cp]);
    ax += v.x;
    ay += v.y;
  }
  ax += __shfl_xor(ax, 16);
  ay += __shfl_xor(ay, 16);
  ax += __shfl_xor(ax, 32);
  ay += __shfl_xor(ay, 32);
  if (grp != 0) return;
  const float2 sv = __half22float2(h2v[(size_t)wid * 16 + cp]);
  const float dn = dinv[wid];
  ax = (ax + sv.x) * dn;
  ay = (ay + sv.y) * dn;
  const int c0 = cp * 2, c1 = cp * 2 + 1;
  const float s0 = g3[c0] * rsqrtf(rv3[c0] + BN_EPS);
  const float s1 = g3[c1] * rsqrtf(rv3[c1] + BN_EPS);
  float v0 = (ax + b3[c0] - rm3[c0]) * s0 + be3[c0];
  float v1 = (ay + b3[c1] - rm3[c1]) * s1 + be3[c1];
  v0 = v0 > 0.0f ? v0 : 0.0f;
  v1 = v1 > 0.0f ? v1 : 0.0f;
  float l0 = v0 * Wc[c0 * 2 + 0] + v1 * Wc[c1 * 2 + 0];
  float l1 = v0 * Wc[c0 * 2 + 1] + v1 * Wc[c1 * 2 + 1];
  l0 += __shfl_xor(l0, 1);
  l1 += __shfl_xor(l1, 1);
  l0 += __shfl_xor(l0, 2);
  l1 += __shfl_xor(l1, 2);
  l0 += __shfl_xor(l0, 4);
  l1 += __shfl_xor(l1, 4);
  l0 += __shfl_xor(l0, 8);
  l1 += __shfl_xor(l1, 8);
  if (lane == 0) {
    l0 += bc[0];
    l1 += bc[1];
    const float m = fmaxf(l0, l1);
    const float lse = m + logf(expf(l0 - m) + expf(l1 - m));
    *reinterpret_cast<float2*>(&out[(size_t)wid * 2]) = make_float2(l0 - lse, l1 - lse);
  }
}

// ============ launch ============
extern "C" void kernel_launch(void* const* d_in, const int* in_sizes, int n_in,
                              void* d_out, int out_size, void* d_ws, size_t ws_size,
                              hipStream_t stream) {
  const float* x  = (const float*)d_in[0];
  const int* ei   = (const int*)d_in[1];   // int32 on device per harness contract
  const float* W1 = (const float*)d_in[2];
  const float* b1 = (const float*)d_in[3];
  const float* g1 = (const float*)d_in[4];
  const float* be1 = (const float*)d_in[5];
  const float* rm1 = (const float*)d_in[6];
  const float* rv1 = (const float*)d_in[7];
  const float* W2 = (const float*)d_in[8];
  const float* b2 = (const float*)d_in[9];
  const float* g2 = (const float*)d_in[10];
  const float* be2 = (const float*)d_in[11];
  const float* rm2 = (const float*)d_in[12];
  const float* rv2 = (const float*)d_in[13];
  const float* W3 = (const float*)d_in[14];
  const float* b3 = (const float*)d_in[15];
  const float* g3 = (const float*)d_in[16];
  const float* be3 = (const float*)d_in[17];
  const float* rm3 = (const float*)d_in[18];
  const float* rv3 = (const float*)d_in[19];
  const float* Wc = (const float*)d_in[20];
  const float* bc = (const float*)d_in[21];

  const int N_ = in_sizes[0] / 8;
  const int E_ = in_sizes[1] / 2;
  const int NB = (N_ + 255) >> 8;          // 256-node buckets
  const int nbW = (N_ + 3) / 4;            // 1 wave/node, 256-thread blocks

  auto align = [](size_t v) { return (v + 255) & ~(size_t)255; };
  char* ws = (char*)d_ws;
  size_t off = 0;
  float* dinv   = (float*)(ws + off); off += align((size_t)N_ * 4);
  int* bcur     = (int*)(ws + off);   off += align((size_t)NB * 4);
  int* row_ptr  = (int*)(ws + off);   off += align(((size_t)N_ + 1) * 4);
  int* gbase    = (int*)(ws + off);   off += align(520 * 4);
  int* edata    = (int*)(ws + off);   off += align((size_t)E_ * 4);
  float* xs     = (float*)(ws + off); off += align((size_t)N_ * 8 * 4);
  float* aggx   = (float*)(ws + off); off += align((size_t)N_ * 8 * 4);
  float* bufA   = (float*)(ws + off); off += align((size_t)N_ * 64 * 4);   // bucketbuf, then t1, then agg2
  __half* bufH  = (__half*)(ws + off); off += align((size_t)N_ * 64 * 2);  // h2', then h3'
  int2* bucketbuf = (int2*)bufA;  // NB*BCAP*8B = 16.0MB <= 25.6MB, dead before mm1 writes t1

  // ---- bucketed CSR build (also produces dinv) ----
  zero_int<<<(NB + 255) / 256, 256, 0, stream>>>(bcur, NB);
  p1_partition<<<(E_ + 4095) / 4096, 256, 0, stream>>>(ei, bucketbuf, bcur, E_, NB);
  scan_buckets<<<1, 512, 0, stream>>>(bcur, gbase, NB, E_, row_ptr, N_);
  p2_sort<<<NB, 256, 0, stream>>>(bucketbuf, gbase, edata, row_ptr, dinv, N_);

  // ---- layer 1: x' = dinv*x, aggregate (C=8), fused matmul+BN1+ReLU ----
  scale_x<<<(N_ * 8 + 255) / 256, 256, 0, stream>>>(x, dinv, xs, N_);
  gather_x<<<nbW, 256, 0, stream>>>(xs, dinv, row_ptr, edata, aggx, N_);
  mm1_act<<<(N_ + 7) / 8, 256, 0, stream>>>(aggx, W1, b1, g1, be1, rm1, rv1, bufA, N_);

  // ---- layer 2: h2' = dinv*(t1 @ W2) fp16, gather -> agg2 fp32 ----
  mm2<<<(N_ + 7) / 8, 256, 0, stream>>>(bufA, W2, dinv, bufH, N_);
  gather_h64<<<nbW, 256, 0, stream>>>(bufH, dinv, row_ptr, edata, bufA, N_);

  // ---- layer 3: h3' = dinv*(act2(agg2) @ W3) fp16, gather + classifier ----
  mm3_act<<<(N_ + 15) / 16, 256, 0, stream>>>(bufA, W3, b2, g2, be2, rm2, rv2, dinv, bufH, N_);
  gather_cls<<<nbW, 256, 0, stream>>>(bufH, dinv, row_ptr, edata,
                                      b3, g3, be3, rm3, rv3, Wc, bc,
                                      (float*)d_out, N_);
}

// Round 7
// 252.541 us; speedup vs baseline: 14.1815x; 1.1122x over previous
//
#include <hip/hip_runtime.h>
#include <hip/hip_fp16.h>

#define BN_EPS 1e-5f
#define BCAP 5120   // bucket capacity; mean 4096 edges/bucket, large safety margin

__device__ __forceinline__ float2 u2f(unsigned u) {
  __half2 h = *reinterpret_cast<__half2*>(&u);
  return __half22float2(h);
}
__device__ __forceinline__ unsigned f2u(float a, float b) {
  __half2 h = __floats2half2_rn(a, b);
  return *reinterpret_cast<unsigned*>(&h);
}

// ============ CSR build (bucketed two-phase sort; degrees fall out of phase 2) ============
__global__ void zero_int(int* __restrict__ p, int n) {
  int i = blockIdx.x * blockDim.x + threadIdx.x;
  if (i < n) p[i] = 0;
}

// Phase 1: partition edges into per-bucket regions (bucket = dst>>8).
__global__ void p1_partition(const int* __restrict__ ei, int2* __restrict__ bucketbuf,
                             int* __restrict__ bcur, int E_, int NB) {
  __shared__ int hist[512];
  __shared__ int bbase[512];
  const int tid = threadIdx.x;
  const int e0 = blockIdx.x * 4096;
  const int ecount = min(4096, E_ - e0);
  for (int i = tid; i < NB; i += 256) hist[i] = 0;
  __syncthreads();
  for (int i = tid; i < ecount; i += 256) {
    const int d = ei[(size_t)E_ + e0 + i];
    atomicAdd(&hist[d >> 8], 1);
  }
  __syncthreads();
  for (int i = tid; i < NB; i += 256) {
    const int c = hist[i];
    bbase[i] = c ? atomicAdd(&bcur[i], c) : 0;
    hist[i] = 0;  // reuse as local cursor
  }
  __syncthreads();
  for (int i = tid; i < ecount; i += 256) {
    const int s = ei[e0 + i];
    const int d = ei[(size_t)E_ + e0 + i];
    const int b = d >> 8;
    const int slot = bbase[b] + atomicAdd(&hist[b], 1);
    bucketbuf[(size_t)b * BCAP + slot] = make_int2(s, d);
  }
}

// exclusive scan over NB bucket counts (NB <= 512); also sets row_ptr[N]=E.
__global__ void scan_buckets(const int* __restrict__ bcur, int* __restrict__ gbase,
                             int NB, int E_, int* __restrict__ row_ptr, int N_) {
  __shared__ int sh[512];
  const int t = threadIdx.x;
  const int v = (t < NB) ? bcur[t] : 0;
  sh[t] = v;
  __syncthreads();
  for (int off = 1; off < 512; off <<= 1) {
    int u = (t >= off) ? sh[t - off] : 0;
    __syncthreads();
    sh[t] += u;
    __syncthreads();
  }
  if (t < NB) gbase[t] = sh[t] - v;  // exclusive
  if (t == 0) { gbase[NB] = E_; row_ptr[N_] = E_; }
}

// Phase 2: per-bucket counting sort in LDS; emits row_ptr AND dinv.
__global__ void p2_sort(const int2* __restrict__ bucketbuf, const int* __restrict__ gbase,
                        int* __restrict__ edata, int* __restrict__ row_ptr,
                        float* __restrict__ dinv, int N_) {
  __shared__ int cntl[256];
  __shared__ int scn[256];
  __shared__ int cur[256];
  __shared__ int sbuf[BCAP];
  const int b = blockIdx.x;
  const int tid = threadIdx.x;
  const int base = gbase[b];
  const int m = gbase[b + 1] - base;
  const int2* srcp = bucketbuf + (size_t)b * BCAP;
  cntl[tid] = 0;
  __syncthreads();
  for (int i = tid; i < m; i += 256) atomicAdd(&cntl[srcp[i].y & 255], 1);
  __syncthreads();
  const int v = cntl[tid];
  scn[tid] = v;
  __syncthreads();
  for (int off = 1; off < 256; off <<= 1) {
    int u = (tid >= off) ? scn[tid - off] : 0;
    __syncthreads();
    scn[tid] += u;
    __syncthreads();
  }
  const int excl = scn[tid] - v;
  cur[tid] = excl;
  const int node = (b << 8) + tid;
  if (node < N_) {
    row_ptr[node] = base + excl;
    dinv[node] = rsqrtf((float)v + 1.0f);   // deg = in-degree + self-loop
  }
  __syncthreads();
  for (int i = tid; i < m; i += 256) {
    const int2 sd = srcp[i];
    const int slot = atomicAdd(&cur[sd.y & 255], 1);
    sbuf[slot] = sd.x;
  }
  __syncthreads();
  for (int i = tid; i < m; i += 256) edata[(size_t)base + i] = sbuf[i];
}

// ============ xs = fp16(x * dinv) ============
__global__ void scale_x(const float* __restrict__ x, const float* __restrict__ dinv,
                        __half2* __restrict__ xs, int n4) {
  const int i = blockIdx.x * blockDim.x + threadIdx.x;
  if (i < n4) {
    const float dn = dinv[i >> 2];
    const float2 v = reinterpret_cast<const float2*>(x)[i];
    xs[i] = __floats2half2_rn(v.x * dn, v.y * dn);
  }
}

// ============ gather on xs (C=8 fp16): aggx = dinv * (sum + self), fp32 out ============
// 16 groups x 4 lanes; each lane one half2 (2 ch); 16 edges in flight per wave.
__global__ void gather_x(const __half* __restrict__ xs, const float* __restrict__ dinv,
                         const int* __restrict__ row_ptr, const int* __restrict__ edata,
                         float* __restrict__ aggx, int n) {
  const int wid = (int)(((long long)blockIdx.x * blockDim.x + threadIdx.x) >> 6);
  if (wid >= n) return;
  const int lane = threadIdx.x & 63;
  const int cp = lane & 3;    // half2 index (8 ch = 4 half2)
  const int grp = lane >> 2;  // 16 groups
  const int beg = row_ptr[wid], end = row_ptr[wid + 1];
  const __half2* xv = reinterpret_cast<const __half2*>(xs);
  float ax = 0.0f, ay = 0.0f;
  for (int e = beg + grp; e < end; e += 16) {
    const float2 v = __half22float2(xv[(size_t)edata[e] * 4 + cp]);
    ax += v.x;
    ay += v.y;
  }
  ax += __shfl_xor(ax, 4);  ay += __shfl_xor(ay, 4);
  ax += __shfl_xor(ax, 8);  ay += __shfl_xor(ay, 8);
  ax += __shfl_xor(ax, 16); ay += __shfl_xor(ay, 16);
  ax += __shfl_xor(ax, 32); ay += __shfl_xor(ay, 32);
  if (grp == 0) {
    const float2 sv = __half22float2(xv[(size_t)wid * 4 + cp]);
    const float dn = dinv[wid];
    *reinterpret_cast<float2*>(&aggx[(size_t)wid * 8 + cp * 2]) =
        make_float2((ax + sv.x) * dn, (ay + sv.y) * dn);
  }
}

// ============ mm1: t1 = fp16(act1(aggx @ W1 + b1))  [8 -> 64] ============
__global__ void mm1_act(const float* __restrict__ aggx, const float* __restrict__ W1,
                        const float* __restrict__ b1, const float* __restrict__ g1,
                        const float* __restrict__ be1, const float* __restrict__ rm1,
                        const float* __restrict__ rv1, __half* __restrict__ t1, int n) {
  constexpr int ROWS = 8;
  __shared__ float shin[ROWS * 8];
  __shared__ float shw[8 * 64];
  const int tid = threadIdx.x;
  const int nodeBase = blockIdx.x * ROWS;
  for (int i = tid; i < ROWS * 8; i += 256) {
    const int node = nodeBase + i / 8;
    shin[i] = (node < n) ? aggx[(size_t)node * 8 + (i & 7)] : 0.0f;
  }
  for (int i = tid; i < 8 * 64; i += 256) shw[i] = W1[i];
  __syncthreads();

  const int nl = tid >> 5;
  const int c = (tid & 31) * 2;
  const int node = nodeBase + nl;
  if (node >= n) return;
  float a0 = 0.0f, a1 = 0.0f;
#pragma unroll
  for (int k = 0; k < 8; ++k) {
    const float s = shin[nl * 8 + k];
    const float2 w = *reinterpret_cast<const float2*>(&shw[k * 64 + c]);
    a0 += s * w.x;
    a1 += s * w.y;
  }
  const float s0 = g1[c] * rsqrtf(rv1[c] + BN_EPS);
  const float s1 = g1[c + 1] * rsqrtf(rv1[c + 1] + BN_EPS);
  float v0 = (a0 + b1[c] - rm1[c]) * s0 + be1[c];
  float v1 = (a1 + b1[c + 1] - rm1[c + 1]) * s1 + be1[c + 1];
  v0 = v0 > 0.0f ? v0 : 0.0f;
  v1 = v1 > 0.0f ? v1 : 0.0f;
  reinterpret_cast<__half2*>(t1)[(size_t)node * 32 + (tid & 31)] = __floats2half2_rn(v0, v1);
}

// ============ mm2: h2' = fp16(dinv * (t1 @ W2))  [64 -> 64] ============
__global__ void mm2(const __half* __restrict__ t1, const float* __restrict__ W2,
                    const float* __restrict__ dinv, __half* __restrict__ h2, int n) {
  constexpr int ROWS = 8;
  __shared__ float shin[ROWS * 64];
  __shared__ float shw[64 * 64];
  const int tid = threadIdx.x;
  const int nodeBase = blockIdx.x * ROWS;
  const __half2* t1h = reinterpret_cast<const __half2*>(t1);
  for (int i = tid; i < ROWS * 32; i += 256) {
    const int node = nodeBase + (i >> 5);
    float2 v = make_float2(0.0f, 0.0f);
    if (node < n) v = __half22float2(t1h[(size_t)node * 32 + (i & 31)]);
    shin[(i >> 5) * 64 + (i & 31) * 2] = v.x;
    shin[(i >> 5) * 64 + (i & 31) * 2 + 1] = v.y;
  }
  for (int i = tid; i < 64 * 64; i += 256) shw[i] = W2[i];
  __syncthreads();

  const int nl = tid >> 5;
  const int c = (tid & 31) * 2;
  const int node = nodeBase + nl;
  if (node >= n) return;
  float a0 = 0.0f, a1 = 0.0f;
#pragma unroll
  for (int k = 0; k < 64; ++k) {
    const float s = shin[nl * 64 + k];
    const float2 w = *reinterpret_cast<const float2*>(&shw[k * 64 + c]);
    a0 += s * w.x;
    a1 += s * w.y;
  }
  const float dn = dinv[node];
  reinterpret_cast<__half2*>(h2)[(size_t)node * 32 + (tid & 31)] =
      __floats2half2_rn(a0 * dn, a1 * dn);
}

// ============ gather h2' (C=64 fp16): agg2 = fp16(dinv * (sum + self)) ============
// 8 groups x 8 lanes; each lane one uint4 (8 ch, 16 B); row = 128 B.
__global__ void gather_h64(const __half* __restrict__ h, const float* __restrict__ dinv,
                           const int* __restrict__ row_ptr, const int* __restrict__ edata,
                           __half* __restrict__ agg, int n) {
  const int wid = (int)(((long long)blockIdx.x * blockDim.x + threadIdx.x) >> 6);
  if (wid >= n) return;
  const int lane = threadIdx.x & 63;
  const int qi = lane & 7;    // uint4 index within row (8 x 16B = 128B)
  const int grp = lane >> 3;  // 8 groups
  const int beg = row_ptr[wid], end = row_ptr[wid + 1];
  const uint4* hv = reinterpret_cast<const uint4*>(h);
  float a0 = 0, a1 = 0, a2 = 0, a3 = 0, a4 = 0, a5 = 0, a6 = 0, a7 = 0;
  int e = beg + grp;
  for (; e + 8 < end; e += 16) {
    const int s0 = edata[e];
    const int s1 = edata[e + 8];
    const uint4 q0 = hv[(size_t)s0 * 8 + qi];
    const uint4 q1 = hv[(size_t)s1 * 8 + qi];
    float2 f;
    f = u2f(q0.x); a0 += f.x; a1 += f.y;
    f = u2f(q0.y); a2 += f.x; a3 += f.y;
    f = u2f(q0.z); a4 += f.x; a5 += f.y;
    f = u2f(q0.w); a6 += f.x; a7 += f.y;
    f = u2f(q1.x); a0 += f.x; a1 += f.y;
    f = u2f(q1.y); a2 += f.x; a3 += f.y;
    f = u2f(q1.z); a4 += f.x; a5 += f.y;
    f = u2f(q1.w); a6 += f.x; a7 += f.y;
  }
  if (e < end) {
    const uint4 q = hv[(size_t)edata[e] * 8 + qi];
    float2 f;
    f = u2f(q.x); a0 += f.x; a1 += f.y;
    f = u2f(q.y); a2 += f.x; a3 += f.y;
    f = u2f(q.z); a4 += f.x; a5 += f.y;
    f = u2f(q.w); a6 += f.x; a7 += f.y;
  }
#pragma unroll
  for (int m = 8; m <= 32; m <<= 1) {
    a0 += __shfl_xor(a0, m); a1 += __shfl_xor(a1, m);
    a2 += __shfl_xor(a2, m); a3 += __shfl_xor(a3, m);
    a4 += __shfl_xor(a4, m); a5 += __shfl_xor(a5, m);
    a6 += __shfl_xor(a6, m); a7 += __shfl_xor(a7, m);
  }
  if (grp == 0) {
    const uint4 q = hv[(size_t)wid * 8 + qi];
    float2 f;
    f = u2f(q.x); a0 += f.x; a1 += f.y;
    f = u2f(q.y); a2 += f.x; a3 += f.y;
    f = u2f(q.z); a4 += f.x; a5 += f.y;
    f = u2f(q.w); a6 += f.x; a7 += f.y;
    const float dn = dinv[wid];
    uint4 o;
    o.x = f2u(a0 * dn, a1 * dn);
    o.y = f2u(a2 * dn, a3 * dn);
    o.z = f2u(a4 * dn, a5 * dn);
    o.w = f2u(a6 * dn, a7 * dn);
    reinterpret_cast<uint4*>(agg)[(size_t)wid * 8 + qi] = o;
  }
}

// ============ mm3: h3' = fp16(dinv * (act2(agg2 + b2) @ W3))  [64 -> 32] ============
__global__ void mm3_act(const __half* __restrict__ agg2, const float* __restrict__ W3,
                        const float* __restrict__ b2, const float* __restrict__ g2,
                        const float* __restrict__ be2, const float* __restrict__ rm2,
                        const float* __restrict__ rv2, const float* __restrict__ dinv,
                        __half* __restrict__ h3, int n) {
  constexpr int ROWS = 16;
  __shared__ float shin[ROWS * 64];
  __shared__ float shw[64 * 32];
  const int tid = threadIdx.x;
  const int nodeBase = blockIdx.x * ROWS;
  const __half2* ah = reinterpret_cast<const __half2*>(agg2);
  for (int i = tid; i < ROWS * 32; i += 256) {
    const int node = nodeBase + (i >> 5);
    const int kp = i & 31;
    const int k0 = kp * 2, k1 = kp * 2 + 1;
    float v0 = 0.0f, v1 = 0.0f;
    if (node < n) {
      const float2 v = __half22float2(ah[(size_t)node * 32 + kp]);
      const float a0 = g2[k0] * rsqrtf(rv2[k0] + BN_EPS);
      const float a1 = g2[k1] * rsqrtf(rv2[k1] + BN_EPS);
      v0 = (v.x + b2[k0] - rm2[k0]) * a0 + be2[k0];
      v1 = (v.y + b2[k1] - rm2[k1]) * a1 + be2[k1];
      v0 = v0 > 0.0f ? v0 : 0.0f;
      v1 = v1 > 0.0f ? v1 : 0.0f;
    }
    shin[(i >> 5) * 64 + k0] = v0;
    shin[(i >> 5) * 64 + k1] = v1;
  }
  for (int i = tid; i < 64 * 32; i += 256) shw[i] = W3[i];
  __syncthreads();

  const int nl = tid >> 4;
  const int c = (tid & 15) * 2;
  const int node = nodeBase + nl;
  if (node >= n) return;
  float a0 = 0.0f, a1 = 0.0f;
#pragma unroll
  for (int k = 0; k < 64; ++k) {
    const float s = shin[nl * 64 + k];
    const float2 w = *reinterpret_cast<const float2*>(&shw[k * 32 + c]);
    a0 += s * w.x;
    a1 += s * w.y;
  }
  const float dn = dinv[node];
  reinterpret_cast<__half2*>(h3)[(size_t)node * 16 + (tid & 15)] =
      __floats2half2_rn(a0 * dn, a1 * dn);
}

// ============ gather h3' (C=32 fp16) + BN3 + ReLU + 32x2 linear + log_softmax ============
// 16 groups x 4 lanes; each lane one uint4 (8 ch, 16 B); row = 64 B.
__global__ void gather_cls(const __half* __restrict__ h, const float* __restrict__ dinv,
                           const int* __restrict__ row_ptr, const int* __restrict__ edata,
                           const float* __restrict__ b3, const float* __restrict__ g3,
                           const float* __restrict__ be3, const float* __restrict__ rm3,
                           const float* __restrict__ rv3, const float* __restrict__ Wc,
                           const float* __restrict__ bc, float* __restrict__ out, int n) {
  const int wid = (int)(((long long)blockIdx.x * blockDim.x + threadIdx.x) >> 6);
  if (wid >= n) return;
  const int lane = threadIdx.x & 63;
  const int qi = lane & 3;    // uint4 index (4 x 16B = 64B row)
  const int grp = lane >> 2;  // 16 groups
  const int beg = row_ptr[wid], end = row_ptr[wid + 1];
  const uint4* hv = reinterpret_cast<const uint4*>(h);
  float a0 = 0, a1 = 0, a2 = 0, a3 = 0, a4 = 0, a5 = 0, a6 = 0, a7 = 0;
  for (int e = beg + grp; e < end; e += 16) {
    const uint4 q = hv[(size_t)edata[e] * 4 + qi];
    float2 f;
    f = u2f(q.x); a0 += f.x; a1 += f.y;
    f = u2f(q.y); a2 += f.x; a3 += f.y;
    f = u2f(q.z); a4 += f.x; a5 += f.y;
    f = u2f(q.w); a6 += f.x; a7 += f.y;
  }
#pragma unroll
  for (int m = 4; m <= 32; m <<= 1) {
    a0 += __shfl_xor(a0, m); a1 += __shfl_xor(a1, m);
    a2 += __shfl_xor(a2, m); a3 += __shfl_xor(a3, m);
    a4 += __shfl_xor(a4, m); a5 += __shfl_xor(a5, m);
    a6 += __shfl_xor(a6, m); a7 += __shfl_xor(a7, m);
  }
  if (grp != 0) return;
  // lanes 0..3: lane qi covers channels 8*qi .. 8*qi+7
  {
    const uint4 q = hv[(size_t)wid * 4 + qi];
    float2 f;
    f = u2f(q.x); a0 += f.x; a1 += f.y;
    f = u2f(q.y); a2 += f.x; a3 += f.y;
    f = u2f(q.z); a4 += f.x; a5 += f.y;
    f = u2f(q.w); a6 += f.x; a7 += f.y;
  }
  const float dn = dinv[wid];
  float v[8] = {a0 * dn, a1 * dn, a2 * dn, a3 * dn, a4 * dn, a5 * dn, a6 * dn, a7 * dn};
  float l0 = 0.0f, l1 = 0.0f;
#pragma unroll
  for (int j = 0; j < 8; ++j) {
    const int c = qi * 8 + j;
    const float s = g3[c] * rsqrtf(rv3[c] + BN_EPS);
    float t = (v[j] + b3[c] - rm3[c]) * s + be3[c];
    t = t > 0.0f ? t : 0.0f;
    l0 += t * Wc[c * 2 + 0];
    l1 += t * Wc[c * 2 + 1];
  }
  l0 += __shfl_xor(l0, 1); l1 += __shfl_xor(l1, 1);
  l0 += __shfl_xor(l0, 2); l1 += __shfl_xor(l1, 2);
  if (lane == 0) {
    l0 += bc[0];
    l1 += bc[1];
    const float m = fmaxf(l0, l1);
    const float lse = m + logf(expf(l0 - m) + expf(l1 - m));
    *reinterpret_cast<float2*>(&out[(size_t)wid * 2]) = make_float2(l0 - lse, l1 - lse);
  }
}

// ============ launch ============
extern "C" void kernel_launch(void* const* d_in, const int* in_sizes, int n_in,
                              void* d_out, int out_size, void* d_ws, size_t ws_size,
                              hipStream_t stream) {
  const float* x  = (const float*)d_in[0];
  const int* ei   = (const int*)d_in[1];   // int32 on device per harness contract
  const float* W1 = (const float*)d_in[2];
  const float* b1 = (const float*)d_in[3];
  const float* g1 = (const float*)d_in[4];
  const float* be1 = (const float*)d_in[5];
  const float* rm1 = (const float*)d_in[6];
  const float* rv1 = (const float*)d_in[7];
  const float* W2 = (const float*)d_in[8];
  const float* b2 = (const float*)d_in[9];
  const float* g2 = (const float*)d_in[10];
  const float* be2 = (const float*)d_in[11];
  const float* rm2 = (const float*)d_in[12];
  const float* rv2 = (const float*)d_in[13];
  const float* W3 = (const float*)d_in[14];
  const float* b3 = (const float*)d_in[15];
  const float* g3 = (const float*)d_in[16];
  const float* be3 = (const float*)d_in[17];
  const float* rm3 = (const float*)d_in[18];
  const float* rv3 = (const float*)d_in[19];
  const float* Wc = (const float*)d_in[20];
  const float* bc = (const float*)d_in[21];

  const int N_ = in_sizes[0] / 8;
  const int E_ = in_sizes[1] / 2;
  const int NB = (N_ + 255) >> 8;          // 256-node buckets
  const int nbW = (N_ + 3) / 4;            // 1 wave/node, 256-thread blocks

  auto align = [](size_t v) { return (v + 255) & ~(size_t)255; };
  char* ws = (char*)d_ws;
  size_t off = 0;
  float* dinv   = (float*)(ws + off); off += align((size_t)N_ * 4);
  int* bcur     = (int*)(ws + off);   off += align((size_t)NB * 4);
  int* row_ptr  = (int*)(ws + off);   off += align(((size_t)N_ + 1) * 4);
  int* gbase    = (int*)(ws + off);   off += align(520 * 4);
  int* edata    = (int*)(ws + off);   off += align((size_t)E_ * 4);
  __half* xs    = (__half*)(ws + off); off += align((size_t)N_ * 8 * 2);
  float* aggx   = (float*)(ws + off); off += align((size_t)N_ * 8 * 4);
  // regionA: bucketbuf (16 MB) -> t1 fp16 (12.8) -> agg2 fp16 (12.8)
  char* regionA = ws + off;           off += align((size_t)NB * BCAP * 8);
  // regionB: h2' fp16 (12.8) -> h3' fp16 (6.4)
  char* regionB = ws + off;           off += align((size_t)N_ * 64 * 2);

  int2* bucketbuf = (int2*)regionA;
  __half* t1   = (__half*)regionA;   // after p2_sort consumed bucketbuf
  __half* agg2 = (__half*)regionA;   // after mm2 consumed t1
  __half* h2   = (__half*)regionB;
  __half* h3   = (__half*)regionB;   // after gather_h64 consumed h2

  // ---- bucketed CSR build (also produces dinv) ----
  zero_int<<<(NB + 255) / 256, 256, 0, stream>>>(bcur, NB);
  p1_partition<<<(E_ + 4095) / 4096, 256, 0, stream>>>(ei, bucketbuf, bcur, E_, NB);
  scan_buckets<<<1, 512, 0, stream>>>(bcur, gbase, NB, E_, row_ptr, N_);
  p2_sort<<<NB, 256, 0, stream>>>(bucketbuf, gbase, edata, row_ptr, dinv, N_);

  // ---- layer 1: xs = fp16(dinv*x), gather (C=8), fused matmul+BN1+ReLU -> t1 fp16 ----
  scale_x<<<(N_ * 4 + 255) / 256, 256, 0, stream>>>(x, dinv, (__half2*)xs, N_ * 4);
  gather_x<<<nbW, 256, 0, stream>>>(xs, dinv, row_ptr, edata, aggx, N_);
  mm1_act<<<(N_ + 7) / 8, 256, 0, stream>>>(aggx, W1, b1, g1, be1, rm1, rv1, t1, N_);

  // ---- layer 2: h2' = fp16(dinv*(t1 @ W2)), gather -> agg2 fp16 ----
  mm2<<<(N_ + 7) / 8, 256, 0, stream>>>(t1, W2, dinv, h2, N_);
  gather_h64<<<nbW, 256, 0, stream>>>(h2, dinv, row_ptr, edata, agg2, N_);

  // ---- layer 3: h3' = fp16(dinv*(act2(agg2) @ W3)), gather + classifier ----
  mm3_act<<<(N_ + 15) / 16, 256, 0, stream>>>(agg2, W3, b2, g2, be2, rm2, rv2, dinv, h3, N_);
  gather_cls<<<nbW, 256, 0, stream>>>(h3, dinv, row_ptr, edata,
                                      b3, g3, be3, rm3, rv3, Wc, bc,
                                      (float*)d_out, N_);
}

// Round 8
// 202.312 us; speedup vs baseline: 17.7024x; 1.2483x over previous
//
#include <hip/hip_runtime.h>
#include <hip/hip_fp16.h>

#define BN_EPS 1e-5f
#define BCAP 5120   // bucket capacity; mean 4096 edges/bucket, large safety margin

__device__ __forceinline__ float2 u2f(unsigned u) {
  __half2 h = *reinterpret_cast<__half2*>(&u);
  return __half22float2(h);
}
__device__ __forceinline__ unsigned f2u(float a, float b) {
  __half2 h = __floats2half2_rn(a, b);
  return *reinterpret_cast<unsigned*>(&h);
}

// ============ CSR build (bucketed two-phase sort; degrees fall out of phase 2) ============
__global__ void zero_int(int* __restrict__ p, int n) {
  int i = blockIdx.x * blockDim.x + threadIdx.x;
  if (i < n) p[i] = 0;
}

// Phase 1: partition edges into per-bucket regions (bucket = dst>>8).
__global__ void p1_partition(const int* __restrict__ ei, int2* __restrict__ bucketbuf,
                             int* __restrict__ bcur, int E_, int NB) {
  __shared__ int hist[512];
  __shared__ int bbase[512];
  const int tid = threadIdx.x;
  const int e0 = blockIdx.x * 4096;
  const int ecount = min(4096, E_ - e0);
  for (int i = tid; i < NB; i += 256) hist[i] = 0;
  __syncthreads();
  for (int i = tid; i < ecount; i += 256) {
    const int d = ei[(size_t)E_ + e0 + i];
    atomicAdd(&hist[d >> 8], 1);
  }
  __syncthreads();
  for (int i = tid; i < NB; i += 256) {
    const int c = hist[i];
    bbase[i] = c ? atomicAdd(&bcur[i], c) : 0;
    hist[i] = 0;  // reuse as local cursor
  }
  __syncthreads();
  for (int i = tid; i < ecount; i += 256) {
    const int s = ei[e0 + i];
    const int d = ei[(size_t)E_ + e0 + i];
    const int b = d >> 8;
    const int slot = bbase[b] + atomicAdd(&hist[b], 1);
    bucketbuf[(size_t)b * BCAP + slot] = make_int2(s, d);
  }
}

// exclusive scan over NB bucket counts (NB <= 512); also sets row_ptr[N]=E.
__global__ void scan_buckets(const int* __restrict__ bcur, int* __restrict__ gbase,
                             int NB, int E_, int* __restrict__ row_ptr, int N_) {
  __shared__ int sh[512];
  const int t = threadIdx.x;
  const int v = (t < NB) ? bcur[t] : 0;
  sh[t] = v;
  __syncthreads();
  for (int off = 1; off < 512; off <<= 1) {
    int u = (t >= off) ? sh[t - off] : 0;
    __syncthreads();
    sh[t] += u;
    __syncthreads();
  }
  if (t < NB) gbase[t] = sh[t] - v;  // exclusive
  if (t == 0) { gbase[NB] = E_; row_ptr[N_] = E_; }
}

// Phase 2: per-bucket counting sort in LDS; emits row_ptr AND dinv.
__global__ void p2_sort(const int2* __restrict__ bucketbuf, const int* __restrict__ gbase,
                        int* __restrict__ edata, int* __restrict__ row_ptr,
                        float* __restrict__ dinv, int N_) {
  __shared__ int cntl[256];
  __shared__ int scn[256];
  __shared__ int cur[256];
  __shared__ int sbuf[BCAP];
  const int b = blockIdx.x;
  const int tid = threadIdx.x;
  const int base = gbase[b];
  const int m = gbase[b + 1] - base;
  const int2* srcp = bucketbuf + (size_t)b * BCAP;
  cntl[tid] = 0;
  __syncthreads();
  for (int i = tid; i < m; i += 256) atomicAdd(&cntl[srcp[i].y & 255], 1);
  __syncthreads();
  const int v = cntl[tid];
  scn[tid] = v;
  __syncthreads();
  for (int off = 1; off < 256; off <<= 1) {
    int u = (tid >= off) ? scn[tid - off] : 0;
    __syncthreads();
    scn[tid] += u;
    __syncthreads();
  }
  const int excl = scn[tid] - v;
  cur[tid] = excl;
  const int node = (b << 8) + tid;
  if (node < N_) {
    row_ptr[node] = base + excl;
    dinv[node] = rsqrtf((float)v + 1.0f);   // deg = in-degree + self-loop
  }
  __syncthreads();
  for (int i = tid; i < m; i += 256) {
    const int2 sd = srcp[i];
    const int slot = atomicAdd(&cur[sd.y & 255], 1);
    sbuf[slot] = sd.x;
  }
  __syncthreads();
  for (int i = tid; i < m; i += 256) edata[(size_t)base + i] = sbuf[i];
}

// ============ BN constant prep: sc/sh for all three BN layers ============
// bn layout: sc1[64] | sh1[64] | sc2[64] | sh2[64] | sc3[32] | sh3[32]
__global__ void bn_prep(const float* __restrict__ b1, const float* __restrict__ g1,
                        const float* __restrict__ be1, const float* __restrict__ rm1,
                        const float* __restrict__ rv1,
                        const float* __restrict__ b2, const float* __restrict__ g2,
                        const float* __restrict__ be2, const float* __restrict__ rm2,
                        const float* __restrict__ rv2,
                        const float* __restrict__ b3, const float* __restrict__ g3,
                        const float* __restrict__ be3, const float* __restrict__ rm3,
                        const float* __restrict__ rv3,
                        float* __restrict__ bn) {
  const int t = threadIdx.x;
  if (t < 64) {
    const float s = g1[t] * rsqrtf(rv1[t] + BN_EPS);
    bn[t] = s;
    bn[64 + t] = (b1[t] - rm1[t]) * s + be1[t];
  } else if (t < 128) {
    const int c = t - 64;
    const float s = g2[c] * rsqrtf(rv2[c] + BN_EPS);
    bn[128 + c] = s;
    bn[192 + c] = (b2[c] - rm2[c]) * s + be2[c];
  } else if (t < 160) {
    const int c = t - 128;
    const float s = g3[c] * rsqrtf(rv3[c] + BN_EPS);
    bn[256 + c] = s;
    bn[288 + c] = (b3[c] - rm3[c]) * s + be3[c];
  }
}

// ============ xs = fp16(x * dinv) ============
__global__ void scale_x(const float* __restrict__ x, const float* __restrict__ dinv,
                        __half2* __restrict__ xs, int n4) {
  const int i = blockIdx.x * blockDim.x + threadIdx.x;
  if (i < n4) {
    const float dn = dinv[i >> 2];
    const float2 v = reinterpret_cast<const float2*>(x)[i];
    xs[i] = __floats2half2_rn(v.x * dn, v.y * dn);
  }
}

// ============ gather on xs (C=8 fp16): 8 nodes/wave, 1 lane = 1 edge row (uint4) ============
__global__ void gather_x(const __half* __restrict__ xs, const float* __restrict__ dinv,
                         const int* __restrict__ row_ptr, const int* __restrict__ edata,
                         float* __restrict__ aggx, int n) {
  const int wave = (int)(((long long)blockIdx.x * blockDim.x + threadIdx.x) >> 6);
  const int lane = threadIdx.x & 63;
  const int nl = lane >> 3;      // node within wave (0..7)
  const int grp = lane & 7;      // 8 groups x 1 lane
  const int node = wave * 8 + nl;
  if (node >= n) return;
  const int beg = row_ptr[node], end = row_ptr[node + 1];
  const uint4* xv = reinterpret_cast<const uint4*>(xs);
  float a0 = 0, a1 = 0, a2 = 0, a3 = 0, a4 = 0, a5 = 0, a6 = 0, a7 = 0;
  int e = beg + grp;
  for (; e + 8 < end; e += 16) {
    const uint4 q0 = xv[edata[e]];
    const uint4 q1 = xv[edata[e + 8]];
    float2 f;
    f = u2f(q0.x); a0 += f.x; a1 += f.y;
    f = u2f(q0.y); a2 += f.x; a3 += f.y;
    f = u2f(q0.z); a4 += f.x; a5 += f.y;
    f = u2f(q0.w); a6 += f.x; a7 += f.y;
    f = u2f(q1.x); a0 += f.x; a1 += f.y;
    f = u2f(q1.y); a2 += f.x; a3 += f.y;
    f = u2f(q1.z); a4 += f.x; a5 += f.y;
    f = u2f(q1.w); a6 += f.x; a7 += f.y;
  }
  if (e < end) {
    const uint4 q = xv[edata[e]];
    float2 f;
    f = u2f(q.x); a0 += f.x; a1 += f.y;
    f = u2f(q.y); a2 += f.x; a3 += f.y;
    f = u2f(q.z); a4 += f.x; a5 += f.y;
    f = u2f(q.w); a6 += f.x; a7 += f.y;
  }
#pragma unroll
  for (int m = 1; m <= 4; m <<= 1) {
    a0 += __shfl_xor(a0, m); a1 += __shfl_xor(a1, m);
    a2 += __shfl_xor(a2, m); a3 += __shfl_xor(a3, m);
    a4 += __shfl_xor(a4, m); a5 += __shfl_xor(a5, m);
    a6 += __shfl_xor(a6, m); a7 += __shfl_xor(a7, m);
  }
  if (grp == 0) {
    const uint4 q = xv[node];  // self term
    float2 f;
    f = u2f(q.x); a0 += f.x; a1 += f.y;
    f = u2f(q.y); a2 += f.x; a3 += f.y;
    f = u2f(q.z); a4 += f.x; a5 += f.y;
    f = u2f(q.w); a6 += f.x; a7 += f.y;
    const float dn = dinv[node];
    float4* op = reinterpret_cast<float4*>(&aggx[(size_t)node * 8]);
    op[0] = make_float4(a0 * dn, a1 * dn, a2 * dn, a3 * dn);
    op[1] = make_float4(a4 * dn, a5 * dn, a6 * dn, a7 * dn);
  }
}

// ============ mm1: t1 = fp16(relu(aggx @ W1 * sc1 + sh1))  [8 -> 64] ============
__global__ void mm1_act(const float* __restrict__ aggx, const float* __restrict__ W1,
                        const float* __restrict__ bn, __half* __restrict__ t1, int n) {
  constexpr int ROWS = 8;
  __shared__ float shin[ROWS * 8];
  __shared__ float shw[8 * 64];
  const int tid = threadIdx.x;
  const int nodeBase = blockIdx.x * ROWS;
  for (int i = tid; i < ROWS * 8; i += 256) {
    const int node = nodeBase + i / 8;
    shin[i] = (node < n) ? aggx[(size_t)node * 8 + (i & 7)] : 0.0f;
  }
  for (int i = tid; i < 8 * 64; i += 256) shw[i] = W1[i];
  __syncthreads();

  const int nl = tid >> 5;
  const int c = (tid & 31) * 2;
  const int node = nodeBase + nl;
  if (node >= n) return;
  float a0 = 0.0f, a1 = 0.0f;
#pragma unroll
  for (int k = 0; k < 8; ++k) {
    const float s = shin[nl * 8 + k];
    const float2 w = *reinterpret_cast<const float2*>(&shw[k * 64 + c]);
    a0 += s * w.x;
    a1 += s * w.y;
  }
  float v0 = a0 * bn[c] + bn[64 + c];
  float v1 = a1 * bn[c + 1] + bn[64 + c + 1];
  v0 = v0 > 0.0f ? v0 : 0.0f;
  v1 = v1 > 0.0f ? v1 : 0.0f;
  reinterpret_cast<__half2*>(t1)[(size_t)node * 32 + (tid & 31)] = __floats2half2_rn(v0, v1);
}

// ============ mm2: h2' = fp16(dinv * (t1 @ W2))  [64 -> 64] ============
__global__ void mm2(const __half* __restrict__ t1, const float* __restrict__ W2,
                    const float* __restrict__ dinv, __half* __restrict__ h2, int n) {
  constexpr int ROWS = 8;
  __shared__ float shin[ROWS * 64];
  __shared__ float shw[64 * 64];
  const int tid = threadIdx.x;
  const int nodeBase = blockIdx.x * ROWS;
  const __half2* t1h = reinterpret_cast<const __half2*>(t1);
  for (int i = tid; i < ROWS * 32; i += 256) {
    const int node = nodeBase + (i >> 5);
    float2 v = make_float2(0.0f, 0.0f);
    if (node < n) v = __half22float2(t1h[(size_t)node * 32 + (i & 31)]);
    shin[(i >> 5) * 64 + (i & 31) * 2] = v.x;
    shin[(i >> 5) * 64 + (i & 31) * 2 + 1] = v.y;
  }
  for (int i = tid; i < 64 * 64; i += 256) shw[i] = W2[i];
  __syncthreads();

  const int nl = tid >> 5;
  const int c = (tid & 31) * 2;
  const int node = nodeBase + nl;
  if (node >= n) return;
  float a0 = 0.0f, a1 = 0.0f;
#pragma unroll
  for (int k = 0; k < 64; ++k) {
    const float s = shin[nl * 64 + k];
    const float2 w = *reinterpret_cast<const float2*>(&shw[k * 64 + c]);
    a0 += s * w.x;
    a1 += s * w.y;
  }
  const float dn = dinv[node];
  reinterpret_cast<__half2*>(h2)[(size_t)node * 32 + (tid & 31)] =
      __floats2half2_rn(a0 * dn, a1 * dn);
}

// ============ gather h2' (C=64 fp16): agg2 = fp16(dinv * (sum + self)) ============
// 8 groups x 8 lanes; each lane one uint4 (8 ch, 16 B); row = 128 B.
__global__ void gather_h64(const __half* __restrict__ h, const float* __restrict__ dinv,
                           const int* __restrict__ row_ptr, const int* __restrict__ edata,
                           __half* __restrict__ agg, int n) {
  const int wid = (int)(((long long)blockIdx.x * blockDim.x + threadIdx.x) >> 6);
  if (wid >= n) return;
  const int lane = threadIdx.x & 63;
  const int qi = lane & 7;    // uint4 index within row (8 x 16B = 128B)
  const int grp = lane >> 3;  // 8 groups
  const int beg = row_ptr[wid], end = row_ptr[wid + 1];
  const uint4* hv = reinterpret_cast<const uint4*>(h);
  float a0 = 0, a1 = 0, a2 = 0, a3 = 0, a4 = 0, a5 = 0, a6 = 0, a7 = 0;
  int e = beg + grp;
  for (; e + 8 < end; e += 16) {
    const int s0 = edata[e];
    const int s1 = edata[e + 8];
    const uint4 q0 = hv[(size_t)s0 * 8 + qi];
    const uint4 q1 = hv[(size_t)s1 * 8 + qi];
    float2 f;
    f = u2f(q0.x); a0 += f.x; a1 += f.y;
    f = u2f(q0.y); a2 += f.x; a3 += f.y;
    f = u2f(q0.z); a4 += f.x; a5 += f.y;
    f = u2f(q0.w); a6 += f.x; a7 += f.y;
    f = u2f(q1.x); a0 += f.x; a1 += f.y;
    f = u2f(q1.y); a2 += f.x; a3 += f.y;
    f = u2f(q1.z); a4 += f.x; a5 += f.y;
    f = u2f(q1.w); a6 += f.x; a7 += f.y;
  }
  if (e < end) {
    const uint4 q = hv[(size_t)edata[e] * 8 + qi];
    float2 f;
    f = u2f(q.x); a0 += f.x; a1 += f.y;
    f = u2f(q.y); a2 += f.x; a3 += f.y;
    f = u2f(q.z); a4 += f.x; a5 += f.y;
    f = u2f(q.w); a6 += f.x; a7 += f.y;
  }
#pragma unroll
  for (int m = 8; m <= 32; m <<= 1) {
    a0 += __shfl_xor(a0, m); a1 += __shfl_xor(a1, m);
    a2 += __shfl_xor(a2, m); a3 += __shfl_xor(a3, m);
    a4 += __shfl_xor(a4, m); a5 += __shfl_xor(a5, m);
    a6 += __shfl_xor(a6, m); a7 += __shfl_xor(a7, m);
  }
  if (grp == 0) {
    const uint4 q = hv[(size_t)wid * 8 + qi];
    float2 f;
    f = u2f(q.x); a0 += f.x; a1 += f.y;
    f = u2f(q.y); a2 += f.x; a3 += f.y;
    f = u2f(q.z); a4 += f.x; a5 += f.y;
    f = u2f(q.w); a6 += f.x; a7 += f.y;
    const float dn = dinv[wid];
    uint4 o;
    o.x = f2u(a0 * dn, a1 * dn);
    o.y = f2u(a2 * dn, a3 * dn);
    o.z = f2u(a4 * dn, a5 * dn);
    o.w = f2u(a6 * dn, a7 * dn);
    reinterpret_cast<uint4*>(agg)[(size_t)wid * 8 + qi] = o;
  }
}

// ============ mm3: h3' = fp16(dinv * (relu(agg2*sc2+sh2) @ W3))  [64 -> 32] ============
__global__ void mm3_act(const __half* __restrict__ agg2, const float* __restrict__ W3,
                        const float* __restrict__ bn, const float* __restrict__ dinv,
                        __half* __restrict__ h3, int n) {
  constexpr int ROWS = 16;
  __shared__ float shin[ROWS * 64];
  __shared__ float shw[64 * 32];
  const int tid = threadIdx.x;
  const int nodeBase = blockIdx.x * ROWS;
  const __half2* ah = reinterpret_cast<const __half2*>(agg2);
  for (int i = tid; i < ROWS * 32; i += 256) {
    const int node = nodeBase + (i >> 5);
    const int kp = i & 31;
    const int k0 = kp * 2, k1 = kp * 2 + 1;
    float v0 = 0.0f, v1 = 0.0f;
    if (node < n) {
      const float2 v = __half22float2(ah[(size_t)node * 32 + kp]);
      v0 = v.x * bn[128 + k0] + bn[192 + k0];
      v1 = v.y * bn[128 + k1] + bn[192 + k1];
      v0 = v0 > 0.0f ? v0 : 0.0f;
      v1 = v1 > 0.0f ? v1 : 0.0f;
    }
    shin[(i >> 5) * 64 + k0] = v0;
    shin[(i >> 5) * 64 + k1] = v1;
  }
  for (int i = tid; i < 64 * 32; i += 256) shw[i] = W3[i];
  __syncthreads();

  const int nl = tid >> 4;
  const int c = (tid & 15) * 2;
  const int node = nodeBase + nl;
  if (node >= n) return;
  float a0 = 0.0f, a1 = 0.0f;
#pragma unroll
  for (int k = 0; k < 64; ++k) {
    const float s = shin[nl * 64 + k];
    const float2 w = *reinterpret_cast<const float2*>(&shw[k * 32 + c]);
    a0 += s * w.x;
    a1 += s * w.y;
  }
  const float dn = dinv[node];
  reinterpret_cast<__half2*>(h3)[(size_t)node * 16 + (tid & 15)] =
      __floats2half2_rn(a0 * dn, a1 * dn);
}

// ============ gather h3' (C=32 fp16) + BN3 + ReLU + 32x2 linear + log_softmax ============
// 4 nodes/wave; per node 4 groups x 4 lanes; unroll x2 (32 loads in flight/wave).
__global__ void gather_cls(const __half* __restrict__ h, const float* __restrict__ dinv,
                           const int* __restrict__ row_ptr, const int* __restrict__ edata,
                           const float* __restrict__ bn, const float* __restrict__ Wc,
                           const float* __restrict__ bc, float* __restrict__ out, int n) {
  const int wave = (int)(((long long)blockIdx.x * blockDim.x + threadIdx.x) >> 6);
  const int lane = threadIdx.x & 63;
  const int nl = lane >> 4;        // node within wave (0..3)
  const int node = wave * 4 + nl;
  const int qi = lane & 3;         // uint4 index within 64B row
  const int grp = (lane >> 2) & 3; // 4 groups per node
  if (node >= n) return;
  const int beg = row_ptr[node], end = row_ptr[node + 1];
  const uint4* hv = reinterpret_cast<const uint4*>(h);
  float a0 = 0, a1 = 0, a2 = 0, a3 = 0, a4 = 0, a5 = 0, a6 = 0, a7 = 0;
  int e = beg + grp;
  for (; e + 4 < end; e += 8) {
    const uint4 q0 = hv[(size_t)edata[e] * 4 + qi];
    const uint4 q1 = hv[(size_t)edata[e + 4] * 4 + qi];
    float2 f;
    f = u2f(q0.x); a0 += f.x; a1 += f.y;
    f = u2f(q0.y); a2 += f.x; a3 += f.y;
    f = u2f(q0.z); a4 += f.x; a5 += f.y;
    f = u2f(q0.w); a6 += f.x; a7 += f.y;
    f = u2f(q1.x); a0 += f.x; a1 += f.y;
    f = u2f(q1.y); a2 += f.x; a3 += f.y;
    f = u2f(q1.z); a4 += f.x; a5 += f.y;
    f = u2f(q1.w); a6 += f.x; a7 += f.y;
  }
  if (e < end) {
    const uint4 q = hv[(size_t)edata[e] * 4 + qi];
    float2 f;
    f = u2f(q.x); a0 += f.x; a1 += f.y;
    f = u2f(q.y); a2 += f.x; a3 += f.y;
    f = u2f(q.z); a4 += f.x; a5 += f.y;
    f = u2f(q.w); a6 += f.x; a7 += f.y;
  }
  // reduce across the 4 groups (lane bits 2-3)
#pragma unroll
  for (int m = 4; m <= 8; m <<= 1) {
    a0 += __shfl_xor(a0, m); a1 += __shfl_xor(a1, m);
    a2 += __shfl_xor(a2, m); a3 += __shfl_xor(a3, m);
    a4 += __shfl_xor(a4, m); a5 += __shfl_xor(a5, m);
    a6 += __shfl_xor(a6, m); a7 += __shfl_xor(a7, m);
  }
  if (grp != 0) return;
  // self term
  {
    const uint4 q = hv[(size_t)node * 4 + qi];
    float2 f;
    f = u2f(q.x); a0 += f.x; a1 += f.y;
    f = u2f(q.y); a2 += f.x; a3 += f.y;
    f = u2f(q.z); a4 += f.x; a5 += f.y;
    f = u2f(q.w); a6 += f.x; a7 += f.y;
  }
  const float dn = dinv[node];
  const float v[8] = {a0 * dn, a1 * dn, a2 * dn, a3 * dn, a4 * dn, a5 * dn, a6 * dn, a7 * dn};
  float l0 = 0.0f, l1 = 0.0f;
#pragma unroll
  for (int j = 0; j < 8; ++j) {
    const int c = qi * 8 + j;
    float t = v[j] * bn[256 + c] + bn[288 + c];
    t = t > 0.0f ? t : 0.0f;
    const float2 w = *reinterpret_cast<const float2*>(&Wc[c * 2]);
    l0 += t * w.x;
    l1 += t * w.y;
  }
  l0 += __shfl_xor(l0, 1); l1 += __shfl_xor(l1, 1);
  l0 += __shfl_xor(l0, 2); l1 += __shfl_xor(l1, 2);
  if (qi == 0) {
    l0 += bc[0];
    l1 += bc[1];
    const float m = fmaxf(l0, l1);
    const float lse = m + log1pf(expf(-fabsf(l0 - l1)));
    *reinterpret_cast<float2*>(&out[(size_t)node * 2]) = make_float2(l0 - lse, l1 - lse);
  }
}

// ============ launch ============
extern "C" void kernel_launch(void* const* d_in, const int* in_sizes, int n_in,
                              void* d_out, int out_size, void* d_ws, size_t ws_size,
                              hipStream_t stream) {
  const float* x  = (const float*)d_in[0];
  const int* ei   = (const int*)d_in[1];   // int32 on device per harness contract
  const float* W1 = (const float*)d_in[2];
  const float* b1 = (const float*)d_in[3];
  const float* g1 = (const float*)d_in[4];
  const float* be1 = (const float*)d_in[5];
  const float* rm1 = (const float*)d_in[6];
  const float* rv1 = (const float*)d_in[7];
  const float* W2 = (const float*)d_in[8];
  const float* b2 = (const float*)d_in[9];
  const float* g2 = (const float*)d_in[10];
  const float* be2 = (const float*)d_in[11];
  const float* rm2 = (const float*)d_in[12];
  const float* rv2 = (const float*)d_in[13];
  const float* W3 = (const float*)d_in[14];
  const float* b3 = (const float*)d_in[15];
  const float* g3 = (const float*)d_in[16];
  const float* be3 = (const float*)d_in[17];
  const float* rm3 = (const float*)d_in[18];
  const float* rv3 = (const float*)d_in[19];
  const float* Wc = (const float*)d_in[20];
  const float* bc = (const float*)d_in[21];

  const int N_ = in_sizes[0] / 8;
  const int E_ = in_sizes[1] / 2;
  const int NB = (N_ + 255) >> 8;          // 256-node buckets
  const int nbW = (N_ + 3) / 4;            // 1 wave/node kernels

  auto align = [](size_t v) { return (v + 255) & ~(size_t)255; };
  char* ws = (char*)d_ws;
  size_t off = 0;
  float* dinv   = (float*)(ws + off); off += align((size_t)N_ * 4);
  int* bcur     = (int*)(ws + off);   off += align((size_t)NB * 4);
  int* row_ptr  = (int*)(ws + off);   off += align(((size_t)N_ + 1) * 4);
  int* gbase    = (int*)(ws + off);   off += align(520 * 4);
  float* bnbuf  = (float*)(ws + off); off += align(320 * 4);
  int* edata    = (int*)(ws + off);   off += align((size_t)E_ * 4);
  __half* xs    = (__half*)(ws + off); off += align((size_t)N_ * 8 * 2);
  float* aggx   = (float*)(ws + off); off += align((size_t)N_ * 8 * 4);
  // regionA: bucketbuf (16 MB) -> t1 fp16 (12.8) -> agg2 fp16 (12.8)
  char* regionA = ws + off;           off += align((size_t)NB * BCAP * 8);
  // regionB: h2' fp16 (12.8) -> h3' fp16 (6.4)
  char* regionB = ws + off;           off += align((size_t)N_ * 64 * 2);

  int2* bucketbuf = (int2*)regionA;
  __half* t1   = (__half*)regionA;   // after p2_sort consumed bucketbuf
  __half* agg2 = (__half*)regionA;   // after mm2 consumed t1
  __half* h2   = (__half*)regionB;
  __half* h3   = (__half*)regionB;   // after gather_h64 consumed h2

  // ---- bucketed CSR build (also produces dinv) + BN constant prep ----
  zero_int<<<(NB + 255) / 256, 256, 0, stream>>>(bcur, NB);
  bn_prep<<<1, 256, 0, stream>>>(b1, g1, be1, rm1, rv1, b2, g2, be2, rm2, rv2,
                                 b3, g3, be3, rm3, rv3, bnbuf);
  p1_partition<<<(E_ + 4095) / 4096, 256, 0, stream>>>(ei, bucketbuf, bcur, E_, NB);
  scan_buckets<<<1, 512, 0, stream>>>(bcur, gbase, NB, E_, row_ptr, N_);
  p2_sort<<<NB, 256, 0, stream>>>(bucketbuf, gbase, edata, row_ptr, dinv, N_);

  // ---- layer 1: xs = fp16(dinv*x), gather (8 nodes/wave), fused matmul+BN1+ReLU ----
  scale_x<<<(N_ * 4 + 255) / 256, 256, 0, stream>>>(x, dinv, (__half2*)xs, N_ * 4);
  gather_x<<<(N_ + 31) / 32, 256, 0, stream>>>(xs, dinv, row_ptr, edata, aggx, N_);
  mm1_act<<<(N_ + 7) / 8, 256, 0, stream>>>(aggx, W1, bnbuf, t1, N_);

  // ---- layer 2: h2' = fp16(dinv*(t1 @ W2)), gather -> agg2 fp16 ----
  mm2<<<(N_ + 7) / 8, 256, 0, stream>>>(t1, W2, dinv, h2, N_);
  gather_h64<<<nbW, 256, 0, stream>>>(h2, dinv, row_ptr, edata, agg2, N_);

  // ---- layer 3: h3' = fp16(dinv*(relu(agg2*sc2+sh2) @ W3)), gather (4 nodes/wave) + classifier ----
  mm3_act<<<(N_ + 15) / 16, 256, 0, stream>>>(agg2, W3, bnbuf, dinv, h3, N_);
  gather_cls<<<(N_ + 15) / 16, 256, 0, stream>>>(h3, dinv, row_ptr, edata,
                                                 bnbuf, Wc, bc, (float*)d_out, N_);
}

// Round 9
// 193.108 us; speedup vs baseline: 18.5461x; 1.0477x over previous
//
#include <hip/hip_runtime.h>
#include <hip/hip_fp16.h>

#define BN_EPS 1e-5f
#define BCAP 5120   // bucket capacity; mean 4096 edges/bucket, large safety margin

__device__ __forceinline__ float2 u2f(unsigned u) {
  __half2 h = *reinterpret_cast<__half2*>(&u);
  return __half22float2(h);
}
__device__ __forceinline__ unsigned f2u(float a, float b) {
  __half2 h = __floats2half2_rn(a, b);
  return *reinterpret_cast<unsigned*>(&h);
}
__device__ __forceinline__ __half2 uh2(unsigned u) {
  return *reinterpret_cast<__half2*>(&u);
}
__device__ __forceinline__ __half2 h2shfl_xor(__half2 v, int m) {
  int i = *reinterpret_cast<int*>(&v);
  i = __shfl_xor(i, m);
  return *reinterpret_cast<__half2*>(&i);
}

// ============ CSR build (bucketed two-phase sort; degrees fall out of phase 2) ============
__global__ void zero_int(int* __restrict__ p, int n) {
  int i = blockIdx.x * blockDim.x + threadIdx.x;
  if (i < n) p[i] = 0;
}

// Phase 1: partition edges into per-bucket regions (bucket = dst>>8).
__global__ void p1_partition(const int* __restrict__ ei, int2* __restrict__ bucketbuf,
                             int* __restrict__ bcur, int E_, int NB) {
  __shared__ int hist[512];
  __shared__ int bbase[512];
  const int tid = threadIdx.x;
  const int e0 = blockIdx.x * 4096;
  const int ecount = min(4096, E_ - e0);
  for (int i = tid; i < NB; i += 256) hist[i] = 0;
  __syncthreads();
  for (int i = tid; i < ecount; i += 256) {
    const int d = ei[(size_t)E_ + e0 + i];
    atomicAdd(&hist[d >> 8], 1);
  }
  __syncthreads();
  for (int i = tid; i < NB; i += 256) {
    const int c = hist[i];
    bbase[i] = c ? atomicAdd(&bcur[i], c) : 0;
    hist[i] = 0;  // reuse as local cursor
  }
  __syncthreads();
  for (int i = tid; i < ecount; i += 256) {
    const int s = ei[e0 + i];
    const int d = ei[(size_t)E_ + e0 + i];
    const int b = d >> 8;
    const int slot = bbase[b] + atomicAdd(&hist[b], 1);
    bucketbuf[(size_t)b * BCAP + slot] = make_int2(s, d);
  }
}

// exclusive scan over NB bucket counts (NB <= 512); also sets row_ptr[N]=E.
__global__ void scan_buckets(const int* __restrict__ bcur, int* __restrict__ gbase,
                             int NB, int E_, int* __restrict__ row_ptr, int N_) {
  __shared__ int sh[512];
  const int t = threadIdx.x;
  const int v = (t < NB) ? bcur[t] : 0;
  sh[t] = v;
  __syncthreads();
  for (int off = 1; off < 512; off <<= 1) {
    int u = (t >= off) ? sh[t - off] : 0;
    __syncthreads();
    sh[t] += u;
    __syncthreads();
  }
  if (t < NB) gbase[t] = sh[t] - v;  // exclusive
  if (t == 0) { gbase[NB] = E_; row_ptr[N_] = E_; }
}

// Phase 2: per-bucket counting sort in LDS; emits row_ptr AND dinv.
__global__ void p2_sort(const int2* __restrict__ bucketbuf, const int* __restrict__ gbase,
                        int* __restrict__ edata, int* __restrict__ row_ptr,
                        float* __restrict__ dinv, int N_) {
  __shared__ int cntl[256];
  __shared__ int scn[256];
  __shared__ int cur[256];
  __shared__ int sbuf[BCAP];
  const int b = blockIdx.x;
  const int tid = threadIdx.x;
  const int base = gbase[b];
  const int m = gbase[b + 1] - base;
  const int2* srcp = bucketbuf + (size_t)b * BCAP;
  cntl[tid] = 0;
  __syncthreads();
  for (int i = tid; i < m; i += 256) atomicAdd(&cntl[srcp[i].y & 255], 1);
  __syncthreads();
  const int v = cntl[tid];
  scn[tid] = v;
  __syncthreads();
  for (int off = 1; off < 256; off <<= 1) {
    int u = (tid >= off) ? scn[tid - off] : 0;
    __syncthreads();
    scn[tid] += u;
    __syncthreads();
  }
  const int excl = scn[tid] - v;
  cur[tid] = excl;
  const int node = (b << 8) + tid;
  if (node < N_) {
    row_ptr[node] = base + excl;
    dinv[node] = rsqrtf((float)v + 1.0f);   // deg = in-degree + self-loop
  }
  __syncthreads();
  for (int i = tid; i < m; i += 256) {
    const int2 sd = srcp[i];
    const int slot = atomicAdd(&cur[sd.y & 255], 1);
    sbuf[slot] = sd.x;
  }
  __syncthreads();
  for (int i = tid; i < m; i += 256) edata[(size_t)base + i] = sbuf[i];
}

// ============ BN constant prep: sc/sh for all three BN layers ============
// bn layout: sc1[64] | sh1[64] | sc2[64] | sh2[64] | sc3[32] | sh3[32]
__global__ void bn_prep(const float* __restrict__ b1, const float* __restrict__ g1,
                        const float* __restrict__ be1, const float* __restrict__ rm1,
                        const float* __restrict__ rv1,
                        const float* __restrict__ b2, const float* __restrict__ g2,
                        const float* __restrict__ be2, const float* __restrict__ rm2,
                        const float* __restrict__ rv2,
                        const float* __restrict__ b3, const float* __restrict__ g3,
                        const float* __restrict__ be3, const float* __restrict__ rm3,
                        const float* __restrict__ rv3,
                        float* __restrict__ bn) {
  const int t = threadIdx.x;
  if (t < 64) {
    const float s = g1[t] * rsqrtf(rv1[t] + BN_EPS);
    bn[t] = s;
    bn[64 + t] = (b1[t] - rm1[t]) * s + be1[t];
  } else if (t < 128) {
    const int c = t - 64;
    const float s = g2[c] * rsqrtf(rv2[c] + BN_EPS);
    bn[128 + c] = s;
    bn[192 + c] = (b2[c] - rm2[c]) * s + be2[c];
  } else if (t < 160) {
    const int c = t - 128;
    const float s = g3[c] * rsqrtf(rv3[c] + BN_EPS);
    bn[256 + c] = s;
    bn[288 + c] = (b3[c] - rm3[c]) * s + be3[c];
  }
}

// ============ xs = fp16(x * dinv) ============
__global__ void scale_x(const float* __restrict__ x, const float* __restrict__ dinv,
                        __half2* __restrict__ xs, int n4) {
  const int i = blockIdx.x * blockDim.x + threadIdx.x;
  if (i < n4) {
    const float dn = dinv[i >> 2];
    const float2 v = reinterpret_cast<const float2*>(x)[i];
    xs[i] = __floats2half2_rn(v.x * dn, v.y * dn);
  }
}

// ============ gather on xs (C=8 fp16): 8 nodes/wave, 1 lane = 1 edge row (uint4) ============
// packed-fp16 accumulation (4 x half2), fp32 restored in epilogue.
__global__ void gather_x(const __half* __restrict__ xs, const float* __restrict__ dinv,
                         const int* __restrict__ row_ptr, const int* __restrict__ edata,
                         float* __restrict__ aggx, int n) {
  const int wave = (int)(((long long)blockIdx.x * blockDim.x + threadIdx.x) >> 6);
  const int lane = threadIdx.x & 63;
  const int nl = lane >> 3;      // node within wave (0..7)
  const int grp = lane & 7;      // 8 groups x 1 lane
  const int node = wave * 8 + nl;
  if (node >= n) return;
  const int beg = row_ptr[node], end = row_ptr[node + 1];
  const uint4* xv = reinterpret_cast<const uint4*>(xs);
  __half2 c0 = __half2{0, 0}, c1 = c0, c2 = c0, c3 = c0;
  int e = beg + grp;
  for (; e + 8 < end; e += 16) {
    const uint4 q0 = xv[edata[e]];
    const uint4 q1 = xv[edata[e + 8]];
    c0 = __hadd2(c0, uh2(q0.x)); c1 = __hadd2(c1, uh2(q0.y));
    c2 = __hadd2(c2, uh2(q0.z)); c3 = __hadd2(c3, uh2(q0.w));
    c0 = __hadd2(c0, uh2(q1.x)); c1 = __hadd2(c1, uh2(q1.y));
    c2 = __hadd2(c2, uh2(q1.z)); c3 = __hadd2(c3, uh2(q1.w));
  }
  if (e < end) {
    const uint4 q = xv[edata[e]];
    c0 = __hadd2(c0, uh2(q.x)); c1 = __hadd2(c1, uh2(q.y));
    c2 = __hadd2(c2, uh2(q.z)); c3 = __hadd2(c3, uh2(q.w));
  }
#pragma unroll
  for (int m = 1; m <= 4; m <<= 1) {
    c0 = __hadd2(c0, h2shfl_xor(c0, m));
    c1 = __hadd2(c1, h2shfl_xor(c1, m));
    c2 = __hadd2(c2, h2shfl_xor(c2, m));
    c3 = __hadd2(c3, h2shfl_xor(c3, m));
  }
  if (grp == 0) {
    const uint4 q = xv[node];  // self term
    c0 = __hadd2(c0, uh2(q.x)); c1 = __hadd2(c1, uh2(q.y));
    c2 = __hadd2(c2, uh2(q.z)); c3 = __hadd2(c3, uh2(q.w));
    const float dn = dinv[node];
    const float2 f0 = __half22float2(c0), f1 = __half22float2(c1);
    const float2 f2 = __half22float2(c2), f3 = __half22float2(c3);
    float4* op = reinterpret_cast<float4*>(&aggx[(size_t)node * 8]);
    op[0] = make_float4(f0.x * dn, f0.y * dn, f1.x * dn, f1.y * dn);
    op[1] = make_float4(f2.x * dn, f2.y * dn, f3.x * dn, f3.y * dn);
  }
}

// ============ mm1: t1 = fp16(relu(aggx @ W1 * sc1 + sh1))  [8 -> 64] ============
__global__ void mm1_act(const float* __restrict__ aggx, const float* __restrict__ W1,
                        const float* __restrict__ bn, __half* __restrict__ t1, int n) {
  constexpr int ROWS = 8;
  __shared__ float shin[ROWS * 8];
  __shared__ float shw[8 * 64];
  const int tid = threadIdx.x;
  const int nodeBase = blockIdx.x * ROWS;
  for (int i = tid; i < ROWS * 8; i += 256) {
    const int node = nodeBase + i / 8;
    shin[i] = (node < n) ? aggx[(size_t)node * 8 + (i & 7)] : 0.0f;
  }
  for (int i = tid; i < 8 * 64; i += 256) shw[i] = W1[i];
  __syncthreads();

  const int nl = tid >> 5;
  const int c = (tid & 31) * 2;
  const int node = nodeBase + nl;
  if (node >= n) return;
  float a0 = 0.0f, a1 = 0.0f;
#pragma unroll
  for (int k = 0; k < 8; ++k) {
    const float s = shin[nl * 8 + k];
    const float2 w = *reinterpret_cast<const float2*>(&shw[k * 64 + c]);
    a0 += s * w.x;
    a1 += s * w.y;
  }
  float v0 = a0 * bn[c] + bn[64 + c];
  float v1 = a1 * bn[c + 1] + bn[64 + c + 1];
  v0 = v0 > 0.0f ? v0 : 0.0f;
  v1 = v1 > 0.0f ? v1 : 0.0f;
  reinterpret_cast<__half2*>(t1)[(size_t)node * 32 + (tid & 31)] = __floats2half2_rn(v0, v1);
}

// ============ mm2: h2' = fp16(dinv * (t1 @ W2))  [64 -> 64] ============
__global__ void mm2(const __half* __restrict__ t1, const float* __restrict__ W2,
                    const float* __restrict__ dinv, __half* __restrict__ h2, int n) {
  constexpr int ROWS = 8;
  __shared__ float shin[ROWS * 64];
  __shared__ float shw[64 * 64];
  const int tid = threadIdx.x;
  const int nodeBase = blockIdx.x * ROWS;
  const __half2* t1h = reinterpret_cast<const __half2*>(t1);
  for (int i = tid; i < ROWS * 32; i += 256) {
    const int node = nodeBase + (i >> 5);
    float2 v = make_float2(0.0f, 0.0f);
    if (node < n) v = __half22float2(t1h[(size_t)node * 32 + (i & 31)]);
    shin[(i >> 5) * 64 + (i & 31) * 2] = v.x;
    shin[(i >> 5) * 64 + (i & 31) * 2 + 1] = v.y;
  }
  for (int i = tid; i < 64 * 64; i += 256) shw[i] = W2[i];
  __syncthreads();

  const int nl = tid >> 5;
  const int c = (tid & 31) * 2;
  const int node = nodeBase + nl;
  if (node >= n) return;
  float a0 = 0.0f, a1 = 0.0f;
#pragma unroll
  for (int k = 0; k < 64; ++k) {
    const float s = shin[nl * 64 + k];
    const float2 w = *reinterpret_cast<const float2*>(&shw[k * 64 + c]);
    a0 += s * w.x;
    a1 += s * w.y;
  }
  const float dn = dinv[node];
  reinterpret_cast<__half2*>(h2)[(size_t)node * 32 + (tid & 31)] =
      __floats2half2_rn(a0 * dn, a1 * dn);
}

// ============ gather h2' (C=64 fp16): 2 nodes/wave, 4 groups x 8 lanes, half2 accum ============
__global__ void gather_h64(const __half* __restrict__ h, const float* __restrict__ dinv,
                           const int* __restrict__ row_ptr, const int* __restrict__ edata,
                           __half* __restrict__ agg, int n) {
  const int wave = (int)(((long long)blockIdx.x * blockDim.x + threadIdx.x) >> 6);
  const int lane = threadIdx.x & 63;
  const int node = wave * 2 + (lane >> 5);
  const int sub = lane & 31;
  const int qi = sub & 7;     // uint4 index within 128B row
  const int grp = sub >> 3;   // 4 groups per node
  if (node >= n) return;
  const int beg = row_ptr[node], end = row_ptr[node + 1];
  const uint4* hv = reinterpret_cast<const uint4*>(h);
  __half2 c0 = __half2{0, 0}, c1 = c0, c2 = c0, c3 = c0;
  int e = beg + grp;
  for (; e + 4 < end; e += 8) {
    const uint4 q0 = hv[(size_t)edata[e] * 8 + qi];
    const uint4 q1 = hv[(size_t)edata[e + 4] * 8 + qi];
    c0 = __hadd2(c0, uh2(q0.x)); c1 = __hadd2(c1, uh2(q0.y));
    c2 = __hadd2(c2, uh2(q0.z)); c3 = __hadd2(c3, uh2(q0.w));
    c0 = __hadd2(c0, uh2(q1.x)); c1 = __hadd2(c1, uh2(q1.y));
    c2 = __hadd2(c2, uh2(q1.z)); c3 = __hadd2(c3, uh2(q1.w));
  }
  if (e < end) {
    const uint4 q = hv[(size_t)edata[e] * 8 + qi];
    c0 = __hadd2(c0, uh2(q.x)); c1 = __hadd2(c1, uh2(q.y));
    c2 = __hadd2(c2, uh2(q.z)); c3 = __hadd2(c3, uh2(q.w));
  }
  // reduce across 4 groups (lane bits 3-4; stays within the 32-lane node half)
#pragma unroll
  for (int m = 8; m <= 16; m <<= 1) {
    c0 = __hadd2(c0, h2shfl_xor(c0, m));
    c1 = __hadd2(c1, h2shfl_xor(c1, m));
    c2 = __hadd2(c2, h2shfl_xor(c2, m));
    c3 = __hadd2(c3, h2shfl_xor(c3, m));
  }
  if (grp == 0) {
    const uint4 q = hv[(size_t)node * 8 + qi];  // self term
    c0 = __hadd2(c0, uh2(q.x)); c1 = __hadd2(c1, uh2(q.y));
    c2 = __hadd2(c2, uh2(q.z)); c3 = __hadd2(c3, uh2(q.w));
    const float dn = dinv[node];
    const float2 f0 = __half22float2(c0), f1 = __half22float2(c1);
    const float2 f2 = __half22float2(c2), f3 = __half22float2(c3);
    uint4 o;
    o.x = f2u(f0.x * dn, f0.y * dn);
    o.y = f2u(f1.x * dn, f1.y * dn);
    o.z = f2u(f2.x * dn, f2.y * dn);
    o.w = f2u(f3.x * dn, f3.y * dn);
    reinterpret_cast<uint4*>(agg)[(size_t)node * 8 + qi] = o;
  }
}

// ============ mm3: h3' = fp16(dinv * (relu(agg2*sc2+sh2) @ W3))  [64 -> 32] ============
__global__ void mm3_act(const __half* __restrict__ agg2, const float* __restrict__ W3,
                        const float* __restrict__ bn, const float* __restrict__ dinv,
                        __half* __restrict__ h3, int n) {
  constexpr int ROWS = 16;
  __shared__ float shin[ROWS * 64];
  __shared__ float shw[64 * 32];
  const int tid = threadIdx.x;
  const int nodeBase = blockIdx.x * ROWS;
  const __half2* ah = reinterpret_cast<const __half2*>(agg2);
  for (int i = tid; i < ROWS * 32; i += 256) {
    const int node = nodeBase + (i >> 5);
    const int kp = i & 31;
    const int k0 = kp * 2, k1 = kp * 2 + 1;
    float v0 = 0.0f, v1 = 0.0f;
    if (node < n) {
      const float2 v = __half22float2(ah[(size_t)node * 32 + kp]);
      v0 = v.x * bn[128 + k0] + bn[192 + k0];
      v1 = v.y * bn[128 + k1] + bn[192 + k1];
      v0 = v0 > 0.0f ? v0 : 0.0f;
      v1 = v1 > 0.0f ? v1 : 0.0f;
    }
    shin[(i >> 5) * 64 + k0] = v0;
    shin[(i >> 5) * 64 + k1] = v1;
  }
  for (int i = tid; i < 64 * 32; i += 256) shw[i] = W3[i];
  __syncthreads();

  const int nl = tid >> 4;
  const int c = (tid & 15) * 2;
  const int node = nodeBase + nl;
  if (node >= n) return;
  float a0 = 0.0f, a1 = 0.0f;
#pragma unroll
  for (int k = 0; k < 64; ++k) {
    const float s = shin[nl * 64 + k];
    const float2 w = *reinterpret_cast<const float2*>(&shw[k * 32 + c]);
    a0 += s * w.x;
    a1 += s * w.y;
  }
  const float dn = dinv[node];
  reinterpret_cast<__half2*>(h3)[(size_t)node * 16 + (tid & 15)] =
      __floats2half2_rn(a0 * dn, a1 * dn);
}

// ============ gather h3' (C=32 fp16) + BN3 + ReLU + 32x2 linear + log_softmax ============
// 4 nodes/wave; per node 4 groups x 4 lanes; half2 accumulation; unroll x2.
__global__ void gather_cls(const __half* __restrict__ h, const float* __restrict__ dinv,
                           const int* __restrict__ row_ptr, const int* __restrict__ edata,
                           const float* __restrict__ bn, const float* __restrict__ Wc,
                           const float* __restrict__ bc, float* __restrict__ out, int n) {
  const int wave = (int)(((long long)blockIdx.x * blockDim.x + threadIdx.x) >> 6);
  const int lane = threadIdx.x & 63;
  const int nl = lane >> 4;        // node within wave (0..3)
  const int node = wave * 4 + nl;
  const int qi = lane & 3;         // uint4 index within 64B row
  const int grp = (lane >> 2) & 3; // 4 groups per node
  if (node >= n) return;
  const int beg = row_ptr[node], end = row_ptr[node + 1];
  const uint4* hv = reinterpret_cast<const uint4*>(h);
  __half2 c0 = __half2{0, 0}, c1 = c0, c2 = c0, c3 = c0;
  int e = beg + grp;
  for (; e + 4 < end; e += 8) {
    const uint4 q0 = hv[(size_t)edata[e] * 4 + qi];
    const uint4 q1 = hv[(size_t)edata[e + 4] * 4 + qi];
    c0 = __hadd2(c0, uh2(q0.x)); c1 = __hadd2(c1, uh2(q0.y));
    c2 = __hadd2(c2, uh2(q0.z)); c3 = __hadd2(c3, uh2(q0.w));
    c0 = __hadd2(c0, uh2(q1.x)); c1 = __hadd2(c1, uh2(q1.y));
    c2 = __hadd2(c2, uh2(q1.z)); c3 = __hadd2(c3, uh2(q1.w));
  }
  if (e < end) {
    const uint4 q = hv[(size_t)edata[e] * 4 + qi];
    c0 = __hadd2(c0, uh2(q.x)); c1 = __hadd2(c1, uh2(q.y));
    c2 = __hadd2(c2, uh2(q.z)); c3 = __hadd2(c3, uh2(q.w));
  }
  // reduce across the 4 groups (lane bits 2-3)
#pragma unroll
  for (int m = 4; m <= 8; m <<= 1) {
    c0 = __hadd2(c0, h2shfl_xor(c0, m));
    c1 = __hadd2(c1, h2shfl_xor(c1, m));
    c2 = __hadd2(c2, h2shfl_xor(c2, m));
    c3 = __hadd2(c3, h2shfl_xor(c3, m));
  }
  if (grp != 0) return;
  // self term
  {
    const uint4 q = hv[(size_t)node * 4 + qi];
    c0 = __hadd2(c0, uh2(q.x)); c1 = __hadd2(c1, uh2(q.y));
    c2 = __hadd2(c2, uh2(q.z)); c3 = __hadd2(c3, uh2(q.w));
  }
  const float dn = dinv[node];
  const float2 f0 = __half22float2(c0), f1 = __half22float2(c1);
  const float2 f2 = __half22float2(c2), f3 = __half22float2(c3);
  const float v[8] = {f0.x * dn, f0.y * dn, f1.x * dn, f1.y * dn,
                      f2.x * dn, f2.y * dn, f3.x * dn, f3.y * dn};
  float l0 = 0.0f, l1 = 0.0f;
#pragma unroll
  for (int j = 0; j < 8; ++j) {
    const int c = qi * 8 + j;
    float t = v[j] * bn[256 + c] + bn[288 + c];
    t = t > 0.0f ? t : 0.0f;
    const float2 w = *reinterpret_cast<const float2*>(&Wc[c * 2]);
    l0 += t * w.x;
    l1 += t * w.y;
  }
  l0 += __shfl_xor(l0, 1); l1 += __shfl_xor(l1, 1);
  l0 += __shfl_xor(l0, 2); l1 += __shfl_xor(l1, 2);
  if (qi == 0) {
    l0 += bc[0];
    l1 += bc[1];
    const float m = fmaxf(l0, l1);
    const float lse = m + log1pf(expf(-fabsf(l0 - l1)));
    *reinterpret_cast<float2*>(&out[(size_t)node * 2]) = make_float2(l0 - lse, l1 - lse);
  }
}

// ============ launch ============
extern "C" void kernel_launch(void* const* d_in, const int* in_sizes, int n_in,
                              void* d_out, int out_size, void* d_ws, size_t ws_size,
                              hipStream_t stream) {
  const float* x  = (const float*)d_in[0];
  const int* ei   = (const int*)d_in[1];   // int32 on device per harness contract
  const float* W1 = (const float*)d_in[2];
  const float* b1 = (const float*)d_in[3];
  const float* g1 = (const float*)d_in[4];
  const float* be1 = (const float*)d_in[5];
  const float* rm1 = (const float*)d_in[6];
  const float* rv1 = (const float*)d_in[7];
  const float* W2 = (const float*)d_in[8];
  const float* b2 = (const float*)d_in[9];
  const float* g2 = (const float*)d_in[10];
  const float* be2 = (const float*)d_in[11];
  const float* rm2 = (const float*)d_in[12];
  const float* rv2 = (const float*)d_in[13];
  const float* W3 = (const float*)d_in[14];
  const float* b3 = (const float*)d_in[15];
  const float* g3 = (const float*)d_in[16];
  const float* be3 = (const float*)d_in[17];
  const float* rm3 = (const float*)d_in[18];
  const float* rv3 = (const float*)d_in[19];
  const float* Wc = (const float*)d_in[20];
  const float* bc = (const float*)d_in[21];

  const int N_ = in_sizes[0] / 8;
  const int E_ = in_sizes[1] / 2;
  const int NB = (N_ + 255) >> 8;          // 256-node buckets

  auto align = [](size_t v) { return (v + 255) & ~(size_t)255; };
  char* ws = (char*)d_ws;
  size_t off = 0;
  float* dinv   = (float*)(ws + off); off += align((size_t)N_ * 4);
  int* bcur     = (int*)(ws + off);   off += align((size_t)NB * 4);
  int* row_ptr  = (int*)(ws + off);   off += align(((size_t)N_ + 1) * 4);
  int* gbase    = (int*)(ws + off);   off += align(520 * 4);
  float* bnbuf  = (float*)(ws + off); off += align(320 * 4);
  int* edata    = (int*)(ws + off);   off += align((size_t)E_ * 4);
  __half* xs    = (__half*)(ws + off); off += align((size_t)N_ * 8 * 2);
  float* aggx   = (float*)(ws + off); off += align((size_t)N_ * 8 * 4);
  // regionA: bucketbuf (16 MB) -> t1 fp16 (12.8) -> agg2 fp16 (12.8)
  char* regionA = ws + off;           off += align((size_t)NB * BCAP * 8);
  // regionB: h2' fp16 (12.8) -> h3' fp16 (6.4)
  char* regionB = ws + off;           off += align((size_t)N_ * 64 * 2);

  int2* bucketbuf = (int2*)regionA;
  __half* t1   = (__half*)regionA;   // after p2_sort consumed bucketbuf
  __half* agg2 = (__half*)regionA;   // after mm2 consumed t1
  __half* h2   = (__half*)regionB;
  __half* h3   = (__half*)regionB;   // after gather_h64 consumed h2

  // ---- bucketed CSR build (also produces dinv) + BN constant prep ----
  zero_int<<<(NB + 255) / 256, 256, 0, stream>>>(bcur, NB);
  bn_prep<<<1, 256, 0, stream>>>(b1, g1, be1, rm1, rv1, b2, g2, be2, rm2, rv2,
                                 b3, g3, be3, rm3, rv3, bnbuf);
  p1_partition<<<(E_ + 4095) / 4096, 256, 0, stream>>>(ei, bucketbuf, bcur, E_, NB);
  scan_buckets<<<1, 512, 0, stream>>>(bcur, gbase, NB, E_, row_ptr, N_);
  p2_sort<<<NB, 256, 0, stream>>>(bucketbuf, gbase, edata, row_ptr, dinv, N_);

  // ---- layer 1: xs = fp16(dinv*x), gather (8 nodes/wave), fused matmul+BN1+ReLU ----
  scale_x<<<(N_ * 4 + 255) / 256, 256, 0, stream>>>(x, dinv, (__half2*)xs, N_ * 4);
  gather_x<<<(N_ + 31) / 32, 256, 0, stream>>>(xs, dinv, row_ptr, edata, aggx, N_);
  mm1_act<<<(N_ + 7) / 8, 256, 0, stream>>>(aggx, W1, bnbuf, t1, N_);

  // ---- layer 2: h2' = fp16(dinv*(t1 @ W2)), gather (2 nodes/wave) -> agg2 fp16 ----
  mm2<<<(N_ + 7) / 8, 256, 0, stream>>>(t1, W2, dinv, h2, N_);
  gather_h64<<<(N_ + 7) / 8, 256, 0, stream>>>(h2, dinv, row_ptr, edata, agg2, N_);

  // ---- layer 3: h3' = fp16(dinv*(relu(agg2*sc2+sh2) @ W3)), gather (4 nodes/wave) + classifier ----
  mm3_act<<<(N_ + 15) / 16, 256, 0, stream>>>(agg2, W3, bnbuf, dinv, h3, N_);
  gather_cls<<<(N_ + 15) / 16, 256, 0, stream>>>(h3, dinv, row_ptr, edata,
                                                 bnbuf, Wc, bc, (float*)d_out, N_);
}

// Round 10
// 190.568 us; speedup vs baseline: 18.7933x; 1.0133x over previous
//
#include <hip/hip_runtime.h>
#include <hip/hip_fp16.h>

#define BN_EPS 1e-5f
#define BCAP 5120   // bucket capacity; mean 4096 edges/bucket, large safety margin

__device__ __forceinline__ unsigned f2u(float a, float b) {
  __half2 h = __floats2half2_rn(a, b);
  return *reinterpret_cast<unsigned*>(&h);
}
__device__ __forceinline__ __half2 uh2(unsigned u) {
  return *reinterpret_cast<__half2*>(&u);
}
__device__ __forceinline__ __half2 h2shfl_xor(__half2 v, int m) {
  int i = *reinterpret_cast<int*>(&v);
  i = __shfl_xor(i, m);
  return *reinterpret_cast<__half2*>(&i);
}

// ============ prep: block 0 computes BN constants; other blocks zero bcur ============
// bn layout: sc1[64] | sh1[64] | sc2[64] | sh2[64] | sc3[32] | sh3[32]
__global__ void prep(const float* __restrict__ b1, const float* __restrict__ g1,
                     const float* __restrict__ be1, const float* __restrict__ rm1,
                     const float* __restrict__ rv1,
                     const float* __restrict__ b2, const float* __restrict__ g2,
                     const float* __restrict__ be2, const float* __restrict__ rm2,
                     const float* __restrict__ rv2,
                     const float* __restrict__ b3, const float* __restrict__ g3,
                     const float* __restrict__ be3, const float* __restrict__ rm3,
                     const float* __restrict__ rv3,
                     float* __restrict__ bn, int* __restrict__ bcur, int NB) {
  if (blockIdx.x == 0) {
    const int t = threadIdx.x;
    if (t < 64) {
      const float s = g1[t] * rsqrtf(rv1[t] + BN_EPS);
      bn[t] = s;
      bn[64 + t] = (b1[t] - rm1[t]) * s + be1[t];
    } else if (t < 128) {
      const int c = t - 64;
      const float s = g2[c] * rsqrtf(rv2[c] + BN_EPS);
      bn[128 + c] = s;
      bn[192 + c] = (b2[c] - rm2[c]) * s + be2[c];
    } else if (t < 160) {
      const int c = t - 128;
      const float s = g3[c] * rsqrtf(rv3[c] + BN_EPS);
      bn[256 + c] = s;
      bn[288 + c] = (b3[c] - rm3[c]) * s + be3[c];
    }
  } else {
    const int i = (blockIdx.x - 1) * 256 + threadIdx.x;
    if (i < NB) bcur[i] = 0;
  }
}

// ============ Phase 1: partition edges into per-bucket regions (bucket = dst>>8) ============
// ei staged through LDS (read once); bucketbuf entry packed: (dst&255)<<24 | src.
__global__ void p1_partition(const int* __restrict__ ei, int* __restrict__ bucketbuf,
                             int* __restrict__ bcur, int E_, int NB) {
  __shared__ int pk[4096];
  __shared__ short bk[4096];
  __shared__ int hist[512];
  __shared__ int bbase[512];
  const int tid = threadIdx.x;
  const int e0 = blockIdx.x * 4096;
  const int ecount = min(4096, E_ - e0);
  for (int i = tid; i < NB; i += 256) hist[i] = 0;
  __syncthreads();
  for (int i = tid; i < ecount; i += 256) {
    const int s = ei[e0 + i];
    const int d = ei[(size_t)E_ + e0 + i];
    pk[i] = ((d & 255) << 24) | s;   // src < 2^24 (N = 100000)
    const int b = d >> 8;
    bk[i] = (short)b;
    atomicAdd(&hist[b], 1);
  }
  __syncthreads();
  for (int i = tid; i < NB; i += 256) {
    const int c = hist[i];
    bbase[i] = c ? atomicAdd(&bcur[i], c) : 0;
    hist[i] = 0;  // reuse as local cursor
  }
  __syncthreads();
  for (int i = tid; i < ecount; i += 256) {
    const int b = bk[i];
    const int slot = bbase[b] + atomicAdd(&hist[b], 1);
    bucketbuf[(size_t)b * BCAP + slot] = pk[i];
  }
}

// exclusive scan over NB bucket counts (NB <= 512); also sets row_ptr[N]=E.
__global__ void scan_buckets(const int* __restrict__ bcur, int* __restrict__ gbase,
                             int NB, int E_, int* __restrict__ row_ptr, int N_) {
  __shared__ int sh[512];
  const int t = threadIdx.x;
  const int v = (t < NB) ? bcur[t] : 0;
  sh[t] = v;
  __syncthreads();
  for (int off = 1; off < 512; off <<= 1) {
    int u = (t >= off) ? sh[t - off] : 0;
    __syncthreads();
    sh[t] += u;
    __syncthreads();
  }
  if (t < NB) gbase[t] = sh[t] - v;  // exclusive
  if (t == 0) { gbase[NB] = E_; row_ptr[N_] = E_; }
}

// ============ Phase 2: per-bucket counting sort; emits row_ptr, dinv AND xs=fp16(dinv*x) ============
__global__ void p2_sort(const int* __restrict__ bucketbuf, const int* __restrict__ gbase,
                        int* __restrict__ edata, int* __restrict__ row_ptr,
                        float* __restrict__ dinv, const float* __restrict__ x,
                        __half2* __restrict__ xs, int N_) {
  __shared__ int cntl[256];
  __shared__ int scn[256];
  __shared__ int cur[256];
  __shared__ float dinvl[256];
  __shared__ int sbuf[BCAP];
  const int b = blockIdx.x;
  const int tid = threadIdx.x;
  const int base = gbase[b];
  const int m = gbase[b + 1] - base;
  const int* srcp = bucketbuf + (size_t)b * BCAP;
  cntl[tid] = 0;
  __syncthreads();
  for (int i = tid; i < m; i += 256) atomicAdd(&cntl[(unsigned)srcp[i] >> 24], 1);
  __syncthreads();
  const int cnt = cntl[tid];
  scn[tid] = cnt;
  __syncthreads();
  for (int off = 1; off < 256; off <<= 1) {
    int u = (tid >= off) ? scn[tid - off] : 0;
    __syncthreads();
    scn[tid] += u;
    __syncthreads();
  }
  const int excl = scn[tid] - cnt;
  cur[tid] = excl;
  const int node = (b << 8) + tid;
  const float dn = rsqrtf((float)cnt + 1.0f);  // deg = in-degree + self-loop
  dinvl[tid] = dn;
  if (node < N_) {
    row_ptr[node] = base + excl;
    dinv[node] = dn;
  }
  __syncthreads();
  for (int i = tid; i < m; i += 256) {
    const int v = srcp[i];
    const int slot = atomicAdd(&cur[(unsigned)v >> 24], 1);
    sbuf[slot] = v & 0xFFFFFF;
  }
  __syncthreads();
  for (int i = tid; i < m; i += 256) edata[(size_t)base + i] = sbuf[i];
  // fused: xs = fp16(dinv * x) for this bucket's 256 nodes (coalesced x reads)
  const int nb0 = b << 8;
  for (int i = tid; i < 1024; i += 256) {
    const int nd = nb0 + (i >> 2);
    if (nd < N_) {
      const float d2 = dinvl[i >> 2];
      const float2 v2 = reinterpret_cast<const float2*>(x)[(size_t)nd * 4 + (i & 3)];
      xs[(size_t)nd * 4 + (i & 3)] = __floats2half2_rn(v2.x * d2, v2.y * d2);
    }
  }
}

// ============ gather on xs (C=8 fp16): 8 nodes/wave, 1 lane = 1 edge row (uint4) ============
__global__ void gather_x(const __half* __restrict__ xs, const float* __restrict__ dinv,
                         const int* __restrict__ row_ptr, const int* __restrict__ edata,
                         float* __restrict__ aggx, int n) {
  const int wave = (int)(((long long)blockIdx.x * blockDim.x + threadIdx.x) >> 6);
  const int lane = threadIdx.x & 63;
  const int nl = lane >> 3;      // node within wave (0..7)
  const int grp = lane & 7;      // 8 groups x 1 lane
  const int node = wave * 8 + nl;
  if (node >= n) return;
  const int beg = row_ptr[node], end = row_ptr[node + 1];
  const uint4* xv = reinterpret_cast<const uint4*>(xs);
  __half2 c0 = __half2{0, 0}, c1 = c0, c2 = c0, c3 = c0;
  int e = beg + grp;
  for (; e + 8 < end; e += 16) {
    const uint4 q0 = xv[edata[e]];
    const uint4 q1 = xv[edata[e + 8]];
    c0 = __hadd2(c0, uh2(q0.x)); c1 = __hadd2(c1, uh2(q0.y));
    c2 = __hadd2(c2, uh2(q0.z)); c3 = __hadd2(c3, uh2(q0.w));
    c0 = __hadd2(c0, uh2(q1.x)); c1 = __hadd2(c1, uh2(q1.y));
    c2 = __hadd2(c2, uh2(q1.z)); c3 = __hadd2(c3, uh2(q1.w));
  }
  if (e < end) {
    const uint4 q = xv[edata[e]];
    c0 = __hadd2(c0, uh2(q.x)); c1 = __hadd2(c1, uh2(q.y));
    c2 = __hadd2(c2, uh2(q.z)); c3 = __hadd2(c3, uh2(q.w));
  }
#pragma unroll
  for (int m = 1; m <= 4; m <<= 1) {
    c0 = __hadd2(c0, h2shfl_xor(c0, m));
    c1 = __hadd2(c1, h2shfl_xor(c1, m));
    c2 = __hadd2(c2, h2shfl_xor(c2, m));
    c3 = __hadd2(c3, h2shfl_xor(c3, m));
  }
  if (grp == 0) {
    const uint4 q = xv[node];  // self term
    c0 = __hadd2(c0, uh2(q.x)); c1 = __hadd2(c1, uh2(q.y));
    c2 = __hadd2(c2, uh2(q.z)); c3 = __hadd2(c3, uh2(q.w));
    const float dn = dinv[node];
    const float2 f0 = __half22float2(c0), f1 = __half22float2(c1);
    const float2 f2 = __half22float2(c2), f3 = __half22float2(c3);
    float4* op = reinterpret_cast<float4*>(&aggx[(size_t)node * 8]);
    op[0] = make_float4(f0.x * dn, f0.y * dn, f1.x * dn, f1.y * dn);
    op[1] = make_float4(f2.x * dn, f2.y * dn, f3.x * dn, f3.y * dn);
  }
}

// ============ mm1: t1 = fp16(relu(aggx @ W1 * sc1 + sh1))  [8 -> 64] ============
__global__ void mm1_act(const float* __restrict__ aggx, const float* __restrict__ W1,
                        const float* __restrict__ bn, __half* __restrict__ t1, int n) {
  constexpr int ROWS = 8;
  __shared__ float shin[ROWS * 8];
  __shared__ float shw[8 * 64];
  const int tid = threadIdx.x;
  const int nodeBase = blockIdx.x * ROWS;
  for (int i = tid; i < ROWS * 8; i += 256) {
    const int node = nodeBase + i / 8;
    shin[i] = (node < n) ? aggx[(size_t)node * 8 + (i & 7)] : 0.0f;
  }
  for (int i = tid; i < 8 * 64; i += 256) shw[i] = W1[i];
  __syncthreads();

  const int nl = tid >> 5;
  const int c = (tid & 31) * 2;
  const int node = nodeBase + nl;
  if (node >= n) return;
  float a0 = 0.0f, a1 = 0.0f;
#pragma unroll
  for (int k = 0; k < 8; ++k) {
    const float s = shin[nl * 8 + k];
    const float2 w = *reinterpret_cast<const float2*>(&shw[k * 64 + c]);
    a0 += s * w.x;
    a1 += s * w.y;
  }
  float v0 = a0 * bn[c] + bn[64 + c];
  float v1 = a1 * bn[c + 1] + bn[64 + c + 1];
  v0 = v0 > 0.0f ? v0 : 0.0f;
  v1 = v1 > 0.0f ? v1 : 0.0f;
  reinterpret_cast<__half2*>(t1)[(size_t)node * 32 + (tid & 31)] = __floats2half2_rn(v0, v1);
}

// ============ mm2: h2' = fp16(dinv * (t1 @ W2))  [64 -> 64] ============
__global__ void mm2(const __half* __restrict__ t1, const float* __restrict__ W2,
                    const float* __restrict__ dinv, __half* __restrict__ h2, int n) {
  constexpr int ROWS = 8;
  __shared__ float shin[ROWS * 64];
  __shared__ float shw[64 * 64];
  const int tid = threadIdx.x;
  const int nodeBase = blockIdx.x * ROWS;
  const __half2* t1h = reinterpret_cast<const __half2*>(t1);
  for (int i = tid; i < ROWS * 32; i += 256) {
    const int node = nodeBase + (i >> 5);
    float2 v = make_float2(0.0f, 0.0f);
    if (node < n) v = __half22float2(t1h[(size_t)node * 32 + (i & 31)]);
    shin[(i >> 5) * 64 + (i & 31) * 2] = v.x;
    shin[(i >> 5) * 64 + (i & 31) * 2 + 1] = v.y;
  }
  for (int i = tid; i < 64 * 64; i += 256) shw[i] = W2[i];
  __syncthreads();

  const int nl = tid >> 5;
  const int c = (tid & 31) * 2;
  const int node = nodeBase + nl;
  if (node >= n) return;
  float a0 = 0.0f, a1 = 0.0f;
#pragma unroll
  for (int k = 0; k < 64; ++k) {
    const float s = shin[nl * 64 + k];
    const float2 w = *reinterpret_cast<const float2*>(&shw[k * 64 + c]);
    a0 += s * w.x;
    a1 += s * w.y;
  }
  const float dn = dinv[node];
  reinterpret_cast<__half2*>(h2)[(size_t)node * 32 + (tid & 31)] =
      __floats2half2_rn(a0 * dn, a1 * dn);
}

// ============ gather h2' (C=64 fp16): 2 nodes/wave, 4 groups x 8 lanes, unroll-4 ============
__global__ void gather_h64(const __half* __restrict__ h, const float* __restrict__ dinv,
                           const int* __restrict__ row_ptr, const int* __restrict__ edata,
                           __half* __restrict__ agg, int n) {
  const int wave = (int)(((long long)blockIdx.x * blockDim.x + threadIdx.x) >> 6);
  const int lane = threadIdx.x & 63;
  const int node = wave * 2 + (lane >> 5);
  const int sub = lane & 31;
  const int qi = sub & 7;     // uint4 index within 128B row
  const int grp = sub >> 3;   // 4 groups per node
  if (node >= n) return;
  const int beg = row_ptr[node], end = row_ptr[node + 1];
  const uint4* hv = reinterpret_cast<const uint4*>(h);
  __half2 c0 = __half2{0, 0}, c1 = c0, c2 = c0, c3 = c0;
  int e = beg + grp;
  for (; e + 12 < end; e += 16) {
    const int s0 = edata[e];
    const int s1 = edata[e + 4];
    const int s2 = edata[e + 8];
    const int s3 = edata[e + 12];
    const uint4 q0 = hv[(size_t)s0 * 8 + qi];
    const uint4 q1 = hv[(size_t)s1 * 8 + qi];
    const uint4 q2 = hv[(size_t)s2 * 8 + qi];
    const uint4 q3 = hv[(size_t)s3 * 8 + qi];
    c0 = __hadd2(c0, uh2(q0.x)); c1 = __hadd2(c1, uh2(q0.y));
    c2 = __hadd2(c2, uh2(q0.z)); c3 = __hadd2(c3, uh2(q0.w));
    c0 = __hadd2(c0, uh2(q1.x)); c1 = __hadd2(c1, uh2(q1.y));
    c2 = __hadd2(c2, uh2(q1.z)); c3 = __hadd2(c3, uh2(q1.w));
    c0 = __hadd2(c0, uh2(q2.x)); c1 = __hadd2(c1, uh2(q2.y));
    c2 = __hadd2(c2, uh2(q2.z)); c3 = __hadd2(c3, uh2(q2.w));
    c0 = __hadd2(c0, uh2(q3.x)); c1 = __hadd2(c1, uh2(q3.y));
    c2 = __hadd2(c2, uh2(q3.z)); c3 = __hadd2(c3, uh2(q3.w));
  }
  for (; e < end; e += 4) {
    const uint4 q = hv[(size_t)edata[e] * 8 + qi];
    c0 = __hadd2(c0, uh2(q.x)); c1 = __hadd2(c1, uh2(q.y));
    c2 = __hadd2(c2, uh2(q.z)); c3 = __hadd2(c3, uh2(q.w));
  }
  // reduce across 4 groups (lane bits 3-4; stays within the 32-lane node half)
#pragma unroll
  for (int m = 8; m <= 16; m <<= 1) {
    c0 = __hadd2(c0, h2shfl_xor(c0, m));
    c1 = __hadd2(c1, h2shfl_xor(c1, m));
    c2 = __hadd2(c2, h2shfl_xor(c2, m));
    c3 = __hadd2(c3, h2shfl_xor(c3, m));
  }
  if (grp == 0) {
    const uint4 q = hv[(size_t)node * 8 + qi];  // self term
    c0 = __hadd2(c0, uh2(q.x)); c1 = __hadd2(c1, uh2(q.y));
    c2 = __hadd2(c2, uh2(q.z)); c3 = __hadd2(c3, uh2(q.w));
    const float dn = dinv[node];
    const float2 f0 = __half22float2(c0), f1 = __half22float2(c1);
    const float2 f2 = __half22float2(c2), f3 = __half22float2(c3);
    uint4 o;
    o.x = f2u(f0.x * dn, f0.y * dn);
    o.y = f2u(f1.x * dn, f1.y * dn);
    o.z = f2u(f2.x * dn, f2.y * dn);
    o.w = f2u(f3.x * dn, f3.y * dn);
    reinterpret_cast<uint4*>(agg)[(size_t)node * 8 + qi] = o;
  }
}

// ============ mm3: h3' = fp16(dinv * (relu(agg2*sc2+sh2) @ W3))  [64 -> 32] ============
__global__ void mm3_act(const __half* __restrict__ agg2, const float* __restrict__ W3,
                        const float* __restrict__ bn, const float* __restrict__ dinv,
                        __half* __restrict__ h3, int n) {
  constexpr int ROWS = 16;
  __shared__ float shin[ROWS * 64];
  __shared__ float shw[64 * 32];
  const int tid = threadIdx.x;
  const int nodeBase = blockIdx.x * ROWS;
  const __half2* ah = reinterpret_cast<const __half2*>(agg2);
  for (int i = tid; i < ROWS * 32; i += 256) {
    const int node = nodeBase + (i >> 5);
    const int kp = i & 31;
    const int k0 = kp * 2, k1 = kp * 2 + 1;
    float v0 = 0.0f, v1 = 0.0f;
    if (node < n) {
      const float2 v = __half22float2(ah[(size_t)node * 32 + kp]);
      v0 = v.x * bn[128 + k0] + bn[192 + k0];
      v1 = v.y * bn[128 + k1] + bn[192 + k1];
      v0 = v0 > 0.0f ? v0 : 0.0f;
      v1 = v1 > 0.0f ? v1 : 0.0f;
    }
    shin[(i >> 5) * 64 + k0] = v0;
    shin[(i >> 5) * 64 + k1] = v1;
  }
  for (int i = tid; i < 64 * 32; i += 256) shw[i] = W3[i];
  __syncthreads();

  const int nl = tid >> 4;
  const int c = (tid & 15) * 2;
  const int node = nodeBase + nl;
  if (node >= n) return;
  float a0 = 0.0f, a1 = 0.0f;
#pragma unroll
  for (int k = 0; k < 64; ++k) {
    const float s = shin[nl * 64 + k];
    const float2 w = *reinterpret_cast<const float2*>(&shw[k * 32 + c]);
    a0 += s * w.x;
    a1 += s * w.y;
  }
  const float dn = dinv[node];
  reinterpret_cast<__half2*>(h3)[(size_t)node * 16 + (tid & 15)] =
      __floats2half2_rn(a0 * dn, a1 * dn);
}

// ============ gather h3' (C=32 fp16) + BN3 + ReLU + 32x2 linear + log_softmax ============
// 4 nodes/wave; per node 4 groups x 4 lanes; half2 accumulation; unroll-4.
__global__ void gather_cls(const __half* __restrict__ h, const float* __restrict__ dinv,
                           const int* __restrict__ row_ptr, const int* __restrict__ edata,
                           const float* __restrict__ bn, const float* __restrict__ Wc,
                           const float* __restrict__ bc, float* __restrict__ out, int n) {
  const int wave = (int)(((long long)blockIdx.x * blockDim.x + threadIdx.x) >> 6);
  const int lane = threadIdx.x & 63;
  const int nl = lane >> 4;        // node within wave (0..3)
  const int node = wave * 4 + nl;
  const int qi = lane & 3;         // uint4 index within 64B row
  const int grp = (lane >> 2) & 3; // 4 groups per node
  if (node >= n) return;
  const int beg = row_ptr[node], end = row_ptr[node + 1];
  const uint4* hv = reinterpret_cast<const uint4*>(h);
  __half2 c0 = __half2{0, 0}, c1 = c0, c2 = c0, c3 = c0;
  int e = beg + grp;
  for (; e + 12 < end; e += 16) {
    const int s0 = edata[e];
    const int s1 = edata[e + 4];
    const int s2 = edata[e + 8];
    const int s3 = edata[e + 12];
    const uint4 q0 = hv[(size_t)s0 * 4 + qi];
    const uint4 q1 = hv[(size_t)s1 * 4 + qi];
    const uint4 q2 = hv[(size_t)s2 * 4 + qi];
    const uint4 q3 = hv[(size_t)s3 * 4 + qi];
    c0 = __hadd2(c0, uh2(q0.x)); c1 = __hadd2(c1, uh2(q0.y));
    c2 = __hadd2(c2, uh2(q0.z)); c3 = __hadd2(c3, uh2(q0.w));
    c0 = __hadd2(c0, uh2(q1.x)); c1 = __hadd2(c1, uh2(q1.y));
    c2 = __hadd2(c2, uh2(q1.z)); c3 = __hadd2(c3, uh2(q1.w));
    c0 = __hadd2(c0, uh2(q2.x)); c1 = __hadd2(c1, uh2(q2.y));
    c2 = __hadd2(c2, uh2(q2.z)); c3 = __hadd2(c3, uh2(q2.w));
    c0 = __hadd2(c0, uh2(q3.x)); c1 = __hadd2(c1, uh2(q3.y));
    c2 = __hadd2(c2, uh2(q3.z)); c3 = __hadd2(c3, uh2(q3.w));
  }
  for (; e < end; e += 4) {
    const uint4 q = hv[(size_t)edata[e] * 4 + qi];
    c0 = __hadd2(c0, uh2(q.x)); c1 = __hadd2(c1, uh2(q.y));
    c2 = __hadd2(c2, uh2(q.z)); c3 = __hadd2(c3, uh2(q.w));
  }
  // reduce across the 4 groups (lane bits 2-3)
#pragma unroll
  for (int m = 4; m <= 8; m <<= 1) {
    c0 = __hadd2(c0, h2shfl_xor(c0, m));
    c1 = __hadd2(c1, h2shfl_xor(c1, m));
    c2 = __hadd2(c2, h2shfl_xor(c2, m));
    c3 = __hadd2(c3, h2shfl_xor(c3, m));
  }
  if (grp != 0) return;
  // self term
  {
    const uint4 q = hv[(size_t)node * 4 + qi];
    c0 = __hadd2(c0, uh2(q.x)); c1 = __hadd2(c1, uh2(q.y));
    c2 = __hadd2(c2, uh2(q.z)); c3 = __hadd2(c3, uh2(q.w));
  }
  const float dn = dinv[node];
  const float2 f0 = __half22float2(c0), f1 = __half22float2(c1);
  const float2 f2 = __half22float2(c2), f3 = __half22float2(c3);
  const float v[8] = {f0.x * dn, f0.y * dn, f1.x * dn, f1.y * dn,
                      f2.x * dn, f2.y * dn, f3.x * dn, f3.y * dn};
  float l0 = 0.0f, l1 = 0.0f;
#pragma unroll
  for (int j = 0; j < 8; ++j) {
    const int c = qi * 8 + j;
    float t = v[j] * bn[256 + c] + bn[288 + c];
    t = t > 0.0f ? t : 0.0f;
    const float2 w = *reinterpret_cast<const float2*>(&Wc[c * 2]);
    l0 += t * w.x;
    l1 += t * w.y;
  }
  l0 += __shfl_xor(l0, 1); l1 += __shfl_xor(l1, 1);
  l0 += __shfl_xor(l0, 2); l1 += __shfl_xor(l1, 2);
  if (qi == 0) {
    l0 += bc[0];
    l1 += bc[1];
    const float m = fmaxf(l0, l1);
    const float lse = m + log1pf(expf(-fabsf(l0 - l1)));
    *reinterpret_cast<float2*>(&out[(size_t)node * 2]) = make_float2(l0 - lse, l1 - lse);
  }
}

// ============ launch ============
extern "C" void kernel_launch(void* const* d_in, const int* in_sizes, int n_in,
                              void* d_out, int out_size, void* d_ws, size_t ws_size,
                              hipStream_t stream) {
  const float* x  = (const float*)d_in[0];
  const int* ei   = (const int*)d_in[1];   // int32 on device per harness contract
  const float* W1 = (const float*)d_in[2];
  const float* b1 = (const float*)d_in[3];
  const float* g1 = (const float*)d_in[4];
  const float* be1 = (const float*)d_in[5];
  const float* rm1 = (const float*)d_in[6];
  const float* rv1 = (const float*)d_in[7];
  const float* W2 = (const float*)d_in[8];
  const float* b2 = (const float*)d_in[9];
  const float* g2 = (const float*)d_in[10];
  const float* be2 = (const float*)d_in[11];
  const float* rm2 = (const float*)d_in[12];
  const float* rv2 = (const float*)d_in[13];
  const float* W3 = (const float*)d_in[14];
  const float* b3 = (const float*)d_in[15];
  const float* g3 = (const float*)d_in[16];
  const float* be3 = (const float*)d_in[17];
  const float* rm3 = (const float*)d_in[18];
  const float* rv3 = (const float*)d_in[19];
  const float* Wc = (const float*)d_in[20];
  const float* bc = (const float*)d_in[21];

  const int N_ = in_sizes[0] / 8;
  const int E_ = in_sizes[1] / 2;
  const int NB = (N_ + 255) >> 8;          // 256-node buckets

  auto align = [](size_t v) { return (v + 255) & ~(size_t)255; };
  char* ws = (char*)d_ws;
  size_t off = 0;
  float* dinv   = (float*)(ws + off); off += align((size_t)N_ * 4);
  int* bcur     = (int*)(ws + off);   off += align((size_t)NB * 4);
  int* row_ptr  = (int*)(ws + off);   off += align(((size_t)N_ + 1) * 4);
  int* gbase    = (int*)(ws + off);   off += align(520 * 4);
  float* bnbuf  = (float*)(ws + off); off += align(320 * 4);
  int* edata    = (int*)(ws + off);   off += align((size_t)E_ * 4);
  __half* xs    = (__half*)(ws + off); off += align((size_t)N_ * 8 * 2);
  float* aggx   = (float*)(ws + off); off += align((size_t)N_ * 8 * 4);
  // regionA: bucketbuf packed int (8 MB) -> t1 fp16 (12.8) -> agg2 fp16 (12.8)
  char* regionA = ws + off;           off += align((size_t)N_ * 64 * 2);
  // regionB: h2' fp16 (12.8) -> h3' fp16 (6.4)
  char* regionB = ws + off;           off += align((size_t)N_ * 64 * 2);

  int* bucketbuf = (int*)regionA;    // NB*BCAP*4B = 8.0 MB <= 12.8 MB
  __half* t1   = (__half*)regionA;   // after p2_sort consumed bucketbuf
  __half* agg2 = (__half*)regionA;   // after mm2 consumed t1
  __half* h2   = (__half*)regionB;
  __half* h3   = (__half*)regionB;   // after gather_h64 consumed h2

  // ---- prep (BN constants + zero bcur) + bucketed CSR build (produces dinv, xs too) ----
  prep<<<1 + (NB + 255) / 256, 256, 0, stream>>>(b1, g1, be1, rm1, rv1,
                                                 b2, g2, be2, rm2, rv2,
                                                 b3, g3, be3, rm3, rv3, bnbuf, bcur, NB);
  p1_partition<<<(E_ + 4095) / 4096, 256, 0, stream>>>(ei, bucketbuf, bcur, E_, NB);
  scan_buckets<<<1, 512, 0, stream>>>(bcur, gbase, NB, E_, row_ptr, N_);
  p2_sort<<<NB, 256, 0, stream>>>(bucketbuf, gbase, edata, row_ptr, dinv, x,
                                  (__half2*)xs, N_);

  // ---- layer 1: gather xs (8 nodes/wave), fused matmul+BN1+ReLU -> t1 fp16 ----
  gather_x<<<(N_ + 31) / 32, 256, 0, stream>>>(xs, dinv, row_ptr, edata, aggx, N_);
  mm1_act<<<(N_ + 7) / 8, 256, 0, stream>>>(aggx, W1, bnbuf, t1, N_);

  // ---- layer 2: h2' = fp16(dinv*(t1 @ W2)), gather (2 nodes/wave) -> agg2 fp16 ----
  mm2<<<(N_ + 7) / 8, 256, 0, stream>>>(t1, W2, dinv, h2, N_);
  gather_h64<<<(N_ + 7) / 8, 256, 0, stream>>>(h2, dinv, row_ptr, edata, agg2, N_);

  // ---- layer 3: h3' = fp16(dinv*(relu(agg2*sc2+sh2) @ W3)), gather (4 nodes/wave) + classifier ----
  mm3_act<<<(N_ + 15) / 16, 256, 0, stream>>>(agg2, W3, bnbuf, dinv, h3, N_);
  gather_cls<<<(N_ + 15) / 16, 256, 0, stream>>>(h3, dinv, row_ptr, edata,
                                                 bnbuf, Wc, bc, (float*)d_out, N_);
}

// Round 11
// 176.160 us; speedup vs baseline: 20.3304x; 1.0818x over previous
//
#include <hip/hip_runtime.h>
#include <hip/hip_fp16.h>

#define BN_EPS 1e-5f
#define BCAP 5120   // bucket capacity; mean 4096 edges/bucket, large safety margin

__device__ __forceinline__ unsigned f2u(float a, float b) {
  __half2 h = __floats2half2_rn(a, b);
  return *reinterpret_cast<unsigned*>(&h);
}
__device__ __forceinline__ __half2 uh2(unsigned u) {
  return *reinterpret_cast<__half2*>(&u);
}
__device__ __forceinline__ float2 h22f2(__half2 h) { return __half22float2(h); }
__device__ __forceinline__ __half2 h2shfl_xor(__half2 v, int m) {
  int i = *reinterpret_cast<int*>(&v);
  i = __shfl_xor(i, m);
  return *reinterpret_cast<__half2*>(&i);
}

// ============ prep: block 0 computes BN constants; other blocks zero bcur ============
// bn layout: sc1[64] | sh1[64] | sc2[64] | sh2[64] | sc3[32] | sh3[32]
__global__ void prep(const float* __restrict__ b1, const float* __restrict__ g1,
                     const float* __restrict__ be1, const float* __restrict__ rm1,
                     const float* __restrict__ rv1,
                     const float* __restrict__ b2, const float* __restrict__ g2,
                     const float* __restrict__ be2, const float* __restrict__ rm2,
                     const float* __restrict__ rv2,
                     const float* __restrict__ b3, const float* __restrict__ g3,
                     const float* __restrict__ be3, const float* __restrict__ rm3,
                     const float* __restrict__ rv3,
                     float* __restrict__ bn, int* __restrict__ bcur, int NB) {
  if (blockIdx.x == 0) {
    const int t = threadIdx.x;
    if (t < 64) {
      const float s = g1[t] * rsqrtf(rv1[t] + BN_EPS);
      bn[t] = s;
      bn[64 + t] = (b1[t] - rm1[t]) * s + be1[t];
    } else if (t < 128) {
      const int c = t - 64;
      const float s = g2[c] * rsqrtf(rv2[c] + BN_EPS);
      bn[128 + c] = s;
      bn[192 + c] = (b2[c] - rm2[c]) * s + be2[c];
    } else if (t < 160) {
      const int c = t - 128;
      const float s = g3[c] * rsqrtf(rv3[c] + BN_EPS);
      bn[256 + c] = s;
      bn[288 + c] = (b3[c] - rm3[c]) * s + be3[c];
    }
  } else {
    const int i = (blockIdx.x - 1) * 256 + threadIdx.x;
    if (i < NB) bcur[i] = 0;
  }
}

// ============ Phase 1: partition edges into per-bucket regions (bucket = dst>>8) ============
__global__ void p1_partition(const int* __restrict__ ei, int* __restrict__ bucketbuf,
                             int* __restrict__ bcur, int E_, int NB) {
  __shared__ int pk[4096];
  __shared__ short bk[4096];
  __shared__ int hist[512];
  __shared__ int bbase[512];
  const int tid = threadIdx.x;
  const int e0 = blockIdx.x * 4096;
  const int ecount = min(4096, E_ - e0);
  for (int i = tid; i < NB; i += 256) hist[i] = 0;
  __syncthreads();
  for (int i = tid; i < ecount; i += 256) {
    const int s = ei[e0 + i];
    const int d = ei[(size_t)E_ + e0 + i];
    pk[i] = ((d & 255) << 24) | s;   // src < 2^24 (N = 100000)
    const int b = d >> 8;
    bk[i] = (short)b;
    atomicAdd(&hist[b], 1);
  }
  __syncthreads();
  for (int i = tid; i < NB; i += 256) {
    const int c = hist[i];
    bbase[i] = c ? atomicAdd(&bcur[i], c) : 0;
    hist[i] = 0;  // reuse as local cursor
  }
  __syncthreads();
  for (int i = tid; i < ecount; i += 256) {
    const int b = bk[i];
    const int slot = bbase[b] + atomicAdd(&hist[b], 1);
    bucketbuf[(size_t)b * BCAP + slot] = pk[i];
  }
}

// exclusive scan over NB bucket counts (NB <= 512); also sets row_ptr[N]=E.
__global__ void scan_buckets(const int* __restrict__ bcur, int* __restrict__ gbase,
                             int NB, int E_, int* __restrict__ row_ptr, int N_) {
  __shared__ int sh[512];
  const int t = threadIdx.x;
  const int v = (t < NB) ? bcur[t] : 0;
  sh[t] = v;
  __syncthreads();
  for (int off = 1; off < 512; off <<= 1) {
    int u = (t >= off) ? sh[t - off] : 0;
    __syncthreads();
    sh[t] += u;
    __syncthreads();
  }
  if (t < NB) gbase[t] = sh[t] - v;  // exclusive
  if (t == 0) { gbase[NB] = E_; row_ptr[N_] = E_; }
}

// ============ Phase 2: per-bucket counting sort; emits row_ptr, dinv AND xs=fp16(dinv*x) ============
__global__ void p2_sort(const int* __restrict__ bucketbuf, const int* __restrict__ gbase,
                        int* __restrict__ edata, int* __restrict__ row_ptr,
                        float* __restrict__ dinv, const float* __restrict__ x,
                        __half2* __restrict__ xs, int N_) {
  __shared__ int cntl[256];
  __shared__ int scn[256];
  __shared__ int cur[256];
  __shared__ float dinvl[256];
  __shared__ int sbuf[BCAP];
  const int b = blockIdx.x;
  const int tid = threadIdx.x;
  const int base = gbase[b];
  const int m = gbase[b + 1] - base;
  const int* srcp = bucketbuf + (size_t)b * BCAP;
  cntl[tid] = 0;
  __syncthreads();
  for (int i = tid; i < m; i += 256) atomicAdd(&cntl[(unsigned)srcp[i] >> 24], 1);
  __syncthreads();
  const int cnt = cntl[tid];
  scn[tid] = cnt;
  __syncthreads();
  for (int off = 1; off < 256; off <<= 1) {
    int u = (tid >= off) ? scn[tid - off] : 0;
    __syncthreads();
    scn[tid] += u;
    __syncthreads();
  }
  const int excl = scn[tid] - cnt;
  cur[tid] = excl;
  const int node = (b << 8) + tid;
  const float dn = rsqrtf((float)cnt + 1.0f);  // deg = in-degree + self-loop
  dinvl[tid] = dn;
  if (node < N_) {
    row_ptr[node] = base + excl;
    dinv[node] = dn;
  }
  __syncthreads();
  for (int i = tid; i < m; i += 256) {
    const int v = srcp[i];
    const int slot = atomicAdd(&cur[(unsigned)v >> 24], 1);
    sbuf[slot] = v & 0xFFFFFF;
  }
  __syncthreads();
  for (int i = tid; i < m; i += 256) edata[(size_t)base + i] = sbuf[i];
  // fused: xs = fp16(dinv * x) for this bucket's 256 nodes (coalesced x reads)
  const int nb0 = b << 8;
  for (int i = tid; i < 1024; i += 256) {
    const int nd = nb0 + (i >> 2);
    if (nd < N_) {
      const float d2 = dinvl[i >> 2];
      const float2 v2 = reinterpret_cast<const float2*>(x)[(size_t)nd * 4 + (i & 3)];
      xs[(size_t)nd * 4 + (i & 3)] = __floats2half2_rn(v2.x * d2, v2.y * d2);
    }
  }
}

// ============ gather on xs (C=8 fp16): 8 nodes/wave, 1 lane = 1 edge row (uint4) ============
__global__ void gather_x(const __half* __restrict__ xs, const float* __restrict__ dinv,
                         const int* __restrict__ row_ptr, const int* __restrict__ edata,
                         float* __restrict__ aggx, int n) {
  const int wave = (int)(((long long)blockIdx.x * blockDim.x + threadIdx.x) >> 6);
  const int lane = threadIdx.x & 63;
  const int nl = lane >> 3;      // node within wave (0..7)
  const int grp = lane & 7;      // 8 groups x 1 lane
  const int node = wave * 8 + nl;
  if (node >= n) return;
  const int beg = row_ptr[node], end = row_ptr[node + 1];
  const uint4* xv = reinterpret_cast<const uint4*>(xs);
  __half2 c0 = __half2{0, 0}, c1 = c0, c2 = c0, c3 = c0;
  int e = beg + grp;
  for (; e + 8 < end; e += 16) {
    const uint4 q0 = xv[edata[e]];
    const uint4 q1 = xv[edata[e + 8]];
    c0 = __hadd2(c0, uh2(q0.x)); c1 = __hadd2(c1, uh2(q0.y));
    c2 = __hadd2(c2, uh2(q0.z)); c3 = __hadd2(c3, uh2(q0.w));
    c0 = __hadd2(c0, uh2(q1.x)); c1 = __hadd2(c1, uh2(q1.y));
    c2 = __hadd2(c2, uh2(q1.z)); c3 = __hadd2(c3, uh2(q1.w));
  }
  if (e < end) {
    const uint4 q = xv[edata[e]];
    c0 = __hadd2(c0, uh2(q.x)); c1 = __hadd2(c1, uh2(q.y));
    c2 = __hadd2(c2, uh2(q.z)); c3 = __hadd2(c3, uh2(q.w));
  }
#pragma unroll
  for (int m = 1; m <= 4; m <<= 1) {
    c0 = __hadd2(c0, h2shfl_xor(c0, m));
    c1 = __hadd2(c1, h2shfl_xor(c1, m));
    c2 = __hadd2(c2, h2shfl_xor(c2, m));
    c3 = __hadd2(c3, h2shfl_xor(c3, m));
  }
  if (grp == 0) {
    const uint4 q = xv[node];  // self term
    c0 = __hadd2(c0, uh2(q.x)); c1 = __hadd2(c1, uh2(q.y));
    c2 = __hadd2(c2, uh2(q.z)); c3 = __hadd2(c3, uh2(q.w));
    const float dn = dinv[node];
    const float2 f0 = h22f2(c0), f1 = h22f2(c1);
    const float2 f2 = h22f2(c2), f3 = h22f2(c3);
    float4* op = reinterpret_cast<float4*>(&aggx[(size_t)node * 8]);
    op[0] = make_float4(f0.x * dn, f0.y * dn, f1.x * dn, f1.y * dn);
    op[1] = make_float4(f2.x * dn, f2.y * dn, f3.x * dn, f3.y * dn);
  }
}

// ============ mm1: t1 = fp16(relu(aggx @ W1 * sc1 + sh1))  [8 -> 64] ============
__global__ void mm1_act(const float* __restrict__ aggx, const float* __restrict__ W1,
                        const float* __restrict__ bn, __half* __restrict__ t1, int n) {
  constexpr int ROWS = 8;
  __shared__ float shin[ROWS * 8];
  __shared__ float shw[8 * 64];
  const int tid = threadIdx.x;
  const int nodeBase = blockIdx.x * ROWS;
  for (int i = tid; i < ROWS * 8; i += 256) {
    const int node = nodeBase + i / 8;
    shin[i] = (node < n) ? aggx[(size_t)node * 8 + (i & 7)] : 0.0f;
  }
  for (int i = tid; i < 8 * 64; i += 256) shw[i] = W1[i];
  __syncthreads();

  const int nl = tid >> 5;
  const int c = (tid & 31) * 2;
  const int node = nodeBase + nl;
  if (node >= n) return;
  float a0 = 0.0f, a1 = 0.0f;
#pragma unroll
  for (int k = 0; k < 8; ++k) {
    const float s = shin[nl * 8 + k];
    const float2 w = *reinterpret_cast<const float2*>(&shw[k * 64 + c]);
    a0 += s * w.x;
    a1 += s * w.y;
  }
  float v0 = a0 * bn[c] + bn[64 + c];
  float v1 = a1 * bn[c + 1] + bn[64 + c + 1];
  v0 = v0 > 0.0f ? v0 : 0.0f;
  v1 = v1 > 0.0f ? v1 : 0.0f;
  reinterpret_cast<__half2*>(t1)[(size_t)node * 32 + (tid & 31)] = __floats2half2_rn(v0, v1);
}

// ============ mm2: h2' = fp16(dinv * (t1 @ W2))  [64 -> 64] ============
// Register-tiled: 64 nodes/block; thread = 4 nodes x 4 outputs; LDS in fp16 (k-packed half2).
__global__ void mm2(const __half* __restrict__ t1, const float* __restrict__ W2,
                    const float* __restrict__ dinv, __half* __restrict__ h2, int n) {
  __shared__ __half2 shin[64 * 33];   // [node][kp], stride 33 to dodge bank conflicts
  __shared__ uint4 shw[32 * 16];      // [kp][cquad]: 4x half2(W[2kp][c], W[2kp+1][c])
  const int tid = threadIdx.x;
  const int node0 = blockIdx.x * 64;
  const __half2* t1h = reinterpret_cast<const __half2*>(t1);
  for (int i = tid; i < 64 * 32; i += 256) {
    const int nd = i >> 5, kp = i & 31;
    __half2 v = __half2{0, 0};
    if (node0 + nd < n) v = t1h[(size_t)(node0 + nd) * 32 + kp];
    shin[nd * 33 + kp] = v;
  }
  __half2* shwh = reinterpret_cast<__half2*>(shw);
  for (int i = tid; i < 32 * 64; i += 256) {
    const int kp = i >> 6, c = i & 63;
    shwh[kp * 64 + c] = __floats2half2_rn(W2[(2 * kp) * 64 + c], W2[(2 * kp + 1) * 64 + c]);
  }
  __syncthreads();

  const int cq = tid & 15;        // output quad: c = cq*4 .. cq*4+3
  const int nb = (tid >> 4) * 4;  // local node base (0..60)
  float acc[4][4];
#pragma unroll
  for (int j = 0; j < 4; ++j)
#pragma unroll
    for (int k = 0; k < 4; ++k) acc[j][k] = 0.0f;

  for (int kp = 0; kp < 32; ++kp) {
    const uint4 wq = shw[kp * 16 + cq];
    const float2 w0 = h22f2(uh2(wq.x)), w1 = h22f2(uh2(wq.y));
    const float2 w2 = h22f2(uh2(wq.z)), w3 = h22f2(uh2(wq.w));
#pragma unroll
    for (int j = 0; j < 4; ++j) {
      const float2 s = h22f2(shin[(nb + j) * 33 + kp]);
      acc[j][0] += s.x * w0.x + s.y * w0.y;
      acc[j][1] += s.x * w1.x + s.y * w1.y;
      acc[j][2] += s.x * w2.x + s.y * w2.y;
      acc[j][3] += s.x * w3.x + s.y * w3.y;
    }
  }
#pragma unroll
  for (int j = 0; j < 4; ++j) {
    const int node = node0 + nb + j;
    if (node < n) {
      const float dn = dinv[node];
      uint2 o;
      o.x = f2u(acc[j][0] * dn, acc[j][1] * dn);
      o.y = f2u(acc[j][2] * dn, acc[j][3] * dn);
      reinterpret_cast<uint2*>(h2)[(size_t)node * 16 + cq] = o;
    }
  }
}

// ============ gather h2' (C=64 fp16): 2 nodes/wave, 4 groups x 8 lanes, unroll-4 ============
__global__ void gather_h64(const __half* __restrict__ h, const float* __restrict__ dinv,
                           const int* __restrict__ row_ptr, const int* __restrict__ edata,
                           __half* __restrict__ agg, int n) {
  const int wave = (int)(((long long)blockIdx.x * blockDim.x + threadIdx.x) >> 6);
  const int lane = threadIdx.x & 63;
  const int node = wave * 2 + (lane >> 5);
  const int sub = lane & 31;
  const int qi = sub & 7;     // uint4 index within 128B row
  const int grp = sub >> 3;   // 4 groups per node
  if (node >= n) return;
  const int beg = row_ptr[node], end = row_ptr[node + 1];
  const uint4* hv = reinterpret_cast<const uint4*>(h);
  __half2 c0 = __half2{0, 0}, c1 = c0, c2 = c0, c3 = c0;
  int e = beg + grp;
  for (; e + 12 < end; e += 16) {
    const int s0 = edata[e];
    const int s1 = edata[e + 4];
    const int s2 = edata[e + 8];
    const int s3 = edata[e + 12];
    const uint4 q0 = hv[(size_t)s0 * 8 + qi];
    const uint4 q1 = hv[(size_t)s1 * 8 + qi];
    const uint4 q2 = hv[(size_t)s2 * 8 + qi];
    const uint4 q3 = hv[(size_t)s3 * 8 + qi];
    c0 = __hadd2(c0, uh2(q0.x)); c1 = __hadd2(c1, uh2(q0.y));
    c2 = __hadd2(c2, uh2(q0.z)); c3 = __hadd2(c3, uh2(q0.w));
    c0 = __hadd2(c0, uh2(q1.x)); c1 = __hadd2(c1, uh2(q1.y));
    c2 = __hadd2(c2, uh2(q1.z)); c3 = __hadd2(c3, uh2(q1.w));
    c0 = __hadd2(c0, uh2(q2.x)); c1 = __hadd2(c1, uh2(q2.y));
    c2 = __hadd2(c2, uh2(q2.z)); c3 = __hadd2(c3, uh2(q2.w));
    c0 = __hadd2(c0, uh2(q3.x)); c1 = __hadd2(c1, uh2(q3.y));
    c2 = __hadd2(c2, uh2(q3.z)); c3 = __hadd2(c3, uh2(q3.w));
  }
  for (; e < end; e += 4) {
    const uint4 q = hv[(size_t)edata[e] * 8 + qi];
    c0 = __hadd2(c0, uh2(q.x)); c1 = __hadd2(c1, uh2(q.y));
    c2 = __hadd2(c2, uh2(q.z)); c3 = __hadd2(c3, uh2(q.w));
  }
#pragma unroll
  for (int m = 8; m <= 16; m <<= 1) {
    c0 = __hadd2(c0, h2shfl_xor(c0, m));
    c1 = __hadd2(c1, h2shfl_xor(c1, m));
    c2 = __hadd2(c2, h2shfl_xor(c2, m));
    c3 = __hadd2(c3, h2shfl_xor(c3, m));
  }
  if (grp == 0) {
    const uint4 q = hv[(size_t)node * 8 + qi];  // self term
    c0 = __hadd2(c0, uh2(q.x)); c1 = __hadd2(c1, uh2(q.y));
    c2 = __hadd2(c2, uh2(q.z)); c3 = __hadd2(c3, uh2(q.w));
    const float dn = dinv[node];
    const float2 f0 = h22f2(c0), f1 = h22f2(c1);
    const float2 f2 = h22f2(c2), f3 = h22f2(c3);
    uint4 o;
    o.x = f2u(f0.x * dn, f0.y * dn);
    o.y = f2u(f1.x * dn, f1.y * dn);
    o.z = f2u(f2.x * dn, f2.y * dn);
    o.w = f2u(f3.x * dn, f3.y * dn);
    reinterpret_cast<uint4*>(agg)[(size_t)node * 8 + qi] = o;
  }
}

// ============ mm3: h3' = fp16(dinv * (relu(agg2*sc2+sh2) @ W3))  [64 -> 32] ============
// Register-tiled: 128 nodes/block; thread = 4 nodes x 4 outputs; BN2+ReLU fused in staging.
__global__ void mm3_act(const __half* __restrict__ agg2, const float* __restrict__ W3,
                        const float* __restrict__ bn, const float* __restrict__ dinv,
                        __half* __restrict__ h3, int n) {
  __shared__ __half2 shin[128 * 33];  // [node][kp]
  __shared__ uint4 shw[32 * 8];       // [kp][cquad]
  const int tid = threadIdx.x;
  const int node0 = blockIdx.x * 128;
  const __half2* ah = reinterpret_cast<const __half2*>(agg2);
  for (int i = tid; i < 128 * 32; i += 256) {
    const int nd = i >> 5, kp = i & 31;
    __half2 o = __half2{0, 0};
    if (node0 + nd < n) {
      const float2 v = h22f2(ah[(size_t)(node0 + nd) * 32 + kp]);
      float v0 = v.x * bn[128 + 2 * kp] + bn[192 + 2 * kp];
      float v1 = v.y * bn[128 + 2 * kp + 1] + bn[192 + 2 * kp + 1];
      v0 = v0 > 0.0f ? v0 : 0.0f;
      v1 = v1 > 0.0f ? v1 : 0.0f;
      o = __floats2half2_rn(v0, v1);
    }
    shin[nd * 33 + kp] = o;
  }
  __half2* shwh = reinterpret_cast<__half2*>(shw);
  for (int i = tid; i < 32 * 32; i += 256) {
    const int kp = i >> 5, c = i & 31;
    shwh[kp * 32 + c] = __floats2half2_rn(W3[(2 * kp) * 32 + c], W3[(2 * kp + 1) * 32 + c]);
  }
  __syncthreads();

  const int cq = tid & 7;         // output quad: c = cq*4 .. cq*4+3
  const int nb = (tid >> 3) * 4;  // local node base (0..124)
  float acc[4][4];
#pragma unroll
  for (int j = 0; j < 4; ++j)
#pragma unroll
    for (int k = 0; k < 4; ++k) acc[j][k] = 0.0f;

  for (int kp = 0; kp < 32; ++kp) {
    const uint4 wq = shw[kp * 8 + cq];
    const float2 w0 = h22f2(uh2(wq.x)), w1 = h22f2(uh2(wq.y));
    const float2 w2 = h22f2(uh2(wq.z)), w3 = h22f2(uh2(wq.w));
#pragma unroll
    for (int j = 0; j < 4; ++j) {
      const float2 s = h22f2(shin[(nb + j) * 33 + kp]);
      acc[j][0] += s.x * w0.x + s.y * w0.y;
      acc[j][1] += s.x * w1.x + s.y * w1.y;
      acc[j][2] += s.x * w2.x + s.y * w2.y;
      acc[j][3] += s.x * w3.x + s.y * w3.y;
    }
  }
#pragma unroll
  for (int j = 0; j < 4; ++j) {
    const int node = node0 + nb + j;
    if (node < n) {
      const float dn = dinv[node];
      uint2 o;
      o.x = f2u(acc[j][0] * dn, acc[j][1] * dn);
      o.y = f2u(acc[j][2] * dn, acc[j][3] * dn);
      reinterpret_cast<uint2*>(h3)[(size_t)node * 8 + cq] = o;
    }
  }
}

// ============ gather h3' (C=32 fp16) + BN3 + ReLU + 32x2 linear + log_softmax ============
// 4 nodes/wave; per node 4 groups x 4 lanes; half2 accumulation; unroll-4.
__global__ void gather_cls(const __half* __restrict__ h, const float* __restrict__ dinv,
                           const int* __restrict__ row_ptr, const int* __restrict__ edata,
                           const float* __restrict__ bn, const float* __restrict__ Wc,
                           const float* __restrict__ bc, float* __restrict__ out, int n) {
  const int wave = (int)(((long long)blockIdx.x * blockDim.x + threadIdx.x) >> 6);
  const int lane = threadIdx.x & 63;
  const int nl = lane >> 4;        // node within wave (0..3)
  const int node = wave * 4 + nl;
  const int qi = lane & 3;         // uint4 index within 64B row
  const int grp = (lane >> 2) & 3; // 4 groups per node
  if (node >= n) return;
  const int beg = row_ptr[node], end = row_ptr[node + 1];
  const uint4* hv = reinterpret_cast<const uint4*>(h);
  __half2 c0 = __half2{0, 0}, c1 = c0, c2 = c0, c3 = c0;
  int e = beg + grp;
  for (; e + 12 < end; e += 16) {
    const int s0 = edata[e];
    const int s1 = edata[e + 4];
    const int s2 = edata[e + 8];
    const int s3 = edata[e + 12];
    const uint4 q0 = hv[(size_t)s0 * 4 + qi];
    const uint4 q1 = hv[(size_t)s1 * 4 + qi];
    const uint4 q2 = hv[(size_t)s2 * 4 + qi];
    const uint4 q3 = hv[(size_t)s3 * 4 + qi];
    c0 = __hadd2(c0, uh2(q0.x)); c1 = __hadd2(c1, uh2(q0.y));
    c2 = __hadd2(c2, uh2(q0.z)); c3 = __hadd2(c3, uh2(q0.w));
    c0 = __hadd2(c0, uh2(q1.x)); c1 = __hadd2(c1, uh2(q1.y));
    c2 = __hadd2(c2, uh2(q1.z)); c3 = __hadd2(c3, uh2(q1.w));
    c0 = __hadd2(c0, uh2(q2.x)); c1 = __hadd2(c1, uh2(q2.y));
    c2 = __hadd2(c2, uh2(q2.z)); c3 = __hadd2(c3, uh2(q2.w));
    c0 = __hadd2(c0, uh2(q3.x)); c1 = __hadd2(c1, uh2(q3.y));
    c2 = __hadd2(c2, uh2(q3.z)); c3 = __hadd2(c3, uh2(q3.w));
  }
  for (; e < end; e += 4) {
    const uint4 q = hv[(size_t)edata[e] * 4 + qi];
    c0 = __hadd2(c0, uh2(q.x)); c1 = __hadd2(c1, uh2(q.y));
    c2 = __hadd2(c2, uh2(q.z)); c3 = __hadd2(c3, uh2(q.w));
  }
#pragma unroll
  for (int m = 4; m <= 8; m <<= 1) {
    c0 = __hadd2(c0, h2shfl_xor(c0, m));
    c1 = __hadd2(c1, h2shfl_xor(c1, m));
    c2 = __hadd2(c2, h2shfl_xor(c2, m));
    c3 = __hadd2(c3, h2shfl_xor(c3, m));
  }
  if (grp != 0) return;
  // self term
  {
    const uint4 q = hv[(size_t)node * 4 + qi];
    c0 = __hadd2(c0, uh2(q.x)); c1 = __hadd2(c1, uh2(q.y));
    c2 = __hadd2(c2, uh2(q.z)); c3 = __hadd2(c3, uh2(q.w));
  }
  const float dn = dinv[node];
  const float2 f0 = h22f2(c0), f1 = h22f2(c1);
  const float2 f2 = h22f2(c2), f3 = h22f2(c3);
  const float v[8] = {f0.x * dn, f0.y * dn, f1.x * dn, f1.y * dn,
                      f2.x * dn, f2.y * dn, f3.x * dn, f3.y * dn};
  float l0 = 0.0f, l1 = 0.0f;
#pragma unroll
  for (int j = 0; j < 8; ++j) {
    const int c = qi * 8 + j;
    float t = v[j] * bn[256 + c] + bn[288 + c];
    t = t > 0.0f ? t : 0.0f;
    const float2 w = *reinterpret_cast<const float2*>(&Wc[c * 2]);
    l0 += t * w.x;
    l1 += t * w.y;
  }
  l0 += __shfl_xor(l0, 1); l1 += __shfl_xor(l1, 1);
  l0 += __shfl_xor(l0, 2); l1 += __shfl_xor(l1, 2);
  if (qi == 0) {
    l0 += bc[0];
    l1 += bc[1];
    const float m = fmaxf(l0, l1);
    const float lse = m + log1pf(expf(-fabsf(l0 - l1)));
    *reinterpret_cast<float2*>(&out[(size_t)node * 2]) = make_float2(l0 - lse, l1 - lse);
  }
}

// ============ launch ============
extern "C" void kernel_launch(void* const* d_in, const int* in_sizes, int n_in,
                              void* d_out, int out_size, void* d_ws, size_t ws_size,
                              hipStream_t stream) {
  const float* x  = (const float*)d_in[0];
  const int* ei   = (const int*)d_in[1];   // int32 on device per harness contract
  const float* W1 = (const float*)d_in[2];
  const float* b1 = (const float*)d_in[3];
  const float* g1 = (const float*)d_in[4];
  const float* be1 = (const float*)d_in[5];
  const float* rm1 = (const float*)d_in[6];
  const float* rv1 = (const float*)d_in[7];
  const float* W2 = (const float*)d_in[8];
  const float* b2 = (const float*)d_in[9];
  const float* g2 = (const float*)d_in[10];
  const float* be2 = (const float*)d_in[11];
  const float* rm2 = (const float*)d_in[12];
  const float* rv2 = (const float*)d_in[13];
  const float* W3 = (const float*)d_in[14];
  const float* b3 = (const float*)d_in[15];
  const float* g3 = (const float*)d_in[16];
  const float* be3 = (const float*)d_in[17];
  const float* rm3 = (const float*)d_in[18];
  const float* rv3 = (const float*)d_in[19];
  const float* Wc = (const float*)d_in[20];
  const float* bc = (const float*)d_in[21];

  const int N_ = in_sizes[0] / 8;
  const int E_ = in_sizes[1] / 2;
  const int NB = (N_ + 255) >> 8;          // 256-node buckets

  auto align = [](size_t v) { return (v + 255) & ~(size_t)255; };
  char* ws = (char*)d_ws;
  size_t off = 0;
  float* dinv   = (float*)(ws + off); off += align((size_t)N_ * 4);
  int* bcur     = (int*)(ws + off);   off += align((size_t)NB * 4);
  int* row_ptr  = (int*)(ws + off);   off += align(((size_t)N_ + 1) * 4);
  int* gbase    = (int*)(ws + off);   off += align(520 * 4);
  float* bnbuf  = (float*)(ws + off); off += align(320 * 4);
  int* edata    = (int*)(ws + off);   off += align((size_t)E_ * 4);
  __half* xs    = (__half*)(ws + off); off += align((size_t)N_ * 8 * 2);
  float* aggx   = (float*)(ws + off); off += align((size_t)N_ * 8 * 4);
  // regionA: bucketbuf packed int (8 MB) -> t1 fp16 (12.8) -> agg2 fp16 (12.8)
  char* regionA = ws + off;           off += align((size_t)N_ * 64 * 2);
  // regionB: h2' fp16 (12.8) -> h3' fp16 (6.4)
  char* regionB = ws + off;           off += align((size_t)N_ * 64 * 2);

  int* bucketbuf = (int*)regionA;    // NB*BCAP*4B = 8.0 MB <= 12.8 MB
  __half* t1   = (__half*)regionA;   // after p2_sort consumed bucketbuf
  __half* agg2 = (__half*)regionA;   // after mm2 consumed t1
  __half* h2   = (__half*)regionB;
  __half* h3   = (__half*)regionB;   // after gather_h64 consumed h2

  // ---- prep (BN constants + zero bcur) + bucketed CSR build (produces dinv, xs too) ----
  prep<<<1 + (NB + 255) / 256, 256, 0, stream>>>(b1, g1, be1, rm1, rv1,
                                                 b2, g2, be2, rm2, rv2,
                                                 b3, g3, be3, rm3, rv3, bnbuf, bcur, NB);
  p1_partition<<<(E_ + 4095) / 4096, 256, 0, stream>>>(ei, bucketbuf, bcur, E_, NB);
  scan_buckets<<<1, 512, 0, stream>>>(bcur, gbase, NB, E_, row_ptr, N_);
  p2_sort<<<NB, 256, 0, stream>>>(bucketbuf, gbase, edata, row_ptr, dinv, x,
                                  (__half2*)xs, N_);

  // ---- layer 1: gather xs (8 nodes/wave), fused matmul+BN1+ReLU -> t1 fp16 ----
  gather_x<<<(N_ + 31) / 32, 256, 0, stream>>>(xs, dinv, row_ptr, edata, aggx, N_);
  mm1_act<<<(N_ + 7) / 8, 256, 0, stream>>>(aggx, W1, bnbuf, t1, N_);

  // ---- layer 2: h2' = fp16(dinv*(t1 @ W2)) [reg-tiled], gather (2 nodes/wave) ----
  mm2<<<(N_ + 63) / 64, 256, 0, stream>>>(t1, W2, dinv, h2, N_);
  gather_h64<<<(N_ + 7) / 8, 256, 0, stream>>>(h2, dinv, row_ptr, edata, agg2, N_);

  // ---- layer 3: h3' = fp16(dinv*(relu(agg2*sc2+sh2) @ W3)) [reg-tiled], gather + classifier ----
  mm3_act<<<(N_ + 127) / 128, 256, 0, stream>>>(agg2, W3, bnbuf, dinv, h3, N_);
  gather_cls<<<(N_ + 15) / 16, 256, 0, stream>>>(h3, dinv, row_ptr, edata,
                                                 bnbuf, Wc, bc, (float*)d_out, N_);
}

// Round 12
// 166.738 us; speedup vs baseline: 21.4792x; 1.0565x over previous
//
#include <hip/hip_runtime.h>
#include <hip/hip_fp16.h>

#define BN_EPS 1e-5f
#define BCAP 5120        // bucket capacity (mean 4096 edges/bucket)
#define EDCAP_H64 768    // LDS edge staging, 8 nodes/block (mean 128)
#define EDCAP_CLS 1280   // LDS edge staging, 16 nodes/block (mean 256)

__device__ __forceinline__ unsigned f2u(float a, float b) {
  __half2 h = __floats2half2_rn(a, b);
  return *reinterpret_cast<unsigned*>(&h);
}
__device__ __forceinline__ __half2 uh2(unsigned u) {
  return *reinterpret_cast<__half2*>(&u);
}
__device__ __forceinline__ float2 h22f2(__half2 h) { return __half22float2(h); }
__device__ __forceinline__ __half2 h2shfl_xor(__half2 v, int m) {
  int i = *reinterpret_cast<int*>(&v);
  i = __shfl_xor(i, m);
  return *reinterpret_cast<__half2*>(&i);
}

// ============ prep: block 0 computes BN constants; other blocks zero bcur[0..NB] ============
// bn layout: sc1[64] | sh1[64] | sc2[64] | sh2[64] | sc3[32] | sh3[32]
__global__ void prep(const float* __restrict__ b1, const float* __restrict__ g1,
                     const float* __restrict__ be1, const float* __restrict__ rm1,
                     const float* __restrict__ rv1,
                     const float* __restrict__ b2, const float* __restrict__ g2,
                     const float* __restrict__ be2, const float* __restrict__ rm2,
                     const float* __restrict__ rv2,
                     const float* __restrict__ b3, const float* __restrict__ g3,
                     const float* __restrict__ be3, const float* __restrict__ rm3,
                     const float* __restrict__ rv3,
                     float* __restrict__ bn, int* __restrict__ bcur, int NB) {
  if (blockIdx.x == 0) {
    const int t = threadIdx.x;
    if (t < 64) {
      const float s = g1[t] * rsqrtf(rv1[t] + BN_EPS);
      bn[t] = s;
      bn[64 + t] = (b1[t] - rm1[t]) * s + be1[t];
    } else if (t < 128) {
      const int c = t - 64;
      const float s = g2[c] * rsqrtf(rv2[c] + BN_EPS);
      bn[128 + c] = s;
      bn[192 + c] = (b2[c] - rm2[c]) * s + be2[c];
    } else if (t < 160) {
      const int c = t - 128;
      const float s = g3[c] * rsqrtf(rv3[c] + BN_EPS);
      bn[256 + c] = s;
      bn[288 + c] = (b3[c] - rm3[c]) * s + be3[c];
    }
  } else {
    const int i = (blockIdx.x - 1) * 256 + threadIdx.x;
    if (i <= NB) bcur[i] = 0;  // includes the global cursor at bcur[NB]
  }
}

// ============ Phase 1: partition edges into per-bucket regions (bucket = dst>>8) ============
__global__ void p1_partition(const int* __restrict__ ei, int* __restrict__ bucketbuf,
                             int* __restrict__ bcur, int E_, int NB) {
  __shared__ int pk[4096];
  __shared__ short bk[4096];
  __shared__ int hist[512];
  __shared__ int bbase[512];
  const int tid = threadIdx.x;
  const int e0 = blockIdx.x * 4096;
  const int ecount = min(4096, E_ - e0);
  for (int i = tid; i < NB; i += 256) hist[i] = 0;
  __syncthreads();
  for (int i = tid; i < ecount; i += 256) {
    const int s = ei[e0 + i];
    const int d = ei[(size_t)E_ + e0 + i];
    pk[i] = ((d & 255) << 24) | s;   // src < 2^24 (N = 100000)
    const int b = d >> 8;
    bk[i] = (short)b;
    atomicAdd(&hist[b], 1);
  }
  __syncthreads();
  for (int i = tid; i < NB; i += 256) {
    const int c = hist[i];
    bbase[i] = c ? atomicAdd(&bcur[i], c) : 0;
    hist[i] = 0;  // reuse as local cursor
  }
  __syncthreads();
  for (int i = tid; i < ecount; i += 256) {
    const int b = bk[i];
    const int slot = bbase[b] + atomicAdd(&hist[b], 1);
    bucketbuf[(size_t)b * BCAP + slot] = pk[i];
  }
}

// ============ Phase 2: per-bucket counting sort; atomic global base; emits rbeg/rend, dinv, xs ============
__global__ void p2_sort(const int* __restrict__ bucketbuf, const int* __restrict__ bcur,
                        int* __restrict__ gcursor, int* __restrict__ edata,
                        int* __restrict__ rbeg, int* __restrict__ rend,
                        float* __restrict__ dinv, const float* __restrict__ x,
                        __half2* __restrict__ xs, int N_) {
  __shared__ int cntl[256];
  __shared__ int scn[256];
  __shared__ int cur[256];
  __shared__ float dinvl[256];
  __shared__ int sbuf[BCAP];
  __shared__ int sbase;
  const int b = blockIdx.x;
  const int tid = threadIdx.x;
  const int m = bcur[b];
  const int* srcp = bucketbuf + (size_t)b * BCAP;
  cntl[tid] = 0;
  __syncthreads();
  for (int i = tid; i < m; i += 256) atomicAdd(&cntl[(unsigned)srcp[i] >> 24], 1);
  __syncthreads();
  if (tid == 0) sbase = atomicAdd(gcursor, m);  // order-free range claim
  const int cnt = cntl[tid];
  scn[tid] = cnt;
  __syncthreads();
  for (int off = 1; off < 256; off <<= 1) {
    int u = (tid >= off) ? scn[tid - off] : 0;
    __syncthreads();
    scn[tid] += u;
    __syncthreads();
  }
  const int excl = scn[tid] - cnt;
  cur[tid] = excl;
  const int base = sbase;  // barriers in scan loop make this visible
  const int node = (b << 8) + tid;
  const float dn = rsqrtf((float)cnt + 1.0f);  // deg = in-degree + self-loop
  dinvl[tid] = dn;
  if (node < N_) {
    rbeg[node] = base + excl;
    rend[node] = base + excl + cnt;
    dinv[node] = dn;
  }
  __syncthreads();
  for (int i = tid; i < m; i += 256) {
    const int v = srcp[i];
    const int slot = atomicAdd(&cur[(unsigned)v >> 24], 1);
    sbuf[slot] = v & 0xFFFFFF;
  }
  __syncthreads();
  for (int i = tid; i < m; i += 256) edata[(size_t)base + i] = sbuf[i];
  // fused: xs = fp16(dinv * x) for this bucket's 256 nodes (coalesced x reads)
  const int nb0 = b << 8;
  for (int i = tid; i < 1024; i += 256) {
    const int nd = nb0 + (i >> 2);
    if (nd < N_) {
      const float d2 = dinvl[i >> 2];
      const float2 v2 = reinterpret_cast<const float2*>(x)[(size_t)nd * 4 + (i & 3)];
      xs[(size_t)nd * 4 + (i & 3)] = __floats2half2_rn(v2.x * d2, v2.y * d2);
    }
  }
}

// ============ gx_mm1: gather xs (C=8) + matmul 8->64 + BN1 + ReLU, fused ============
// Block = 256 threads = 4 waves = 32 nodes. Gather phase: 8 nodes/wave, 1 lane = 1 edge row.
// Matmul phase: thread = 1 node x 8 outputs from LDS-staged agg + W1.
__global__ void gx_mm1(const __half* __restrict__ xs, const float* __restrict__ dinv,
                       const int* __restrict__ rbeg, const int* __restrict__ rend,
                       const int* __restrict__ edata, const float* __restrict__ W1,
                       const float* __restrict__ bn, __half* __restrict__ t1, int n) {
  __shared__ float shagg[32][8];
  __shared__ float shw[8 * 64];
  const int tid = threadIdx.x;
  for (int i = tid; i < 512; i += 256) shw[i] = W1[i];
  const int node0 = blockIdx.x * 32;
  const int lane = tid & 63;
  const int nl = ((tid >> 6) << 3) + (lane >> 3);  // local node 0..31
  const int grp = lane & 7;                        // 8 groups x 1 lane
  const int node = node0 + nl;
  if (node < n) {
    const int beg = rbeg[node], end = rend[node];
    const uint4* xv = reinterpret_cast<const uint4*>(xs);
    __half2 c0 = __half2{0, 0}, c1 = c0, c2 = c0, c3 = c0;
    int e = beg + grp;
    for (; e + 8 < end; e += 16) {
      const uint4 q0 = xv[edata[e]];
      const uint4 q1 = xv[edata[e + 8]];
      c0 = __hadd2(c0, uh2(q0.x)); c1 = __hadd2(c1, uh2(q0.y));
      c2 = __hadd2(c2, uh2(q0.z)); c3 = __hadd2(c3, uh2(q0.w));
      c0 = __hadd2(c0, uh2(q1.x)); c1 = __hadd2(c1, uh2(q1.y));
      c2 = __hadd2(c2, uh2(q1.z)); c3 = __hadd2(c3, uh2(q1.w));
    }
    if (e < end) {
      const uint4 q = xv[edata[e]];
      c0 = __hadd2(c0, uh2(q.x)); c1 = __hadd2(c1, uh2(q.y));
      c2 = __hadd2(c2, uh2(q.z)); c3 = __hadd2(c3, uh2(q.w));
    }
#pragma unroll
    for (int m = 1; m <= 4; m <<= 1) {
      c0 = __hadd2(c0, h2shfl_xor(c0, m));
      c1 = __hadd2(c1, h2shfl_xor(c1, m));
      c2 = __hadd2(c2, h2shfl_xor(c2, m));
      c3 = __hadd2(c3, h2shfl_xor(c3, m));
    }
    if (grp == 0) {
      const uint4 q = xv[node];  // self term
      c0 = __hadd2(c0, uh2(q.x)); c1 = __hadd2(c1, uh2(q.y));
      c2 = __hadd2(c2, uh2(q.z)); c3 = __hadd2(c3, uh2(q.w));
      const float dn = dinv[node];
      const float2 f0 = h22f2(c0), f1 = h22f2(c1);
      const float2 f2 = h22f2(c2), f3 = h22f2(c3);
      shagg[nl][0] = f0.x * dn; shagg[nl][1] = f0.y * dn;
      shagg[nl][2] = f1.x * dn; shagg[nl][3] = f1.y * dn;
      shagg[nl][4] = f2.x * dn; shagg[nl][5] = f2.y * dn;
      shagg[nl][6] = f3.x * dn; shagg[nl][7] = f3.y * dn;
    }
  }
  __syncthreads();
  // matmul phase: thread -> node (tid>>3), output channels c..c+7
  const int mn = tid >> 3;
  const int node2 = node0 + mn;
  if (node2 >= n) return;
  const int c = (tid & 7) * 8;
  float a[8] = {0, 0, 0, 0, 0, 0, 0, 0};
#pragma unroll
  for (int k = 0; k < 8; ++k) {
    const float s = shagg[mn][k];
#pragma unroll
    for (int j = 0; j < 8; ++j) a[j] += s * shw[k * 64 + c + j];
  }
  float v[8];
#pragma unroll
  for (int j = 0; j < 8; ++j) {
    float t = a[j] * bn[c + j] + bn[64 + c + j];
    v[j] = t > 0.0f ? t : 0.0f;
  }
  uint4 o;
  o.x = f2u(v[0], v[1]);
  o.y = f2u(v[2], v[3]);
  o.z = f2u(v[4], v[5]);
  o.w = f2u(v[6], v[7]);
  reinterpret_cast<uint4*>(t1)[(size_t)node2 * 8 + (tid & 7)] = o;
}

// ============ mm2: h2' = fp16(dinv * (t1 @ W2))  [64 -> 64], register-tiled ============
__global__ void mm2(const __half* __restrict__ t1, const float* __restrict__ W2,
                    const float* __restrict__ dinv, __half* __restrict__ h2, int n) {
  __shared__ __half2 shin[64 * 33];
  __shared__ uint4 shw[32 * 16];
  const int tid = threadIdx.x;
  const int node0 = blockIdx.x * 64;
  const __half2* t1h = reinterpret_cast<const __half2*>(t1);
  for (int i = tid; i < 64 * 32; i += 256) {
    const int nd = i >> 5, kp = i & 31;
    __half2 v = __half2{0, 0};
    if (node0 + nd < n) v = t1h[(size_t)(node0 + nd) * 32 + kp];
    shin[nd * 33 + kp] = v;
  }
  __half2* shwh = reinterpret_cast<__half2*>(shw);
  for (int i = tid; i < 32 * 64; i += 256) {
    const int kp = i >> 6, c = i & 63;
    shwh[kp * 64 + c] = __floats2half2_rn(W2[(2 * kp) * 64 + c], W2[(2 * kp + 1) * 64 + c]);
  }
  __syncthreads();

  const int cq = tid & 15;
  const int nb = (tid >> 4) * 4;
  float acc[4][4];
#pragma unroll
  for (int j = 0; j < 4; ++j)
#pragma unroll
    for (int k = 0; k < 4; ++k) acc[j][k] = 0.0f;

  for (int kp = 0; kp < 32; ++kp) {
    const uint4 wq = shw[kp * 16 + cq];
    const float2 w0 = h22f2(uh2(wq.x)), w1 = h22f2(uh2(wq.y));
    const float2 w2 = h22f2(uh2(wq.z)), w3 = h22f2(uh2(wq.w));
#pragma unroll
    for (int j = 0; j < 4; ++j) {
      const float2 s = h22f2(shin[(nb + j) * 33 + kp]);
      acc[j][0] += s.x * w0.x + s.y * w0.y;
      acc[j][1] += s.x * w1.x + s.y * w1.y;
      acc[j][2] += s.x * w2.x + s.y * w2.y;
      acc[j][3] += s.x * w3.x + s.y * w3.y;
    }
  }
#pragma unroll
  for (int j = 0; j < 4; ++j) {
    const int node = node0 + nb + j;
    if (node < n) {
      const float dn = dinv[node];
      uint2 o;
      o.x = f2u(acc[j][0] * dn, acc[j][1] * dn);
      o.y = f2u(acc[j][2] * dn, acc[j][3] * dn);
      reinterpret_cast<uint2*>(h2)[(size_t)node * 16 + cq] = o;
    }
  }
}

// ============ gather h2' (C=64): 8 nodes/block, edata LDS-staged, unroll-4 ============
__global__ void gather_h64(const __half* __restrict__ h, const float* __restrict__ dinv,
                           const int* __restrict__ rbeg, const int* __restrict__ rend,
                           const int* __restrict__ edata, __half* __restrict__ agg, int n) {
  __shared__ int se[EDCAP_H64];
  const int tid = threadIdx.x;
  const int node0 = blockIdx.x * 8;
  const int last = min(node0 + 7, n - 1);
  const int gb = rbeg[node0];
  const int total = rend[last] - gb;   // block's nodes are contiguous in edata (same bucket)
  const bool lds = (total <= EDCAP_H64);
  if (lds) {
    for (int i = tid; i < total; i += 256) se[i] = edata[gb + i];
  }
  __syncthreads();
  const int lane = tid & 63;
  const int node = node0 + ((tid >> 6) << 1) + (lane >> 5);
  if (node >= n) return;
  const int sub = lane & 31;
  const int qi = sub & 7;     // uint4 index within 128B row
  const int grp = sub >> 3;   // 4 groups per node
  const uint4* hv = reinterpret_cast<const uint4*>(h);
  __half2 c0 = __half2{0, 0}, c1 = c0, c2 = c0, c3 = c0;
  if (lds) {
    const int beg = rbeg[node] - gb, end = rend[node] - gb;
    int e = beg + grp;
    for (; e + 12 < end; e += 16) {
      const int s0 = se[e], s1 = se[e + 4], s2 = se[e + 8], s3 = se[e + 12];
      const uint4 q0 = hv[(size_t)s0 * 8 + qi];
      const uint4 q1 = hv[(size_t)s1 * 8 + qi];
      const uint4 q2 = hv[(size_t)s2 * 8 + qi];
      const uint4 q3 = hv[(size_t)s3 * 8 + qi];
      c0 = __hadd2(c0, uh2(q0.x)); c1 = __hadd2(c1, uh2(q0.y));
      c2 = __hadd2(c2, uh2(q0.z)); c3 = __hadd2(c3, uh2(q0.w));
      c0 = __hadd2(c0, uh2(q1.x)); c1 = __hadd2(c1, uh2(q1.y));
      c2 = __hadd2(c2, uh2(q1.z)); c3 = __hadd2(c3, uh2(q1.w));
      c0 = __hadd2(c0, uh2(q2.x)); c1 = __hadd2(c1, uh2(q2.y));
      c2 = __hadd2(c2, uh2(q2.z)); c3 = __hadd2(c3, uh2(q2.w));
      c0 = __hadd2(c0, uh2(q3.x)); c1 = __hadd2(c1, uh2(q3.y));
      c2 = __hadd2(c2, uh2(q3.z)); c3 = __hadd2(c3, uh2(q3.w));
    }
    for (; e < end; e += 4) {
      const uint4 q = hv[(size_t)se[e] * 8 + qi];
      c0 = __hadd2(c0, uh2(q.x)); c1 = __hadd2(c1, uh2(q.y));
      c2 = __hadd2(c2, uh2(q.z)); c3 = __hadd2(c3, uh2(q.w));
    }
  } else {
    const int beg = rbeg[node], end = rend[node];
    int e = beg + grp;
    for (; e + 12 < end; e += 16) {
      const int s0 = edata[e], s1 = edata[e + 4], s2 = edata[e + 8], s3 = edata[e + 12];
      const uint4 q0 = hv[(size_t)s0 * 8 + qi];
      const uint4 q1 = hv[(size_t)s1 * 8 + qi];
      const uint4 q2 = hv[(size_t)s2 * 8 + qi];
      const uint4 q3 = hv[(size_t)s3 * 8 + qi];
      c0 = __hadd2(c0, uh2(q0.x)); c1 = __hadd2(c1, uh2(q0.y));
      c2 = __hadd2(c2, uh2(q0.z)); c3 = __hadd2(c3, uh2(q0.w));
      c0 = __hadd2(c0, uh2(q1.x)); c1 = __hadd2(c1, uh2(q1.y));
      c2 = __hadd2(c2, uh2(q1.z)); c3 = __hadd2(c3, uh2(q1.w));
      c0 = __hadd2(c0, uh2(q2.x)); c1 = __hadd2(c1, uh2(q2.y));
      c2 = __hadd2(c2, uh2(q2.z)); c3 = __hadd2(c3, uh2(q2.w));
      c0 = __hadd2(c0, uh2(q3.x)); c1 = __hadd2(c1, uh2(q3.y));
      c2 = __hadd2(c2, uh2(q3.z)); c3 = __hadd2(c3, uh2(q3.w));
    }
    for (; e < end; e += 4) {
      const uint4 q = hv[(size_t)edata[e] * 8 + qi];
      c0 = __hadd2(c0, uh2(q.x)); c1 = __hadd2(c1, uh2(q.y));
      c2 = __hadd2(c2, uh2(q.z)); c3 = __hadd2(c3, uh2(q.w));
    }
  }
#pragma unroll
  for (int m = 8; m <= 16; m <<= 1) {
    c0 = __hadd2(c0, h2shfl_xor(c0, m));
    c1 = __hadd2(c1, h2shfl_xor(c1, m));
    c2 = __hadd2(c2, h2shfl_xor(c2, m));
    c3 = __hadd2(c3, h2shfl_xor(c3, m));
  }
  if (grp == 0) {
    const uint4 q = hv[(size_t)node * 8 + qi];  // self term
    c0 = __hadd2(c0, uh2(q.x)); c1 = __hadd2(c1, uh2(q.y));
    c2 = __hadd2(c2, uh2(q.z)); c3 = __hadd2(c3, uh2(q.w));
    const float dn = dinv[node];
    const float2 f0 = h22f2(c0), f1 = h22f2(c1);
    const float2 f2 = h22f2(c2), f3 = h22f2(c3);
    uint4 o;
    o.x = f2u(f0.x * dn, f0.y * dn);
    o.y = f2u(f1.x * dn, f1.y * dn);
    o.z = f2u(f2.x * dn, f2.y * dn);
    o.w = f2u(f3.x * dn, f3.y * dn);
    reinterpret_cast<uint4*>(agg)[(size_t)node * 8 + qi] = o;
  }
}

// ============ mm3: h3' = fp16(dinv * (relu(agg2*sc2+sh2) @ W3))  [64 -> 32], register-tiled ============
__global__ void mm3_act(const __half* __restrict__ agg2, const float* __restrict__ W3,
                        const float* __restrict__ bn, const float* __restrict__ dinv,
                        __half* __restrict__ h3, int n) {
  __shared__ __half2 shin[128 * 33];
  __shared__ uint4 shw[32 * 8];
  const int tid = threadIdx.x;
  const int node0 = blockIdx.x * 128;
  const __half2* ah = reinterpret_cast<const __half2*>(agg2);
  for (int i = tid; i < 128 * 32; i += 256) {
    const int nd = i >> 5, kp = i & 31;
    __half2 o = __half2{0, 0};
    if (node0 + nd < n) {
      const float2 v = h22f2(ah[(size_t)(node0 + nd) * 32 + kp]);
      float v0 = v.x * bn[128 + 2 * kp] + bn[192 + 2 * kp];
      float v1 = v.y * bn[128 + 2 * kp + 1] + bn[192 + 2 * kp + 1];
      v0 = v0 > 0.0f ? v0 : 0.0f;
      v1 = v1 > 0.0f ? v1 : 0.0f;
      o = __floats2half2_rn(v0, v1);
    }
    shin[nd * 33 + kp] = o;
  }
  __half2* shwh = reinterpret_cast<__half2*>(shw);
  for (int i = tid; i < 32 * 32; i += 256) {
    const int kp = i >> 5, c = i & 31;
    shwh[kp * 32 + c] = __floats2half2_rn(W3[(2 * kp) * 32 + c], W3[(2 * kp + 1) * 32 + c]);
  }
  __syncthreads();

  const int cq = tid & 7;
  const int nb = (tid >> 3) * 4;
  float acc[4][4];
#pragma unroll
  for (int j = 0; j < 4; ++j)
#pragma unroll
    for (int k = 0; k < 4; ++k) acc[j][k] = 0.0f;

  for (int kp = 0; kp < 32; ++kp) {
    const uint4 wq = shw[kp * 8 + cq];
    const float2 w0 = h22f2(uh2(wq.x)), w1 = h22f2(uh2(wq.y));
    const float2 w2 = h22f2(uh2(wq.z)), w3 = h22f2(uh2(wq.w));
#pragma unroll
    for (int j = 0; j < 4; ++j) {
      const float2 s = h22f2(shin[(nb + j) * 33 + kp]);
      acc[j][0] += s.x * w0.x + s.y * w0.y;
      acc[j][1] += s.x * w1.x + s.y * w1.y;
      acc[j][2] += s.x * w2.x + s.y * w2.y;
      acc[j][3] += s.x * w3.x + s.y * w3.y;
    }
  }
#pragma unroll
  for (int j = 0; j < 4; ++j) {
    const int node = node0 + nb + j;
    if (node < n) {
      const float dn = dinv[node];
      uint2 o;
      o.x = f2u(acc[j][0] * dn, acc[j][1] * dn);
      o.y = f2u(acc[j][2] * dn, acc[j][3] * dn);
      reinterpret_cast<uint2*>(h3)[(size_t)node * 8 + cq] = o;
    }
  }
}

// ============ gather h3' (C=32) + BN3 + ReLU + 32x2 linear + log_softmax ============
// 16 nodes/block, edata LDS-staged; per node 4 groups x 4 lanes; unroll-4.
__global__ void gather_cls(const __half* __restrict__ h, const float* __restrict__ dinv,
                           const int* __restrict__ rbeg, const int* __restrict__ rend,
                           const int* __restrict__ edata, const float* __restrict__ bn,
                           const float* __restrict__ Wc, const float* __restrict__ bc,
                           float* __restrict__ out, int n) {
  __shared__ int se[EDCAP_CLS];
  const int tid = threadIdx.x;
  const int node0 = blockIdx.x * 16;
  const int last = min(node0 + 15, n - 1);
  const int gb = rbeg[node0];
  const int total = rend[last] - gb;
  const bool lds = (total <= EDCAP_CLS);
  if (lds) {
    for (int i = tid; i < total; i += 256) se[i] = edata[gb + i];
  }
  __syncthreads();
  const int lane = tid & 63;
  const int node = node0 + ((tid >> 6) << 2) + (lane >> 4);
  if (node >= n) return;
  const int qi = lane & 3;
  const int grp = (lane >> 2) & 3;
  const uint4* hv = reinterpret_cast<const uint4*>(h);
  __half2 c0 = __half2{0, 0}, c1 = c0, c2 = c0, c3 = c0;
  if (lds) {
    const int beg = rbeg[node] - gb, end = rend[node] - gb;
    int e = beg + grp;
    for (; e + 12 < end; e += 16) {
      const int s0 = se[e], s1 = se[e + 4], s2 = se[e + 8], s3 = se[e + 12];
      const uint4 q0 = hv[(size_t)s0 * 4 + qi];
      const uint4 q1 = hv[(size_t)s1 * 4 + qi];
      const uint4 q2 = hv[(size_t)s2 * 4 + qi];
      const uint4 q3 = hv[(size_t)s3 * 4 + qi];
      c0 = __hadd2(c0, uh2(q0.x)); c1 = __hadd2(c1, uh2(q0.y));
      c2 = __hadd2(c2, uh2(q0.z)); c3 = __hadd2(c3, uh2(q0.w));
      c0 = __hadd2(c0, uh2(q1.x)); c1 = __hadd2(c1, uh2(q1.y));
      c2 = __hadd2(c2, uh2(q1.z)); c3 = __hadd2(c3, uh2(q1.w));
      c0 = __hadd2(c0, uh2(q2.x)); c1 = __hadd2(c1, uh2(q2.y));
      c2 = __hadd2(c2, uh2(q2.z)); c3 = __hadd2(c3, uh2(q2.w));
      c0 = __hadd2(c0, uh2(q3.x)); c1 = __hadd2(c1, uh2(q3.y));
      c2 = __hadd2(c2, uh2(q3.z)); c3 = __hadd2(c3, uh2(q3.w));
    }
    for (; e < end; e += 4) {
      const uint4 q = hv[(size_t)se[e] * 4 + qi];
      c0 = __hadd2(c0, uh2(q.x)); c1 = __hadd2(c1, uh2(q.y));
      c2 = __hadd2(c2, uh2(q.z)); c3 = __hadd2(c3, uh2(q.w));
    }
  } else {
    const int beg = rbeg[node], end = rend[node];
    int e = beg + grp;
    for (; e + 12 < end; e += 16) {
      const int s0 = edata[e], s1 = edata[e + 4], s2 = edata[e + 8], s3 = edata[e + 12];
      const uint4 q0 = hv[(size_t)s0 * 4 + qi];
      const uint4 q1 = hv[(size_t)s1 * 4 + qi];
      const uint4 q2 = hv[(size_t)s2 * 4 + qi];
      const uint4 q3 = hv[(size_t)s3 * 4 + qi];
      c0 = __hadd2(c0, uh2(q0.x)); c1 = __hadd2(c1, uh2(q0.y));
      c2 = __hadd2(c2, uh2(q0.z)); c3 = __hadd2(c3, uh2(q0.w));
      c0 = __hadd2(c0, uh2(q1.x)); c1 = __hadd2(c1, uh2(q1.y));
      c2 = __hadd2(c2, uh2(q1.z)); c3 = __hadd2(c3, uh2(q1.w));
      c0 = __hadd2(c0, uh2(q2.x)); c1 = __hadd2(c1, uh2(q2.y));
      c2 = __hadd2(c2, uh2(q2.z)); c3 = __hadd2(c3, uh2(q2.w));
      c0 = __hadd2(c0, uh2(q3.x)); c1 = __hadd2(c1, uh2(q3.y));
      c2 = __hadd2(c2, uh2(q3.z)); c3 = __hadd2(c3, uh2(q3.w));
    }
    for (; e < end; e += 4) {
      const uint4 q = hv[(size_t)edata[e] * 4 + qi];
      c0 = __hadd2(c0, uh2(q.x)); c1 = __hadd2(c1, uh2(q.y));
      c2 = __hadd2(c2, uh2(q.z)); c3 = __hadd2(c3, uh2(q.w));
    }
  }
#pragma unroll
  for (int m = 4; m <= 8; m <<= 1) {
    c0 = __hadd2(c0, h2shfl_xor(c0, m));
    c1 = __hadd2(c1, h2shfl_xor(c1, m));
    c2 = __hadd2(c2, h2shfl_xor(c2, m));
    c3 = __hadd2(c3, h2shfl_xor(c3, m));
  }
  if (grp != 0) return;
  // self term
  {
    const uint4 q = hv[(size_t)node * 4 + qi];
    c0 = __hadd2(c0, uh2(q.x)); c1 = __hadd2(c1, uh2(q.y));
    c2 = __hadd2(c2, uh2(q.z)); c3 = __hadd2(c3, uh2(q.w));
  }
  const float dn = dinv[node];
  const float2 f0 = h22f2(c0), f1 = h22f2(c1);
  const float2 f2 = h22f2(c2), f3 = h22f2(c3);
  const float v[8] = {f0.x * dn, f0.y * dn, f1.x * dn, f1.y * dn,
                      f2.x * dn, f2.y * dn, f3.x * dn, f3.y * dn};
  float l0 = 0.0f, l1 = 0.0f;
#pragma unroll
  for (int j = 0; j < 8; ++j) {
    const int c = qi * 8 + j;
    float t = v[j] * bn[256 + c] + bn[288 + c];
    t = t > 0.0f ? t : 0.0f;
    const float2 w = *reinterpret_cast<const float2*>(&Wc[c * 2]);
    l0 += t * w.x;
    l1 += t * w.y;
  }
  l0 += __shfl_xor(l0, 1); l1 += __shfl_xor(l1, 1);
  l0 += __shfl_xor(l0, 2); l1 += __shfl_xor(l1, 2);
  if (qi == 0) {
    l0 += bc[0];
    l1 += bc[1];
    const float m = fmaxf(l0, l1);
    const float lse = m + log1pf(expf(-fabsf(l0 - l1)));
    *reinterpret_cast<float2*>(&out[(size_t)node * 2]) = make_float2(l0 - lse, l1 - lse);
  }
}

// ============ launch ============
extern "C" void kernel_launch(void* const* d_in, const int* in_sizes, int n_in,
                              void* d_out, int out_size, void* d_ws, size_t ws_size,
                              hipStream_t stream) {
  const float* x  = (const float*)d_in[0];
  const int* ei   = (const int*)d_in[1];   // int32 on device per harness contract
  const float* W1 = (const float*)d_in[2];
  const float* b1 = (const float*)d_in[3];
  const float* g1 = (const float*)d_in[4];
  const float* be1 = (const float*)d_in[5];
  const float* rm1 = (const float*)d_in[6];
  const float* rv1 = (const float*)d_in[7];
  const float* W2 = (const float*)d_in[8];
  const float* b2 = (const float*)d_in[9];
  const float* g2 = (const float*)d_in[10];
  const float* be2 = (const float*)d_in[11];
  const float* rm2 = (const float*)d_in[12];
  const float* rv2 = (const float*)d_in[13];
  const float* W3 = (const float*)d_in[14];
  const float* b3 = (const float*)d_in[15];
  const float* g3 = (const float*)d_in[16];
  const float* be3 = (const float*)d_in[17];
  const float* rm3 = (const float*)d_in[18];
  const float* rv3 = (const float*)d_in[19];
  const float* Wc = (const float*)d_in[20];
  const float* bc = (const float*)d_in[21];

  const int N_ = in_sizes[0] / 8;
  const int E_ = in_sizes[1] / 2;
  const int NB = (N_ + 255) >> 8;          // 256-node buckets

  auto align = [](size_t v) { return (v + 255) & ~(size_t)255; };
  char* ws = (char*)d_ws;
  size_t off = 0;
  float* dinv   = (float*)(ws + off); off += align((size_t)N_ * 4);
  int* bcur     = (int*)(ws + off);   off += align(((size_t)NB + 1) * 4);  // +1: global cursor
  int* rbeg     = (int*)(ws + off);   off += align((size_t)N_ * 4);
  int* rend     = (int*)(ws + off);   off += align((size_t)N_ * 4);
  float* bnbuf  = (float*)(ws + off); off += align(320 * 4);
  int* edata    = (int*)(ws + off);   off += align((size_t)E_ * 4);
  __half* xs    = (__half*)(ws + off); off += align((size_t)N_ * 8 * 2);
  // regionA: bucketbuf packed int (8 MB) -> t1 fp16 (12.8) -> agg2 fp16 (12.8)
  char* regionA = ws + off;           off += align((size_t)N_ * 64 * 2);
  // regionB: h2' fp16 (12.8) -> h3' fp16 (6.4)
  char* regionB = ws + off;           off += align((size_t)N_ * 64 * 2);

  int* bucketbuf = (int*)regionA;
  __half* t1   = (__half*)regionA;   // after p2_sort consumed bucketbuf
  __half* agg2 = (__half*)regionA;   // after mm2 consumed t1
  __half* h2   = (__half*)regionB;
  __half* h3   = (__half*)regionB;   // after gather_h64 consumed h2
  int* gcursor = bcur + NB;

  // ---- prep (BN constants + zero bcur/cursor) + bucketed CSR build ----
  prep<<<1 + (NB + 1 + 255) / 256, 256, 0, stream>>>(b1, g1, be1, rm1, rv1,
                                                     b2, g2, be2, rm2, rv2,
                                                     b3, g3, be3, rm3, rv3, bnbuf, bcur, NB);
  p1_partition<<<(E_ + 4095) / 4096, 256, 0, stream>>>(ei, bucketbuf, bcur, E_, NB);
  p2_sort<<<NB, 256, 0, stream>>>(bucketbuf, bcur, gcursor, edata, rbeg, rend,
                                  dinv, x, (__half2*)xs, N_);

  // ---- layer 1: fused gather(xs) + matmul 8->64 + BN1 + ReLU -> t1 fp16 ----
  gx_mm1<<<(N_ + 31) / 32, 256, 0, stream>>>(xs, dinv, rbeg, rend, edata, W1, bnbuf, t1, N_);

  // ---- layer 2: h2' = fp16(dinv*(t1 @ W2)) [reg-tiled], gather (LDS-staged edata) ----
  mm2<<<(N_ + 63) / 64, 256, 0, stream>>>(t1, W2, dinv, h2, N_);
  gather_h64<<<(N_ + 7) / 8, 256, 0, stream>>>(h2, dinv, rbeg, rend, edata, agg2, N_);

  // ---- layer 3: h3' = fp16(dinv*(relu(agg2*sc2+sh2) @ W3)) [reg-tiled], gather + classifier ----
  mm3_act<<<(N_ + 127) / 128, 256, 0, stream>>>(agg2, W3, bnbuf, dinv, h3, N_);
  gather_cls<<<(N_ + 15) / 16, 256, 0, stream>>>(h3, dinv, rbeg, rend, edata,
                                                 bnbuf, Wc, bc, (float*)d_out, N_);
}

// Round 13
// 156.254 us; speedup vs baseline: 22.9204x; 1.0671x over previous
//
#include <hip/hip_runtime.h>
#include <hip/hip_fp16.h>

#define BN_EPS 1e-5f
#define BCAP 5120        // bucket capacity (mean 4096 edges/bucket)
#define EDCAP_H64 768    // LDS edge staging, 8 nodes/block (mean 128)
#define EDCAP_CLS 1280   // LDS edge staging, 16 nodes/block (mean 256)

__device__ __forceinline__ unsigned f2u(float a, float b) {
  __half2 h = __floats2half2_rn(a, b);
  return *reinterpret_cast<unsigned*>(&h);
}
__device__ __forceinline__ __half2 uh2(unsigned u) {
  return *reinterpret_cast<__half2*>(&u);
}
__device__ __forceinline__ float2 h22f2(__half2 h) { return __half22float2(h); }
__device__ __forceinline__ __half2 h2shfl_xor(__half2 v, int m) {
  int i = *reinterpret_cast<int*>(&v);
  i = __shfl_xor(i, m);
  return *reinterpret_cast<__half2*>(&i);
}

// ============ prep: block 0 computes BN constants; other blocks zero bcur[0..NB] ============
// bn layout: sc1[64] | sh1[64] | sc2[64] | sh2[64] | sc3[32] | sh3[32]
__global__ void prep(const float* __restrict__ b1, const float* __restrict__ g1,
                     const float* __restrict__ be1, const float* __restrict__ rm1,
                     const float* __restrict__ rv1,
                     const float* __restrict__ b2, const float* __restrict__ g2,
                     const float* __restrict__ be2, const float* __restrict__ rm2,
                     const float* __restrict__ rv2,
                     const float* __restrict__ b3, const float* __restrict__ g3,
                     const float* __restrict__ be3, const float* __restrict__ rm3,
                     const float* __restrict__ rv3,
                     float* __restrict__ bn, int* __restrict__ bcur, int NB) {
  if (blockIdx.x == 0) {
    const int t = threadIdx.x;
    if (t < 64) {
      const float s = g1[t] * rsqrtf(rv1[t] + BN_EPS);
      bn[t] = s;
      bn[64 + t] = (b1[t] - rm1[t]) * s + be1[t];
    } else if (t < 128) {
      const int c = t - 64;
      const float s = g2[c] * rsqrtf(rv2[c] + BN_EPS);
      bn[128 + c] = s;
      bn[192 + c] = (b2[c] - rm2[c]) * s + be2[c];
    } else if (t < 160) {
      const int c = t - 128;
      const float s = g3[c] * rsqrtf(rv3[c] + BN_EPS);
      bn[256 + c] = s;
      bn[288 + c] = (b3[c] - rm3[c]) * s + be3[c];
    }
  } else {
    const int i = (blockIdx.x - 1) * 256 + threadIdx.x;
    if (i <= NB) bcur[i] = 0;  // includes the global cursor at bcur[NB]
  }
}

// ============ Phase 1: partition edges into per-bucket regions (bucket = dst>>8) ============
__global__ void p1_partition(const int* __restrict__ ei, int* __restrict__ bucketbuf,
                             int* __restrict__ bcur, int E_, int NB) {
  __shared__ int pk[4096];
  __shared__ short bk[4096];
  __shared__ int hist[512];
  __shared__ int bbase[512];
  const int tid = threadIdx.x;
  const int e0 = blockIdx.x * 4096;
  const int ecount = min(4096, E_ - e0);
  for (int i = tid; i < NB; i += 256) hist[i] = 0;
  __syncthreads();
  for (int i = tid; i < ecount; i += 256) {
    const int s = ei[e0 + i];
    const int d = ei[(size_t)E_ + e0 + i];
    pk[i] = ((d & 255) << 24) | s;   // src < 2^24 (N = 100000)
    const int b = d >> 8;
    bk[i] = (short)b;
    atomicAdd(&hist[b], 1);
  }
  __syncthreads();
  for (int i = tid; i < NB; i += 256) {
    const int c = hist[i];
    bbase[i] = c ? atomicAdd(&bcur[i], c) : 0;
    hist[i] = 0;  // reuse as local cursor
  }
  __syncthreads();
  for (int i = tid; i < ecount; i += 256) {
    const int b = bk[i];
    const int slot = bbase[b] + atomicAdd(&hist[b], 1);
    bucketbuf[(size_t)b * BCAP + slot] = pk[i];
  }
}

// ============ Phase 2: per-bucket counting sort; atomic global base; emits rbeg/rend, dinv, xs ============
__global__ void p2_sort(const int* __restrict__ bucketbuf, const int* __restrict__ bcur,
                        int* __restrict__ gcursor, int* __restrict__ edata,
                        int* __restrict__ rbeg, int* __restrict__ rend,
                        float* __restrict__ dinv, const float* __restrict__ x,
                        __half2* __restrict__ xs, int N_) {
  __shared__ int cntl[256];
  __shared__ int scn[256];
  __shared__ int cur[256];
  __shared__ float dinvl[256];
  __shared__ int sbuf[BCAP];
  __shared__ int sbase;
  const int b = blockIdx.x;
  const int tid = threadIdx.x;
  const int m = bcur[b];
  const int* srcp = bucketbuf + (size_t)b * BCAP;
  cntl[tid] = 0;
  __syncthreads();
  for (int i = tid; i < m; i += 256) atomicAdd(&cntl[(unsigned)srcp[i] >> 24], 1);
  __syncthreads();
  if (tid == 0) sbase = atomicAdd(gcursor, m);  // order-free range claim
  const int cnt = cntl[tid];
  scn[tid] = cnt;
  __syncthreads();
  for (int off = 1; off < 256; off <<= 1) {
    int u = (tid >= off) ? scn[tid - off] : 0;
    __syncthreads();
    scn[tid] += u;
    __syncthreads();
  }
  const int excl = scn[tid] - cnt;
  cur[tid] = excl;
  const int base = sbase;  // barriers in scan loop make this visible
  const int node = (b << 8) + tid;
  const float dn = rsqrtf((float)cnt + 1.0f);  // deg = in-degree + self-loop
  dinvl[tid] = dn;
  if (node < N_) {
    rbeg[node] = base + excl;
    rend[node] = base + excl + cnt;
    dinv[node] = dn;
  }
  __syncthreads();
  for (int i = tid; i < m; i += 256) {
    const int v = srcp[i];
    const int slot = atomicAdd(&cur[(unsigned)v >> 24], 1);
    sbuf[slot] = v & 0xFFFFFF;
  }
  __syncthreads();
  for (int i = tid; i < m; i += 256) edata[(size_t)base + i] = sbuf[i];
  // fused: xs = fp16(dinv * x) for this bucket's 256 nodes (coalesced x reads)
  const int nb0 = b << 8;
  for (int i = tid; i < 1024; i += 256) {
    const int nd = nb0 + (i >> 2);
    if (nd < N_) {
      const float d2 = dinvl[i >> 2];
      const float2 v2 = reinterpret_cast<const float2*>(x)[(size_t)nd * 4 + (i & 3)];
      xs[(size_t)nd * 4 + (i & 3)] = __floats2half2_rn(v2.x * d2, v2.y * d2);
    }
  }
}

// ============ l12: gather(xs) + mm1 + BN1 + ReLU + mm2 + dinv, fully fused ============
// Block = 256 threads = 32 nodes. t1 lives only in LDS.
__global__ void l12(const __half* __restrict__ xs, const float* __restrict__ dinv,
                    const int* __restrict__ rbeg, const int* __restrict__ rend,
                    const int* __restrict__ edata, const float* __restrict__ W1,
                    const float* __restrict__ W2, const float* __restrict__ bn,
                    __half* __restrict__ h2, int n) {
  __shared__ float shw1[8 * 64];      // 2 KB
  __shared__ float shagg[32][8];      // 1 KB
  __shared__ __half2 sht1[32 * 33];   // 4.2 KB, stride 33
  __shared__ uint4 shw2[32 * 16];     // 8 KB: [kp][cquad]
  const int tid = threadIdx.x;
  const int node0 = blockIdx.x * 32;
  // stage W1 (fp32) and W2 (fp16 k-packed)
  for (int i = tid; i < 512; i += 256) shw1[i] = W1[i];
  {
    __half2* shw2h = reinterpret_cast<__half2*>(shw2);
    for (int i = tid; i < 32 * 64; i += 256) {
      const int kp = i >> 6, c = i & 63;
      shw2h[kp * 64 + c] = __floats2half2_rn(W2[(2 * kp) * 64 + c], W2[(2 * kp + 1) * 64 + c]);
    }
  }
  // ---- phase 1: gather xs (8 nodes/wave, 1 lane = 1 edge row) ----
  const int lane = tid & 63;
  const int nl = ((tid >> 6) << 3) + (lane >> 3);  // local node 0..31
  const int grp = lane & 7;
  const int node = node0 + nl;
  if (node < n) {
    const int beg = rbeg[node], end = rend[node];
    const uint4* xv = reinterpret_cast<const uint4*>(xs);
    __half2 c0 = __half2{0, 0}, c1 = c0, c2 = c0, c3 = c0;
    int e = beg + grp;
    for (; e + 8 < end; e += 16) {
      const uint4 q0 = xv[edata[e]];
      const uint4 q1 = xv[edata[e + 8]];
      c0 = __hadd2(c0, uh2(q0.x)); c1 = __hadd2(c1, uh2(q0.y));
      c2 = __hadd2(c2, uh2(q0.z)); c3 = __hadd2(c3, uh2(q0.w));
      c0 = __hadd2(c0, uh2(q1.x)); c1 = __hadd2(c1, uh2(q1.y));
      c2 = __hadd2(c2, uh2(q1.z)); c3 = __hadd2(c3, uh2(q1.w));
    }
    if (e < end) {
      const uint4 q = xv[edata[e]];
      c0 = __hadd2(c0, uh2(q.x)); c1 = __hadd2(c1, uh2(q.y));
      c2 = __hadd2(c2, uh2(q.z)); c3 = __hadd2(c3, uh2(q.w));
    }
#pragma unroll
    for (int m = 1; m <= 4; m <<= 1) {
      c0 = __hadd2(c0, h2shfl_xor(c0, m));
      c1 = __hadd2(c1, h2shfl_xor(c1, m));
      c2 = __hadd2(c2, h2shfl_xor(c2, m));
      c3 = __hadd2(c3, h2shfl_xor(c3, m));
    }
    if (grp == 0) {
      const uint4 q = xv[node];  // self term
      c0 = __hadd2(c0, uh2(q.x)); c1 = __hadd2(c1, uh2(q.y));
      c2 = __hadd2(c2, uh2(q.z)); c3 = __hadd2(c3, uh2(q.w));
      const float dn = dinv[node];
      const float2 f0 = h22f2(c0), f1 = h22f2(c1);
      const float2 f2 = h22f2(c2), f3 = h22f2(c3);
      shagg[nl][0] = f0.x * dn; shagg[nl][1] = f0.y * dn;
      shagg[nl][2] = f1.x * dn; shagg[nl][3] = f1.y * dn;
      shagg[nl][4] = f2.x * dn; shagg[nl][5] = f2.y * dn;
      shagg[nl][6] = f3.x * dn; shagg[nl][7] = f3.y * dn;
    }
  }
  __syncthreads();
  // ---- phase 2: mm1 + BN1 + ReLU -> sht1 (LDS) ----
  {
    const int mn = tid >> 3;          // local node
    const int c = (tid & 7) * 8;      // output channels c..c+7
    if (node0 + mn < n) {
      float a[8] = {0, 0, 0, 0, 0, 0, 0, 0};
#pragma unroll
      for (int k = 0; k < 8; ++k) {
        const float s = shagg[mn][k];
#pragma unroll
        for (int j = 0; j < 8; ++j) a[j] += s * shw1[k * 64 + c + j];
      }
      float v[8];
#pragma unroll
      for (int j = 0; j < 8; ++j) {
        float t = a[j] * bn[c + j] + bn[64 + c + j];
        v[j] = t > 0.0f ? t : 0.0f;
      }
#pragma unroll
      for (int j = 0; j < 4; ++j)
        sht1[mn * 33 + (tid & 7) * 4 + j] = __floats2half2_rn(v[2 * j], v[2 * j + 1]);
    }
  }
  __syncthreads();
  // ---- phase 3: mm2 reg-tiled (thread = 2 nodes x 4 outputs) ----
  const int cq = tid & 15;          // c = cq*4..cq*4+3
  const int nbs = (tid >> 4) * 2;   // local node base (0..30)
  float acc[2][4];
#pragma unroll
  for (int j = 0; j < 2; ++j)
#pragma unroll
    for (int k = 0; k < 4; ++k) acc[j][k] = 0.0f;
  for (int kp = 0; kp < 32; ++kp) {
    const uint4 wq = shw2[kp * 16 + cq];
    const float2 w0 = h22f2(uh2(wq.x)), w1 = h22f2(uh2(wq.y));
    const float2 w2 = h22f2(uh2(wq.z)), w3 = h22f2(uh2(wq.w));
#pragma unroll
    for (int j = 0; j < 2; ++j) {
      const float2 s = h22f2(sht1[(nbs + j) * 33 + kp]);
      acc[j][0] += s.x * w0.x + s.y * w0.y;
      acc[j][1] += s.x * w1.x + s.y * w1.y;
      acc[j][2] += s.x * w2.x + s.y * w2.y;
      acc[j][3] += s.x * w3.x + s.y * w3.y;
    }
  }
#pragma unroll
  for (int j = 0; j < 2; ++j) {
    const int nd = node0 + nbs + j;
    if (nd < n) {
      const float dn = dinv[nd];
      uint2 o;
      o.x = f2u(acc[j][0] * dn, acc[j][1] * dn);
      o.y = f2u(acc[j][2] * dn, acc[j][3] * dn);
      reinterpret_cast<uint2*>(h2)[(size_t)nd * 16 + cq] = o;
    }
  }
}

// ============ gh64_mm3: gather h2' + dinv + BN2 + ReLU + mm3 + dinv, fused ============
// 8 nodes/block; agg2 lives only in LDS.
__global__ void gh64_mm3(const __half* __restrict__ h, const float* __restrict__ dinv,
                         const int* __restrict__ rbeg, const int* __restrict__ rend,
                         const int* __restrict__ edata, const float* __restrict__ W3,
                         const float* __restrict__ bn, __half* __restrict__ h3, int n) {
  __shared__ int se[EDCAP_H64];       // 3 KB
  __shared__ __half2 shagg2[8 * 33];  // 2.1 KB (post-BN2+ReLU)
  __shared__ __half2 shw3[32 * 32];   // 4 KB [kp][c]
  __shared__ float shbn[128];         // sc2|sh2
  const int tid = threadIdx.x;
  const int node0 = blockIdx.x * 8;
  const int last = min(node0 + 7, n - 1);
  const int gb = rbeg[node0];
  const int total = rend[last] - gb;   // block's nodes are contiguous in edata
  const bool lds = (total <= EDCAP_H64);
  if (lds) {
    for (int i = tid; i < total; i += 256) se[i] = edata[gb + i];
  }
  for (int i = tid; i < 32 * 32; i += 256) {
    const int kp = i >> 5, c = i & 31;
    shw3[kp * 32 + c] = __floats2half2_rn(W3[(2 * kp) * 32 + c], W3[(2 * kp + 1) * 32 + c]);
  }
  if (tid < 128) shbn[tid] = bn[128 + tid];
  __syncthreads();
  // ---- gather phase (4 groups x 8 lanes per node, 2 nodes/wave) ----
  const int lane = tid & 63;
  const int node = node0 + ((tid >> 6) << 1) + (lane >> 5);
  const int sub = lane & 31;
  const int qi = sub & 7;     // uint4 index within 128B row
  const int grp = sub >> 3;   // 4 groups per node
  if (node < n) {
    const uint4* hv = reinterpret_cast<const uint4*>(h);
    __half2 c0 = __half2{0, 0}, c1 = c0, c2 = c0, c3 = c0;
    if (lds) {
      const int beg = rbeg[node] - gb, end = rend[node] - gb;
      int e = beg + grp;
      for (; e + 12 < end; e += 16) {
        const int s0 = se[e], s1 = se[e + 4], s2 = se[e + 8], s3 = se[e + 12];
        const uint4 q0 = hv[(size_t)s0 * 8 + qi];
        const uint4 q1 = hv[(size_t)s1 * 8 + qi];
        const uint4 q2 = hv[(size_t)s2 * 8 + qi];
        const uint4 q3 = hv[(size_t)s3 * 8 + qi];
        c0 = __hadd2(c0, uh2(q0.x)); c1 = __hadd2(c1, uh2(q0.y));
        c2 = __hadd2(c2, uh2(q0.z)); c3 = __hadd2(c3, uh2(q0.w));
        c0 = __hadd2(c0, uh2(q1.x)); c1 = __hadd2(c1, uh2(q1.y));
        c2 = __hadd2(c2, uh2(q1.z)); c3 = __hadd2(c3, uh2(q1.w));
        c0 = __hadd2(c0, uh2(q2.x)); c1 = __hadd2(c1, uh2(q2.y));
        c2 = __hadd2(c2, uh2(q2.z)); c3 = __hadd2(c3, uh2(q2.w));
        c0 = __hadd2(c0, uh2(q3.x)); c1 = __hadd2(c1, uh2(q3.y));
        c2 = __hadd2(c2, uh2(q3.z)); c3 = __hadd2(c3, uh2(q3.w));
      }
      for (; e < end; e += 4) {
        const uint4 q = hv[(size_t)se[e] * 8 + qi];
        c0 = __hadd2(c0, uh2(q.x)); c1 = __hadd2(c1, uh2(q.y));
        c2 = __hadd2(c2, uh2(q.z)); c3 = __hadd2(c3, uh2(q.w));
      }
    } else {
      const int beg = rbeg[node], end = rend[node];
      int e = beg + grp;
      for (; e + 12 < end; e += 16) {
        const int s0 = edata[e], s1 = edata[e + 4], s2 = edata[e + 8], s3 = edata[e + 12];
        const uint4 q0 = hv[(size_t)s0 * 8 + qi];
        const uint4 q1 = hv[(size_t)s1 * 8 + qi];
        const uint4 q2 = hv[(size_t)s2 * 8 + qi];
        const uint4 q3 = hv[(size_t)s3 * 8 + qi];
        c0 = __hadd2(c0, uh2(q0.x)); c1 = __hadd2(c1, uh2(q0.y));
        c2 = __hadd2(c2, uh2(q0.z)); c3 = __hadd2(c3, uh2(q0.w));
        c0 = __hadd2(c0, uh2(q1.x)); c1 = __hadd2(c1, uh2(q1.y));
        c2 = __hadd2(c2, uh2(q1.z)); c3 = __hadd2(c3, uh2(q1.w));
        c0 = __hadd2(c0, uh2(q2.x)); c1 = __hadd2(c1, uh2(q2.y));
        c2 = __hadd2(c2, uh2(q2.z)); c3 = __hadd2(c3, uh2(q2.w));
        c0 = __hadd2(c0, uh2(q3.x)); c1 = __hadd2(c1, uh2(q3.y));
        c2 = __hadd2(c2, uh2(q3.z)); c3 = __hadd2(c3, uh2(q3.w));
      }
      for (; e < end; e += 4) {
        const uint4 q = hv[(size_t)edata[e] * 8 + qi];
        c0 = __hadd2(c0, uh2(q.x)); c1 = __hadd2(c1, uh2(q.y));
        c2 = __hadd2(c2, uh2(q.z)); c3 = __hadd2(c3, uh2(q.w));
      }
    }
#pragma unroll
    for (int m = 8; m <= 16; m <<= 1) {
      c0 = __hadd2(c0, h2shfl_xor(c0, m));
      c1 = __hadd2(c1, h2shfl_xor(c1, m));
      c2 = __hadd2(c2, h2shfl_xor(c2, m));
      c3 = __hadd2(c3, h2shfl_xor(c3, m));
    }
    if (grp == 0) {
      const uint4 q = hv[(size_t)node * 8 + qi];  // self term
      c0 = __hadd2(c0, uh2(q.x)); c1 = __hadd2(c1, uh2(q.y));
      c2 = __hadd2(c2, uh2(q.z)); c3 = __hadd2(c3, uh2(q.w));
      const float dn = dinv[node];
      const int nl = node - node0;
      const float2 f[4] = {h22f2(c0), h22f2(c1), h22f2(c2), h22f2(c3)};
#pragma unroll
      for (int j = 0; j < 4; ++j) {
        const int ch = qi * 8 + 2 * j;
        float v0 = f[j].x * dn * shbn[ch] + shbn[64 + ch];
        float v1 = f[j].y * dn * shbn[ch + 1] + shbn[64 + ch + 1];
        v0 = v0 > 0.0f ? v0 : 0.0f;
        v1 = v1 > 0.0f ? v1 : 0.0f;
        shagg2[nl * 33 + qi * 4 + j] = __floats2half2_rn(v0, v1);
      }
    }
  }
  __syncthreads();
  // ---- mm3 phase: thread = (node = tid>>5, c = tid&31) ----
  const int mnode = node0 + (tid >> 5);
  const int c = tid & 31;
  float acc = 0.0f;
#pragma unroll 8
  for (int kp = 0; kp < 32; ++kp) {
    const float2 s = h22f2(shagg2[(tid >> 5) * 33 + kp]);
    const float2 w = h22f2(shw3[kp * 32 + c]);
    acc += s.x * w.x + s.y * w.y;
  }
  float outv = 0.0f;
  if (mnode < n) outv = acc * dinv[mnode];
  const float partner = __shfl_xor(outv, 1);
  if ((c & 1) == 0 && mnode < n) {
    reinterpret_cast<unsigned*>(h3)[(size_t)mnode * 16 + (c >> 1)] = f2u(outv, partner);
  }
}

// ============ gather h3' (C=32) + BN3 + ReLU + 32x2 linear + log_softmax ============
__global__ void gather_cls(const __half* __restrict__ h, const float* __restrict__ dinv,
                           const int* __restrict__ rbeg, const int* __restrict__ rend,
                           const int* __restrict__ edata, const float* __restrict__ bn,
                           const float* __restrict__ Wc, const float* __restrict__ bc,
                           float* __restrict__ out, int n) {
  __shared__ int se[EDCAP_CLS];
  const int tid = threadIdx.x;
  const int node0 = blockIdx.x * 16;
  const int last = min(node0 + 15, n - 1);
  const int gb = rbeg[node0];
  const int total = rend[last] - gb;
  const bool lds = (total <= EDCAP_CLS);
  if (lds) {
    for (int i = tid; i < total; i += 256) se[i] = edata[gb + i];
  }
  __syncthreads();
  const int lane = tid & 63;
  const int node = node0 + ((tid >> 6) << 2) + (lane >> 4);
  if (node >= n) return;
  const int qi = lane & 3;
  const int grp = (lane >> 2) & 3;
  const uint4* hv = reinterpret_cast<const uint4*>(h);
  __half2 c0 = __half2{0, 0}, c1 = c0, c2 = c0, c3 = c0;
  if (lds) {
    const int beg = rbeg[node] - gb, end = rend[node] - gb;
    int e = beg + grp;
    for (; e + 12 < end; e += 16) {
      const int s0 = se[e], s1 = se[e + 4], s2 = se[e + 8], s3 = se[e + 12];
      const uint4 q0 = hv[(size_t)s0 * 4 + qi];
      const uint4 q1 = hv[(size_t)s1 * 4 + qi];
      const uint4 q2 = hv[(size_t)s2 * 4 + qi];
      const uint4 q3 = hv[(size_t)s3 * 4 + qi];
      c0 = __hadd2(c0, uh2(q0.x)); c1 = __hadd2(c1, uh2(q0.y));
      c2 = __hadd2(c2, uh2(q0.z)); c3 = __hadd2(c3, uh2(q0.w));
      c0 = __hadd2(c0, uh2(q1.x)); c1 = __hadd2(c1, uh2(q1.y));
      c2 = __hadd2(c2, uh2(q1.z)); c3 = __hadd2(c3, uh2(q1.w));
      c0 = __hadd2(c0, uh2(q2.x)); c1 = __hadd2(c1, uh2(q2.y));
      c2 = __hadd2(c2, uh2(q2.z)); c3 = __hadd2(c3, uh2(q2.w));
      c0 = __hadd2(c0, uh2(q3.x)); c1 = __hadd2(c1, uh2(q3.y));
      c2 = __hadd2(c2, uh2(q3.z)); c3 = __hadd2(c3, uh2(q3.w));
    }
    for (; e < end; e += 4) {
      const uint4 q = hv[(size_t)se[e] * 4 + qi];
      c0 = __hadd2(c0, uh2(q.x)); c1 = __hadd2(c1, uh2(q.y));
      c2 = __hadd2(c2, uh2(q.z)); c3 = __hadd2(c3, uh2(q.w));
    }
  } else {
    const int beg = rbeg[node], end = rend[node];
    int e = beg + grp;
    for (; e + 12 < end; e += 16) {
      const int s0 = edata[e], s1 = edata[e + 4], s2 = edata[e + 8], s3 = edata[e + 12];
      const uint4 q0 = hv[(size_t)s0 * 4 + qi];
      const uint4 q1 = hv[(size_t)s1 * 4 + qi];
      const uint4 q2 = hv[(size_t)s2 * 4 + qi];
      const uint4 q3 = hv[(size_t)s3 * 4 + qi];
      c0 = __hadd2(c0, uh2(q0.x)); c1 = __hadd2(c1, uh2(q0.y));
      c2 = __hadd2(c2, uh2(q0.z)); c3 = __hadd2(c3, uh2(q0.w));
      c0 = __hadd2(c0, uh2(q1.x)); c1 = __hadd2(c1, uh2(q1.y));
      c2 = __hadd2(c2, uh2(q1.z)); c3 = __hadd2(c3, uh2(q1.w));
      c0 = __hadd2(c0, uh2(q2.x)); c1 = __hadd2(c1, uh2(q2.y));
      c2 = __hadd2(c2, uh2(q2.z)); c3 = __hadd2(c3, uh2(q2.w));
      c0 = __hadd2(c0, uh2(q3.x)); c1 = __hadd2(c1, uh2(q3.y));
      c2 = __hadd2(c2, uh2(q3.z)); c3 = __hadd2(c3, uh2(q3.w));
    }
    for (; e < end; e += 4) {
      const uint4 q = hv[(size_t)edata[e] * 4 + qi];
      c0 = __hadd2(c0, uh2(q.x)); c1 = __hadd2(c1, uh2(q.y));
      c2 = __hadd2(c2, uh2(q.z)); c3 = __hadd2(c3, uh2(q.w));
    }
  }
#pragma unroll
  for (int m = 4; m <= 8; m <<= 1) {
    c0 = __hadd2(c0, h2shfl_xor(c0, m));
    c1 = __hadd2(c1, h2shfl_xor(c1, m));
    c2 = __hadd2(c2, h2shfl_xor(c2, m));
    c3 = __hadd2(c3, h2shfl_xor(c3, m));
  }
  if (grp != 0) return;
  // self term
  {
    const uint4 q = hv[(size_t)node * 4 + qi];
    c0 = __hadd2(c0, uh2(q.x)); c1 = __hadd2(c1, uh2(q.y));
    c2 = __hadd2(c2, uh2(q.z)); c3 = __hadd2(c3, uh2(q.w));
  }
  const float dn = dinv[node];
  const float2 f0 = h22f2(c0), f1 = h22f2(c1);
  const float2 f2 = h22f2(c2), f3 = h22f2(c3);
  const float v[8] = {f0.x * dn, f0.y * dn, f1.x * dn, f1.y * dn,
                      f2.x * dn, f2.y * dn, f3.x * dn, f3.y * dn};
  float l0 = 0.0f, l1 = 0.0f;
#pragma unroll
  for (int j = 0; j < 8; ++j) {
    const int c = qi * 8 + j;
    float t = v[j] * bn[256 + c] + bn[288 + c];
    t = t > 0.0f ? t : 0.0f;
    const float2 w = *reinterpret_cast<const float2*>(&Wc[c * 2]);
    l0 += t * w.x;
    l1 += t * w.y;
  }
  l0 += __shfl_xor(l0, 1); l1 += __shfl_xor(l1, 1);
  l0 += __shfl_xor(l0, 2); l1 += __shfl_xor(l1, 2);
  if (qi == 0) {
    l0 += bc[0];
    l1 += bc[1];
    const float m = fmaxf(l0, l1);
    const float lse = m + log1pf(expf(-fabsf(l0 - l1)));
    *reinterpret_cast<float2*>(&out[(size_t)node * 2]) = make_float2(l0 - lse, l1 - lse);
  }
}

// ============ launch ============
extern "C" void kernel_launch(void* const* d_in, const int* in_sizes, int n_in,
                              void* d_out, int out_size, void* d_ws, size_t ws_size,
                              hipStream_t stream) {
  const float* x  = (const float*)d_in[0];
  const int* ei   = (const int*)d_in[1];   // int32 on device per harness contract
  const float* W1 = (const float*)d_in[2];
  const float* b1 = (const float*)d_in[3];
  const float* g1 = (const float*)d_in[4];
  const float* be1 = (const float*)d_in[5];
  const float* rm1 = (const float*)d_in[6];
  const float* rv1 = (const float*)d_in[7];
  const float* W2 = (const float*)d_in[8];
  const float* b2 = (const float*)d_in[9];
  const float* g2 = (const float*)d_in[10];
  const float* be2 = (const float*)d_in[11];
  const float* rm2 = (const float*)d_in[12];
  const float* rv2 = (const float*)d_in[13];
  const float* W3 = (const float*)d_in[14];
  const float* b3 = (const float*)d_in[15];
  const float* g3 = (const float*)d_in[16];
  const float* be3 = (const float*)d_in[17];
  const float* rm3 = (const float*)d_in[18];
  const float* rv3 = (const float*)d_in[19];
  const float* Wc = (const float*)d_in[20];
  const float* bc = (const float*)d_in[21];

  const int N_ = in_sizes[0] / 8;
  const int E_ = in_sizes[1] / 2;
  const int NB = (N_ + 255) >> 8;          // 256-node buckets

  auto align = [](size_t v) { return (v + 255) & ~(size_t)255; };
  char* ws = (char*)d_ws;
  size_t off = 0;
  float* dinv   = (float*)(ws + off); off += align((size_t)N_ * 4);
  int* bcur     = (int*)(ws + off);   off += align(((size_t)NB + 1) * 4);  // +1: global cursor
  int* rbeg     = (int*)(ws + off);   off += align((size_t)N_ * 4);
  int* rend     = (int*)(ws + off);   off += align((size_t)N_ * 4);
  float* bnbuf  = (float*)(ws + off); off += align(320 * 4);
  int* edata    = (int*)(ws + off);   off += align((size_t)E_ * 4);
  __half* xs    = (__half*)(ws + off); off += align((size_t)N_ * 8 * 2);
  // regionA: bucketbuf packed int (8 MB) -> h3' fp16 (6.4 MB, after p2 consumed bucketbuf)
  char* regionA = ws + off;           off += align((size_t)NB * BCAP * 4);
  // regionB: h2' fp16 (12.8 MB) — live while h3 is written, so separate from regionA
  char* regionB = ws + off;           off += align((size_t)N_ * 64 * 2);

  int* bucketbuf = (int*)regionA;
  __half* h3   = (__half*)regionA;   // after p2_sort consumed bucketbuf
  __half* h2   = (__half*)regionB;
  int* gcursor = bcur + NB;

  // ---- prep (BN constants + zero bcur/cursor) + bucketed CSR build ----
  prep<<<1 + (NB + 1 + 255) / 256, 256, 0, stream>>>(b1, g1, be1, rm1, rv1,
                                                     b2, g2, be2, rm2, rv2,
                                                     b3, g3, be3, rm3, rv3, bnbuf, bcur, NB);
  p1_partition<<<(E_ + 4095) / 4096, 256, 0, stream>>>(ei, bucketbuf, bcur, E_, NB);
  p2_sort<<<NB, 256, 0, stream>>>(bucketbuf, bcur, gcursor, edata, rbeg, rend,
                                  dinv, x, (__half2*)xs, N_);

  // ---- layers 1+2 fused: gather(xs) + mm1 + BN1 + ReLU + mm2 -> h2' ----
  l12<<<(N_ + 31) / 32, 256, 0, stream>>>(xs, dinv, rbeg, rend, edata, W1, W2, bnbuf, h2, N_);

  // ---- layers 2+3 fused: gather(h2') + BN2 + ReLU + mm3 -> h3' ----
  gh64_mm3<<<(N_ + 7) / 8, 256, 0, stream>>>(h2, dinv, rbeg, rend, edata, W3, bnbuf, h3, N_);

  // ---- layer 3 gather + classifier ----
  gather_cls<<<(N_ + 15) / 16, 256, 0, stream>>>(h3, dinv, rbeg, rend, edata,
                                                 bnbuf, Wc, bc, (float*)d_out, N_);
}